// Round 1
// 543.053 us; speedup vs baseline: 1.2217x; 1.2217x over previous
//
#include <hip/hip_runtime.h>

// ---------------------------------------------------------------------------
// Algebra: emb = nd ⊙ (Â (ns ⊙ (feats@Wc + bc))) + b_gcn
//        = nd ⊙ ( g@Wc + h·bcᵀ ) + b_gcn     with g = Â(ns⊙feats), h = Â ns
// (Â = adjacency-by-dst incl. self loops; Wc = W_aff@W_gcn, bc = b_aff@W_gcn)
// Gather is done in F=128 feature space (4x less traffic than D=500 space).
// pred MLP is linear => weights[r] = emb[s]·v1 + emb[o]·v2 + bias_dot,
// v = W_pred_in @ W_pred_out; u-dots fused into the MFMA GEMM epilogue.
//
// R1: replaced the single-workgroup 1024-thread scan (128 µs, 0.145% occ,
// 3.9 GB/s) with a 3-phase multi-block scan; norm computation fused into
// scan phase 1 (same input arrays). Predicted: −120 µs total.
// ---------------------------------------------------------------------------

typedef float f32x4 __attribute__((ext_vector_type(4)));
typedef short s16x8 __attribute__((ext_vector_type(8)));

__device__ __forceinline__ unsigned short f2bf(float f) {
    unsigned u = __float_as_uint(f);
    unsigned r = (u + 0x7FFFu + ((u >> 16) & 1u)) >> 16;
    return (unsigned short)r;
}

__device__ __forceinline__ void async_ld16(const void* g, void* lds) {
    __builtin_amdgcn_global_load_lds(
        (const __attribute__((address_space(1))) unsigned int*)g,
        (__attribute__((address_space(3))) unsigned int*)lds,
        16, 0, 0);
}

// ---------------------------------------------------------------------------
__global__ void degree_kernel(const int* __restrict__ src, const int* __restrict__ dst,
                              unsigned* __restrict__ outd, unsigned* __restrict__ ind, int E) {
    int e = blockIdx.x * blockDim.x + threadIdx.x;
    if (e < E) {
        atomicAdd(&outd[src[e]], 1u);
        atomicAdd(&ind[dst[e]], 1u);
    }
}

// ---------------------------------------------------------------------------
// 3-phase exclusive scan of ind[0..N) -> row_ptr/cursor, fused with norm calc.
// Phase 1: per-block (1024 elems) sums -> partials[b]; also ns/nd = rsqrt(deg+1).
// Phase 2: 1 wave scans partials in-place (exclusive), writes row_ptr[N]=total.
// Phase 3: per-block local exclusive scan + partials offset -> row_ptr, cursor.
// ---------------------------------------------------------------------------
__global__ __launch_bounds__(256) void scan_part1(const unsigned* __restrict__ outd,
                                                  const unsigned* __restrict__ ind,
                                                  float* __restrict__ ns, float* __restrict__ nd,
                                                  int* __restrict__ partials, int N) {
    __shared__ int wsum[4];
    const int tid = threadIdx.x;
    const int lane = tid & 63, w = tid >> 6;
    const int base = blockIdx.x * 1024 + tid * 4;

    unsigned ivr[4] = {0u, 0u, 0u, 0u};
    if (base + 3 < N) {
        uint4 iv = *reinterpret_cast<const uint4*>(ind + base);
        uint4 ov = *reinterpret_cast<const uint4*>(outd + base);
        ivr[0] = iv.x; ivr[1] = iv.y; ivr[2] = iv.z; ivr[3] = iv.w;
        float4 nsv, ndv;
        nsv.x = rsqrtf((float)(ov.x + 1u)); nsv.y = rsqrtf((float)(ov.y + 1u));
        nsv.z = rsqrtf((float)(ov.z + 1u)); nsv.w = rsqrtf((float)(ov.w + 1u));
        ndv.x = rsqrtf((float)(iv.x + 1u)); ndv.y = rsqrtf((float)(iv.y + 1u));
        ndv.z = rsqrtf((float)(iv.z + 1u)); ndv.w = rsqrtf((float)(iv.w + 1u));
        *reinterpret_cast<float4*>(ns + base) = nsv;
        *reinterpret_cast<float4*>(nd + base) = ndv;
    } else {
#pragma unroll
        for (int q = 0; q < 4; ++q) {
            int idx = base + q;
            if (idx < N) {
                unsigned ivq = ind[idx];
                unsigned ovq = outd[idx];
                ns[idx] = rsqrtf((float)(ovq + 1u));
                nd[idx] = rsqrtf((float)(ivq + 1u));
                ivr[q] = ivq;
            }
        }
    }

    int s = (int)(ivr[0] + ivr[1] + ivr[2] + ivr[3]);
#pragma unroll
    for (int m = 32; m > 0; m >>= 1) s += __shfl_down(s, m);
    if (lane == 0) wsum[w] = s;
    __syncthreads();
    if (tid == 0) partials[blockIdx.x] = wsum[0] + wsum[1] + wsum[2] + wsum[3];
}

__global__ void scan_part2(int* __restrict__ partials, int* __restrict__ row_ptr,
                           int NB, int N) {
    const int lane = threadIdx.x;   // 64 threads, 1 wave
    int run = 0;
    for (int b = 0; b < NB; b += 64) {
        int i = b + lane;
        int pv = (i < NB) ? partials[i] : 0;
        int v = pv;
#pragma unroll
        for (int off = 1; off < 64; off <<= 1) {
            int t = __shfl_up(v, off);
            if (lane >= off) v += t;
        }
        if (i < NB) partials[i] = run + v - pv;    // exclusive
        run += __shfl(v, 63);
    }
    if (lane == 0) row_ptr[N] = run;
}

__global__ __launch_bounds__(256) void scan_part3(const unsigned* __restrict__ ind,
                                                  const int* __restrict__ partials,
                                                  int* __restrict__ row_ptr,
                                                  int* __restrict__ cursor, int N) {
    __shared__ int wsum[4];
    const int tid = threadIdx.x;
    const int lane = tid & 63, w = tid >> 6;
    const int base = blockIdx.x * 1024 + tid * 4;

    unsigned ivr[4] = {0u, 0u, 0u, 0u};
    if (base + 3 < N) {
        uint4 iv = *reinterpret_cast<const uint4*>(ind + base);
        ivr[0] = iv.x; ivr[1] = iv.y; ivr[2] = iv.z; ivr[3] = iv.w;
    } else {
#pragma unroll
        for (int q = 0; q < 4; ++q) {
            int idx = base + q;
            if (idx < N) ivr[q] = ind[idx];
        }
    }
    const int tsum = (int)(ivr[0] + ivr[1] + ivr[2] + ivr[3]);
    int v = tsum;
#pragma unroll
    for (int off = 1; off < 64; off <<= 1) {
        int t = __shfl_up(v, off);
        if (lane >= off) v += t;
    }
    if (lane == 63) wsum[w] = v;
    __syncthreads();
    int woff = partials[blockIdx.x];
#pragma unroll
    for (int i = 0; i < 4; ++i) woff += (i < w) ? wsum[i] : 0;
    const int excl = woff + v - tsum;

    int4 o;
    o.x = excl;
    o.y = o.x + (int)ivr[0];
    o.z = o.y + (int)ivr[1];
    o.w = o.z + (int)ivr[2];
    if (base + 3 < N) {
        *reinterpret_cast<int4*>(row_ptr + base) = o;
        *reinterpret_cast<int4*>(cursor + base) = o;
    } else {
        const int ov[4] = {o.x, o.y, o.z, o.w};
#pragma unroll
        for (int q = 0; q < 4; ++q) {
            int idx = base + q;
            if (idx < N) { row_ptr[idx] = ov[q]; cursor[idx] = ov[q]; }
        }
    }
}

__global__ void csr_fill_kernel(const int* __restrict__ src, const int* __restrict__ dst,
                                int* __restrict__ cursor, int* __restrict__ csr_src, int E) {
    int e = blockIdx.x * blockDim.x + threadIdx.x;
    if (e < E) {
        int pos = atomicAdd(&cursor[dst[e]], 1);
        csr_src[pos] = src[e];
    }
}

// bc[n] = sum_k b_aff[k] * W_gcn[k*D + n]
__global__ void bcomb_kernel(const float* __restrict__ b_aff, const float* __restrict__ W_gcn,
                             float* __restrict__ bc, int D) {
    int n = blockIdx.x * blockDim.x + threadIdx.x;
    if (n < D) {
        float s = 0.f;
        for (int k = 0; k < D; ++k) s = fmaf(b_aff[k], W_gcn[k * D + n], s);
        bc[n] = s;
    }
}

// v[k] = sum_c W_pred_in[k*D + c] * w_out[c]   (one wave per row k, k < 2D)
__global__ void vcomb_kernel(const float* __restrict__ Win, const float* __restrict__ wout,
                             float* __restrict__ v, int D, int K2) {
    int k = blockIdx.x * (blockDim.x >> 6) + (threadIdx.x >> 6);
    int lane = threadIdx.x & 63;
    if (k >= K2) return;
    float s = 0.f;
    for (int c = lane; c < D; c += 64) s = fmaf(Win[(long)k * D + c], wout[c], s);
#pragma unroll
    for (int m = 32; m > 0; m >>= 1) s += __shfl_down(s, m);
    if (lane == 0) v[k] = s;
}

// bias_dot = b_pred_out + sum_c b_pred_in[c]*w_out[c]
__global__ void bias_dot_kernel(const float* __restrict__ b_in, const float* __restrict__ w_out,
                                const float* __restrict__ b_out, float* __restrict__ bias_dot, int D) {
    __shared__ float sm[256];
    float s = 0.f;
    for (int c = threadIdx.x; c < D; c += 256) s = fmaf(b_in[c], w_out[c], s);
    sm[threadIdx.x] = s;
    __syncthreads();
    for (int st = 128; st > 0; st >>= 1) {
        if (threadIdx.x < st) sm[threadIdx.x] += sm[threadIdx.x + st];
        __syncthreads();
    }
    if (threadIdx.x == 0) bias_dot[0] = sm[0] + b_out[0];
}

// Zero-pad small vectors to PD=512: bcp, bgp, v1p, v2p
__global__ void pad_kernel(const float* __restrict__ bc, const float* __restrict__ b_gcn,
                           const float* __restrict__ v, float* __restrict__ bcp,
                           float* __restrict__ bgp, float* __restrict__ v1p,
                           float* __restrict__ v2p, int D, int PD) {
    int i = blockIdx.x * blockDim.x + threadIdx.x;
    if (i < PD) {
        bcp[i] = (i < D) ? bc[i] : 0.f;
        bgp[i] = (i < D) ? b_gcn[i] : 0.f;
        v1p[i] = (i < D) ? v[i] : 0.f;
        v2p[i] = (i < D) ? v[D + i] : 0.f;
    }
}

// ---------------------------------------------------------------------------
// fp32 tiled GEMM (only used for the tiny Wc = W_aff @ W_gcn)
// ---------------------------------------------------------------------------
__global__ __launch_bounds__(256) void sgemm_kernel(const float* __restrict__ A, int lda,
                                                    const float* __restrict__ B, int ldb,
                                                    float* __restrict__ C, int ldc,
                                                    int M, int N, int K) {
    __shared__ __align__(16) float As[16][68];
    __shared__ __align__(16) float Bs[16][68];
    const int tid = threadIdx.x;
    const int tx = tid & 15, ty = tid >> 4;
    const int row0 = blockIdx.x * 64;
    const int col0 = blockIdx.y * 64;

    const int a_row = tid >> 2;
    const int a_k   = (tid & 3) * 4;
    const int b_k   = tid >> 4;
    const int b_c   = (tid & 15) * 4;

    float acc[4][4] = {};

    for (int k0 = 0; k0 < K; k0 += 16) {
        float4 av = make_float4(0.f, 0.f, 0.f, 0.f);
        {
            int gr = row0 + a_row;
            int gk = k0 + a_k;
            if (gr < M) {
                if (gk + 3 < K) {
                    av = *reinterpret_cast<const float4*>(&A[(long)gr * lda + gk]);
                } else {
                    float t0 = (gk + 0 < K) ? A[(long)gr * lda + gk + 0] : 0.f;
                    float t1 = (gk + 1 < K) ? A[(long)gr * lda + gk + 1] : 0.f;
                    float t2 = (gk + 2 < K) ? A[(long)gr * lda + gk + 2] : 0.f;
                    float t3 = (gk + 3 < K) ? A[(long)gr * lda + gk + 3] : 0.f;
                    av = make_float4(t0, t1, t2, t3);
                }
            }
        }
        float4 bv = make_float4(0.f, 0.f, 0.f, 0.f);
        {
            int gk = k0 + b_k;
            int gc = col0 + b_c;
            if (gk < K) {
                if (gc + 3 < N) {
                    bv = *reinterpret_cast<const float4*>(&B[(long)gk * ldb + gc]);
                } else {
                    float t0 = (gc + 0 < N) ? B[(long)gk * ldb + gc + 0] : 0.f;
                    float t1 = (gc + 1 < N) ? B[(long)gk * ldb + gc + 1] : 0.f;
                    float t2 = (gc + 2 < N) ? B[(long)gk * ldb + gc + 2] : 0.f;
                    float t3 = (gc + 3 < N) ? B[(long)gk * ldb + gc + 3] : 0.f;
                    bv = make_float4(t0, t1, t2, t3);
                }
            }
        }
        __syncthreads();
        As[a_k + 0][a_row] = av.x;
        As[a_k + 1][a_row] = av.y;
        As[a_k + 2][a_row] = av.z;
        As[a_k + 3][a_row] = av.w;
        *reinterpret_cast<float4*>(&Bs[b_k][b_c]) = bv;
        __syncthreads();

#pragma unroll
        for (int k = 0; k < 16; ++k) {
            const float4 a = *reinterpret_cast<const float4*>(&As[k][ty * 4]);
            const float4 b = *reinterpret_cast<const float4*>(&Bs[k][tx * 4]);
            const float avv[4] = {a.x, a.y, a.z, a.w};
            const float bvv[4] = {b.x, b.y, b.z, b.w};
#pragma unroll
            for (int i = 0; i < 4; ++i)
#pragma unroll
                for (int j = 0; j < 4; ++j)
                    acc[i][j] = fmaf(avv[i], bvv[j], acc[i][j]);
        }
    }

#pragma unroll
    for (int i = 0; i < 4; ++i) {
        int r = row0 + ty * 4 + i;
        if (r >= M) continue;
#pragma unroll
        for (int j = 0; j < 4; ++j) {
            int c = col0 + tx * 4 + j;
            if (c < N) C[(long)r * ldc + c] = acc[i][j];
        }
    }
}

// fs16[s][c] = bf16(feats[s][c] * ns[s])   (F = 128)
__global__ void conv_feats_kernel(const float* __restrict__ feats, const float* __restrict__ ns,
                                  unsigned short* __restrict__ fs16, int N) {
    int idx = blockIdx.x * blockDim.x + threadIdx.x;
    if (idx >= N * 16) return;
    int node = idx >> 4;
    int c = (idx & 15) * 8;
    float s = ns[node];
    const float* p = feats + (long)node * 128 + c;
    float4 a = *reinterpret_cast<const float4*>(p);
    float4 b = *reinterpret_cast<const float4*>(p + 4);
    uint4 o;
    o.x = (unsigned)f2bf(a.x * s) | ((unsigned)f2bf(a.y * s) << 16);
    o.y = (unsigned)f2bf(a.z * s) | ((unsigned)f2bf(a.w * s) << 16);
    o.z = (unsigned)f2bf(b.x * s) | ((unsigned)f2bf(b.y * s) << 16);
    o.w = (unsigned)f2bf(b.z * s) | ((unsigned)f2bf(b.w * s) << 16);
    *reinterpret_cast<uint4*>(fs16 + (long)node * 128 + c) = o;
}

// Wc [128][D] fp32 -> Bt [PD=512 rows n][128 k] bf16 (transposed, pad rows zero)
__global__ void conv_Bt_kernel(const float* __restrict__ Wc, unsigned short* __restrict__ Bt,
                               int D, int PD) {
    int idx = blockIdx.x * blockDim.x + threadIdx.x;   // PD*16 threads
    if (idx >= PD * 16) return;
    int n = idx >> 4;
    int k8 = (idx & 15) * 8;
    uint4 o = make_uint4(0, 0, 0, 0);
    if (n < D) {
        unsigned short t[8];
#pragma unroll
        for (int q = 0; q < 8; ++q) t[q] = f2bf(Wc[(long)(k8 + q) * D + n]);
        o.x = (unsigned)t[0] | ((unsigned)t[1] << 16);
        o.y = (unsigned)t[2] | ((unsigned)t[3] << 16);
        o.z = (unsigned)t[4] | ((unsigned)t[5] << 16);
        o.w = (unsigned)t[6] | ((unsigned)t[7] << 16);
    }
    *reinterpret_cast<uint4*>(Bt + (long)n * 128 + k8) = o;
}

// ---------------------------------------------------------------------------
// Feature-space CSR gather, wave per node:
//   g16[d] = bf16( Σ_{s∈in(d)} fs16[s] + fs16[d] )   (fp32 accum)
//   h[d]   = Σ ns[s] + ns[d]
// Lane owns 2 cols (ushort2 load per neighbor); neighbor ids broadcast by shfl.
// ---------------------------------------------------------------------------
__global__ __launch_bounds__(256) void gather_feats_kernel(
    const unsigned short* __restrict__ fs16, const int* __restrict__ csr_src,
    const int* __restrict__ row_ptr, const float* __restrict__ ns,
    unsigned short* __restrict__ g16, float* __restrict__ h, int N) {
    int d = blockIdx.x * 4 + (threadIdx.x >> 6);
    int lane = threadIdx.x & 63;
    if (d >= N) return;

    // self loop init
    unsigned su = *reinterpret_cast<const unsigned*>(fs16 + (long)d * 128 + lane * 2);
    float a0 = __uint_as_float(su << 16);
    float a1 = __uint_as_float(su & 0xFFFF0000u);
    float hacc = 0.f;

    const int beg = row_ptr[d], end = row_ptr[d + 1];
    for (int j0 = beg; j0 < end; j0 += 64) {
        int cnt = end - j0;
        if (cnt > 64) cnt = 64;
        int s = (lane < cnt) ? csr_src[j0 + lane] : 0;
        if (lane < cnt) hacc += ns[s];
        for (int k = 0; k < cnt; ++k) {
            int sk = __shfl(s, k);
            unsigned v = *reinterpret_cast<const unsigned*>(fs16 + (long)sk * 128 + lane * 2);
            a0 += __uint_as_float(v << 16);
            a1 += __uint_as_float(v & 0xFFFF0000u);
        }
    }
#pragma unroll
    for (int m = 32; m > 0; m >>= 1) hacc += __shfl_xor(hacc, m);
    if (lane == 0) h[d] = hacc + ns[d];
    unsigned o = (unsigned)f2bf(a0) | ((unsigned)f2bf(a1) << 16);
    *reinterpret_cast<unsigned*>(g16 + (long)d * 128 + lane * 2) = o;
}

// ---------------------------------------------------------------------------
// MFMA GEMM: emb[r][c] = nd[r]*( (g16@Wc)[r][c] + h[r]*bcp[c] ) + bgp[c]
// fused epilogue dots: u1[r] += Σ_c emb·v1p, u2[r] += Σ_c emb·v2p (atomic per col-block)
// BM=128 BN=128, K=128 (4 k-steps of 32), 256 threads / 4 waves of 64x64.
// ---------------------------------------------------------------------------
__global__ __launch_bounds__(256) void gcn_gemm_kernel(
    const unsigned short* __restrict__ g16, const unsigned short* __restrict__ Bt,
    const float* __restrict__ h, const float* __restrict__ nd,
    const float* __restrict__ bcp, const float* __restrict__ bgp,
    const float* __restrict__ v1p, const float* __restrict__ v2p,
    float* __restrict__ emb, float* __restrict__ u1, float* __restrict__ u2,
    int M, int D) {

    __shared__ __align__(16) unsigned short As[128 * 32];
    __shared__ __align__(16) unsigned short Bs[128 * 32];

    const int tid  = threadIdx.x;
    const int w    = tid >> 6;
    const int lane = tid & 63;
    const int row0 = blockIdx.x * 128;
    const int col0 = blockIdx.y * 128;

    // staging: wave w owns chunks {2w, 2w+1} of both A and B (16 rows x 32 k each)
    const int r0   = 2 * w * 16 + (lane >> 2);
    const int r1   = (2 * w + 1) * 16 + (lane >> 2);
    const int slot = lane & 3;
    const int c0   = slot ^ ((r0 >> 1) & 3);
    const int c1   = slot ^ ((r1 >> 1) & 3);

    const unsigned short* pA0 = g16 + (long)(row0 + r0) * 128 + c0 * 8;
    const unsigned short* pA1 = g16 + (long)(row0 + r1) * 128 + c1 * 8;
    const unsigned short* pB0 = Bt + (long)(col0 + r0) * 128 + c0 * 8;
    const unsigned short* pB1 = Bt + (long)(col0 + r1) * 128 + c1 * 8;

    unsigned short* dA0 = As + 2 * w * 512;
    unsigned short* dA1 = As + (2 * w + 1) * 512;
    unsigned short* dB0 = Bs + 2 * w * 512;
    unsigned short* dB1 = Bs + (2 * w + 1) * 512;

    const int wrow = (w & 1) * 64;
    const int wcol = (w >> 1) * 64;
    const int lm = lane & 15, q = lane >> 4;
    const s16x8* pa[4];
    const s16x8* pb[4];
#pragma unroll
    for (int i = 0; i < 4; ++i) {
        int r = wrow + i * 16 + lm;
        int cs = q ^ ((r >> 1) & 3);
        pa[i] = reinterpret_cast<const s16x8*>(As + r * 32 + cs * 8);
        int n = wcol + i * 16 + lm;
        int cs2 = q ^ ((n >> 1) & 3);
        pb[i] = reinterpret_cast<const s16x8*>(Bs + n * 32 + cs2 * 8);
    }

    f32x4 acc[4][4];
#pragma unroll
    for (int i = 0; i < 4; ++i)
#pragma unroll
        for (int j = 0; j < 4; ++j) acc[i][j] = (f32x4)0.f;

    for (int k0 = 0; k0 < 128; k0 += 32) {
        async_ld16(pA0 + k0, dA0);
        async_ld16(pA1 + k0, dA1);
        async_ld16(pB0 + k0, dB0);
        async_ld16(pB1 + k0, dB1);
        __syncthreads();

        s16x8 af[4], bf[4];
#pragma unroll
        for (int i = 0; i < 4; ++i) { af[i] = *pa[i]; bf[i] = *pb[i]; }
#pragma unroll
        for (int i = 0; i < 4; ++i)
#pragma unroll
            for (int j = 0; j < 4; ++j)
                acc[i][j] = __builtin_amdgcn_mfma_f32_16x16x32_bf16(af[i], bf[j], acc[i][j], 0, 0, 0);
        __syncthreads();
    }

    // epilogue: finalize emb + fused u-dots
    float bcv[4], bgv[4], w1[4], w2[4];
    int colv[4];
#pragma unroll
    for (int j = 0; j < 4; ++j) {
        int c = col0 + wcol + j * 16 + lm;
        colv[j] = c;
        bcv[j] = bcp[c];
        bgv[j] = bgp[c];
        w1[j] = v1p[c];
        w2[j] = v2p[c];
    }

#pragma unroll
    for (int i = 0; i < 4; ++i) {
        float p1[4], p2[4];
#pragma unroll
        for (int reg = 0; reg < 4; ++reg) {
            int row = row0 + wrow + i * 16 + q * 4 + reg;
            float hb = h[row];
            float sc = nd[row];
            float s1 = 0.f, s2 = 0.f;
#pragma unroll
            for (int j = 0; j < 4; ++j) {
                float o = fmaf(sc, acc[i][j][reg] + hb * bcv[j], bgv[j]);
                if (row < M && colv[j] < D) emb[(long)row * D + colv[j]] = o;
                s1 = fmaf(o, w1[j], s1);
                s2 = fmaf(o, w2[j], s2);
            }
            p1[reg] = s1;
            p2[reg] = s2;
        }
#pragma unroll
        for (int mask = 1; mask < 16; mask <<= 1)
#pragma unroll
            for (int reg = 0; reg < 4; ++reg) {
                p1[reg] += __shfl_xor(p1[reg], mask);
                p2[reg] += __shfl_xor(p2[reg], mask);
            }
        if (lm == 0) {
#pragma unroll
            for (int reg = 0; reg < 4; ++reg) {
                int row = row0 + wrow + i * 16 + q * 4 + reg;
                if (row < M) {
                    atomicAdd(&u1[row], p1[reg]);
                    atomicAdd(&u2[row], p2[reg]);
                }
            }
        }
    }
}

// weights[r] = u1[trip[r,0]] + u2[trip[r,2]] + bias_dot
__global__ void weights_kernel(const int* __restrict__ trip, const float* __restrict__ u1,
                               const float* __restrict__ u2, const float* __restrict__ bdot,
                               float* __restrict__ w, int T) {
    int r = blockIdx.x * blockDim.x + threadIdx.x;
    if (r < T) {
        int s = trip[(long)r * 3 + 0];
        int o = trip[(long)r * 3 + 2];
        w[r] = u1[s] + u2[o] + bdot[0];
    }
}

// ---------------------------------------------------------------------------

extern "C" void kernel_launch(void* const* d_in, const int* in_sizes, int n_in,
                              void* d_out, int out_size, void* d_ws, size_t ws_size,
                              hipStream_t stream) {
    const float* feats      = (const float*)d_in[0];
    const float* W_aff      = (const float*)d_in[1];
    const float* b_aff      = (const float*)d_in[2];
    const float* W_gcn      = (const float*)d_in[3];
    const float* b_gcn      = (const float*)d_in[4];
    const float* W_pred_in  = (const float*)d_in[5];
    const float* b_pred_in  = (const float*)d_in[6];
    const float* W_pred_out = (const float*)d_in[7];
    const float* b_pred_out = (const float*)d_in[8];
    const int*   src        = (const int*)d_in[9];
    const int*   dst        = (const int*)d_in[10];
    const int*   trip       = (const int*)d_in[11];

    const int D = in_sizes[2];           // 500
    const int F = in_sizes[1] / D;       // 128
    const int N = in_sizes[0] / F;       // 50000
    const int E = in_sizes[9];           // 800000
    const int T = in_sizes[11] / 3;      // 200000

    const int PD = 512;
    const int GX = (N + 127) / 128;      // 391 row-blocks
    const int Mpad = GX * 128;           // 50048
    const int NB = (N + 1023) / 1024;    // scan blocks (49)

    float* weights = (float*)d_out;          // [T]
    float* emb     = (float*)d_out + T;      // [N*D]

    // workspace layout (16B-aligned chunks first)
    char* p = (char*)d_ws;
    unsigned short* fs16 = (unsigned short*)p;  p += (size_t)N * 128 * 2;        // 12.8 MB
    unsigned short* g16  = (unsigned short*)p;  p += (size_t)Mpad * 128 * 2;     // 12.8 MB
    unsigned short* Bt   = (unsigned short*)p;  p += (size_t)PD * 128 * 2;       // 128 KB
    float* Wc   = (float*)p;  p += (size_t)F * D * 4;                            // 256 KB
    float* bc   = (float*)p;  p += 512 * 4;
    float* bcp  = (float*)p;  p += PD * 4;
    float* bgp  = (float*)p;  p += PD * 4;
    float* v1p  = (float*)p;  p += PD * 4;
    float* v2p  = (float*)p;  p += PD * 4;
    float* v    = (float*)p;  p += 1024 * 4;
    float* bdot = (float*)p;  p += 16;
    float* ns   = (float*)p;  p += (size_t)N * 4;
    float* nd   = (float*)p;  p += (size_t)N * 4;
    float* h    = (float*)p;  p += (size_t)Mpad * 4;
    float* u1   = (float*)p;  p += (size_t)N * 4;
    float* u2   = (float*)p;  p += (size_t)N * 4;
    unsigned* outd = (unsigned*)p;  p += (size_t)N * 4;
    unsigned* ind  = (unsigned*)p;  p += (size_t)N * 4;
    int* row_ptr = (int*)p;  p += (size_t)(N + 1) * 4;
    int* cursor  = (int*)p;  p += (size_t)N * 4;
    int* csr_src = (int*)p;  p += (size_t)E * 4;
    int* partials = (int*)p; p += 1024 * 4;

    // zero: degree counters, u-accumulators, g16/h pad rows (deterministic OOB rows)
    hipMemsetAsync(outd, 0, 2 * (size_t)N * sizeof(unsigned), stream);
    hipMemsetAsync(u1, 0, 2 * (size_t)N * sizeof(float), stream);
    hipMemsetAsync(g16 + (size_t)N * 128, 0, (size_t)(Mpad - N) * 128 * 2, stream);
    hipMemsetAsync(h + N, 0, (size_t)(Mpad - N) * 4, stream);

    // degrees + fused norm/scan + CSR build
    degree_kernel<<<(E + 255) / 256, 256, 0, stream>>>(src, dst, outd, ind, E);
    scan_part1<<<NB, 256, 0, stream>>>(outd, ind, ns, nd, partials, N);
    scan_part2<<<1, 64, 0, stream>>>(partials, row_ptr, NB, N);
    scan_part3<<<NB, 256, 0, stream>>>(ind, partials, row_ptr, cursor, N);
    csr_fill_kernel<<<(E + 255) / 256, 256, 0, stream>>>(src, dst, cursor, csr_src, E);

    // pred linearization + weight prep
    vcomb_kernel<<<(2 * D + 3) / 4, 256, 0, stream>>>(W_pred_in, W_pred_out, v, D, 2 * D);
    bias_dot_kernel<<<1, 256, 0, stream>>>(b_pred_in, W_pred_out, b_pred_out, bdot, D);

    // Wc = W_aff @ W_gcn ; bc = b_aff @ W_gcn ; pads ; Bt (bf16 transposed Wc)
    {
        dim3 grid((F + 63) / 64, (D + 63) / 64);
        sgemm_kernel<<<grid, 256, 0, stream>>>(W_aff, D, W_gcn, D, Wc, D, F, D, D);
    }
    bcomb_kernel<<<(D + 255) / 256, 256, 0, stream>>>(b_aff, W_gcn, bc, D);
    pad_kernel<<<(PD + 255) / 256, 256, 0, stream>>>(bc, b_gcn, v, bcp, bgp, v1p, v2p, D, PD);
    conv_Bt_kernel<<<(PD * 16 + 255) / 256, 256, 0, stream>>>(Wc, Bt, D, PD);

    // fs16 = bf16(ns ⊙ feats)
    conv_feats_kernel<<<(N * 16 + 255) / 256, 256, 0, stream>>>(feats, ns, fs16, N);

    // feature-space gather: g16, h
    gather_feats_kernel<<<(N + 3) / 4, 256, 0, stream>>>(fs16, csr_src, row_ptr, ns, g16, h, N);

    // MFMA GEMM: emb (+ fused u1/u2 dots)
    {
        dim3 grid(GX, PD / 128);
        gcn_gemm_kernel<<<grid, 256, 0, stream>>>(g16, Bt, h, nd, bcp, bgp, v1p, v2p,
                                                  emb, u1, u2, N, D);
    }

    // weights from per-node scalars
    weights_kernel<<<(T + 255) / 256, 256, 0, stream>>>(trip, u1, u2, bdot, weights, T);
}

// Round 2
// 441.046 us; speedup vs baseline: 1.5042x; 1.2313x over previous
//
#include <hip/hip_runtime.h>

// ---------------------------------------------------------------------------
// Algebra: emb = nd ⊙ (Â (ns ⊙ (feats@Wc + bc))) + b_gcn
//        = nd ⊙ ( g@Wc + h·bcᵀ ) + b_gcn     with g = Â(ns⊙feats), h = Â ns
// (Â = adjacency-by-dst incl. self loops; Wc = W_aff@W_gcn, bc = b_aff@W_gcn)
// Gather is done in F=128 feature space (4x less traffic than D=500 space).
// pred MLP is linear => weights[r] = emb[s]·v1 + emb[o]·v2 + bias_dot,
// v = W_pred_in @ W_pred_out; u-dots fused into the MFMA GEMM epilogue.
//
// R1: 3-phase multi-block scan (+norm fusion). 663→543 µs (pred −120, got −120).
// R2: bcomb (2-block, 126 µs, 0.088% occ) -> split-K 126-block partials,
// reduced inside pad_kernel. Predicted total ~420 µs.
// ---------------------------------------------------------------------------

typedef float f32x4 __attribute__((ext_vector_type(4)));
typedef short s16x8 __attribute__((ext_vector_type(8)));

__device__ __forceinline__ unsigned short f2bf(float f) {
    unsigned u = __float_as_uint(f);
    unsigned r = (u + 0x7FFFu + ((u >> 16) & 1u)) >> 16;
    return (unsigned short)r;
}

__device__ __forceinline__ void async_ld16(const void* g, void* lds) {
    __builtin_amdgcn_global_load_lds(
        (const __attribute__((address_space(1))) unsigned int*)g,
        (__attribute__((address_space(3))) unsigned int*)lds,
        16, 0, 0);
}

// ---------------------------------------------------------------------------
__global__ void degree_kernel(const int* __restrict__ src, const int* __restrict__ dst,
                              unsigned* __restrict__ outd, unsigned* __restrict__ ind, int E) {
    int e = blockIdx.x * blockDim.x + threadIdx.x;
    if (e < E) {
        atomicAdd(&outd[src[e]], 1u);
        atomicAdd(&ind[dst[e]], 1u);
    }
}

// ---------------------------------------------------------------------------
// 3-phase exclusive scan of ind[0..N) -> row_ptr/cursor, fused with norm calc.
// ---------------------------------------------------------------------------
__global__ __launch_bounds__(256) void scan_part1(const unsigned* __restrict__ outd,
                                                  const unsigned* __restrict__ ind,
                                                  float* __restrict__ ns, float* __restrict__ nd,
                                                  int* __restrict__ partials, int N) {
    __shared__ int wsum[4];
    const int tid = threadIdx.x;
    const int lane = tid & 63, w = tid >> 6;
    const int base = blockIdx.x * 1024 + tid * 4;

    unsigned ivr[4] = {0u, 0u, 0u, 0u};
    if (base + 3 < N) {
        uint4 iv = *reinterpret_cast<const uint4*>(ind + base);
        uint4 ov = *reinterpret_cast<const uint4*>(outd + base);
        ivr[0] = iv.x; ivr[1] = iv.y; ivr[2] = iv.z; ivr[3] = iv.w;
        float4 nsv, ndv;
        nsv.x = rsqrtf((float)(ov.x + 1u)); nsv.y = rsqrtf((float)(ov.y + 1u));
        nsv.z = rsqrtf((float)(ov.z + 1u)); nsv.w = rsqrtf((float)(ov.w + 1u));
        ndv.x = rsqrtf((float)(iv.x + 1u)); ndv.y = rsqrtf((float)(iv.y + 1u));
        ndv.z = rsqrtf((float)(iv.z + 1u)); ndv.w = rsqrtf((float)(iv.w + 1u));
        *reinterpret_cast<float4*>(ns + base) = nsv;
        *reinterpret_cast<float4*>(nd + base) = ndv;
    } else {
#pragma unroll
        for (int q = 0; q < 4; ++q) {
            int idx = base + q;
            if (idx < N) {
                unsigned ivq = ind[idx];
                unsigned ovq = outd[idx];
                ns[idx] = rsqrtf((float)(ovq + 1u));
                nd[idx] = rsqrtf((float)(ivq + 1u));
                ivr[q] = ivq;
            }
        }
    }

    int s = (int)(ivr[0] + ivr[1] + ivr[2] + ivr[3]);
#pragma unroll
    for (int m = 32; m > 0; m >>= 1) s += __shfl_down(s, m);
    if (lane == 0) wsum[w] = s;
    __syncthreads();
    if (tid == 0) partials[blockIdx.x] = wsum[0] + wsum[1] + wsum[2] + wsum[3];
}

__global__ void scan_part2(int* __restrict__ partials, int* __restrict__ row_ptr,
                           int NB, int N) {
    const int lane = threadIdx.x;   // 64 threads, 1 wave
    int run = 0;
    for (int b = 0; b < NB; b += 64) {
        int i = b + lane;
        int pv = (i < NB) ? partials[i] : 0;
        int v = pv;
#pragma unroll
        for (int off = 1; off < 64; off <<= 1) {
            int t = __shfl_up(v, off);
            if (lane >= off) v += t;
        }
        if (i < NB) partials[i] = run + v - pv;    // exclusive
        run += __shfl(v, 63);
    }
    if (lane == 0) row_ptr[N] = run;
}

__global__ __launch_bounds__(256) void scan_part3(const unsigned* __restrict__ ind,
                                                  const int* __restrict__ partials,
                                                  int* __restrict__ row_ptr,
                                                  int* __restrict__ cursor, int N) {
    __shared__ int wsum[4];
    const int tid = threadIdx.x;
    const int lane = tid & 63, w = tid >> 6;
    const int base = blockIdx.x * 1024 + tid * 4;

    unsigned ivr[4] = {0u, 0u, 0u, 0u};
    if (base + 3 < N) {
        uint4 iv = *reinterpret_cast<const uint4*>(ind + base);
        ivr[0] = iv.x; ivr[1] = iv.y; ivr[2] = iv.z; ivr[3] = iv.w;
    } else {
#pragma unroll
        for (int q = 0; q < 4; ++q) {
            int idx = base + q;
            if (idx < N) ivr[q] = ind[idx];
        }
    }
    const int tsum = (int)(ivr[0] + ivr[1] + ivr[2] + ivr[3]);
    int v = tsum;
#pragma unroll
    for (int off = 1; off < 64; off <<= 1) {
        int t = __shfl_up(v, off);
        if (lane >= off) v += t;
    }
    if (lane == 63) wsum[w] = v;
    __syncthreads();
    int woff = partials[blockIdx.x];
#pragma unroll
    for (int i = 0; i < 4; ++i) woff += (i < w) ? wsum[i] : 0;
    const int excl = woff + v - tsum;

    int4 o;
    o.x = excl;
    o.y = o.x + (int)ivr[0];
    o.z = o.y + (int)ivr[1];
    o.w = o.z + (int)ivr[2];
    if (base + 3 < N) {
        *reinterpret_cast<int4*>(row_ptr + base) = o;
        *reinterpret_cast<int4*>(cursor + base) = o;
    } else {
        const int ov[4] = {o.x, o.y, o.z, o.w};
#pragma unroll
        for (int q = 0; q < 4; ++q) {
            int idx = base + q;
            if (idx < N) { row_ptr[idx] = ov[q]; cursor[idx] = ov[q]; }
        }
    }
}

__global__ void csr_fill_kernel(const int* __restrict__ src, const int* __restrict__ dst,
                                int* __restrict__ cursor, int* __restrict__ csr_src, int E) {
    int e = blockIdx.x * blockDim.x + threadIdx.x;
    if (e < E) {
        int pos = atomicAdd(&cursor[dst[e]], 1);
        csr_src[pos] = src[e];
    }
}

// Split-K partials for bc[n] = sum_k b_aff[k] * W_gcn[k*D + n]
// grid = (ceil(PD/256), NC);  chunk c covers k in [8c, min(8c+8, D)).
// Rows with n >= D (pad) are written as 0 so pad_kernel can sum blindly.
__global__ __launch_bounds__(256) void bcomb_part_kernel(
    const float* __restrict__ b_aff, const float* __restrict__ W_gcn,
    float* __restrict__ part, int D, int PD) {
    int n = blockIdx.x * blockDim.x + threadIdx.x;
    int c = blockIdx.y;
    if (n >= PD) return;
    float s = 0.f;
    if (n < D) {
        int k0 = c * 8;
        int k1 = k0 + 8; if (k1 > D) k1 = D;
        for (int k = k0; k < k1; ++k) s = fmaf(b_aff[k], W_gcn[(long)k * D + n], s);
    }
    part[(long)c * PD + n] = s;
}

// v[k] = sum_c W_pred_in[k*D + c] * w_out[c]   (one wave per row k, k < 2D)
__global__ void vcomb_kernel(const float* __restrict__ Win, const float* __restrict__ wout,
                             float* __restrict__ v, int D, int K2) {
    int k = blockIdx.x * (blockDim.x >> 6) + (threadIdx.x >> 6);
    int lane = threadIdx.x & 63;
    if (k >= K2) return;
    float s = 0.f;
    for (int c = lane; c < D; c += 64) s = fmaf(Win[(long)k * D + c], wout[c], s);
#pragma unroll
    for (int m = 32; m > 0; m >>= 1) s += __shfl_down(s, m);
    if (lane == 0) v[k] = s;
}

// bias_dot = b_pred_out + sum_c b_pred_in[c]*w_out[c]
__global__ void bias_dot_kernel(const float* __restrict__ b_in, const float* __restrict__ w_out,
                                const float* __restrict__ b_out, float* __restrict__ bias_dot, int D) {
    __shared__ float sm[256];
    float s = 0.f;
    for (int c = threadIdx.x; c < D; c += 256) s = fmaf(b_in[c], w_out[c], s);
    sm[threadIdx.x] = s;
    __syncthreads();
    for (int st = 128; st > 0; st >>= 1) {
        if (threadIdx.x < st) sm[threadIdx.x] += sm[threadIdx.x + st];
        __syncthreads();
    }
    if (threadIdx.x == 0) bias_dot[0] = sm[0] + b_out[0];
}

// Zero-pad small vectors to PD=512: bcp (reduced from split-K partials), bgp, v1p, v2p
__global__ void pad_kernel(const float* __restrict__ part, const float* __restrict__ b_gcn,
                           const float* __restrict__ v, float* __restrict__ bcp,
                           float* __restrict__ bgp, float* __restrict__ v1p,
                           float* __restrict__ v2p, int D, int PD, int NC) {
    int i = blockIdx.x * blockDim.x + threadIdx.x;
    if (i < PD) {
        float s = 0.f;
        for (int c = 0; c < NC; ++c) s += part[(long)c * PD + i];
        bcp[i] = s;                       // pad cols already 0 in part
        bgp[i] = (i < D) ? b_gcn[i] : 0.f;
        v1p[i] = (i < D) ? v[i] : 0.f;
        v2p[i] = (i < D) ? v[D + i] : 0.f;
    }
}

// ---------------------------------------------------------------------------
// fp32 tiled GEMM (only used for the tiny Wc = W_aff @ W_gcn)
// ---------------------------------------------------------------------------
__global__ __launch_bounds__(256) void sgemm_kernel(const float* __restrict__ A, int lda,
                                                    const float* __restrict__ B, int ldb,
                                                    float* __restrict__ C, int ldc,
                                                    int M, int N, int K) {
    __shared__ __align__(16) float As[16][68];
    __shared__ __align__(16) float Bs[16][68];
    const int tid = threadIdx.x;
    const int tx = tid & 15, ty = tid >> 4;
    const int row0 = blockIdx.x * 64;
    const int col0 = blockIdx.y * 64;

    const int a_row = tid >> 2;
    const int a_k   = (tid & 3) * 4;
    const int b_k   = tid >> 4;
    const int b_c   = (tid & 15) * 4;

    float acc[4][4] = {};

    for (int k0 = 0; k0 < K; k0 += 16) {
        float4 av = make_float4(0.f, 0.f, 0.f, 0.f);
        {
            int gr = row0 + a_row;
            int gk = k0 + a_k;
            if (gr < M) {
                if (gk + 3 < K) {
                    av = *reinterpret_cast<const float4*>(&A[(long)gr * lda + gk]);
                } else {
                    float t0 = (gk + 0 < K) ? A[(long)gr * lda + gk + 0] : 0.f;
                    float t1 = (gk + 1 < K) ? A[(long)gr * lda + gk + 1] : 0.f;
                    float t2 = (gk + 2 < K) ? A[(long)gr * lda + gk + 2] : 0.f;
                    float t3 = (gk + 3 < K) ? A[(long)gr * lda + gk + 3] : 0.f;
                    av = make_float4(t0, t1, t2, t3);
                }
            }
        }
        float4 bv = make_float4(0.f, 0.f, 0.f, 0.f);
        {
            int gk = k0 + b_k;
            int gc = col0 + b_c;
            if (gk < K) {
                if (gc + 3 < N) {
                    bv = *reinterpret_cast<const float4*>(&B[(long)gk * ldb + gc]);
                } else {
                    float t0 = (gc + 0 < N) ? B[(long)gk * ldb + gc + 0] : 0.f;
                    float t1 = (gc + 1 < N) ? B[(long)gk * ldb + gc + 1] : 0.f;
                    float t2 = (gc + 2 < N) ? B[(long)gk * ldb + gc + 2] : 0.f;
                    float t3 = (gc + 3 < N) ? B[(long)gk * ldb + gc + 3] : 0.f;
                    bv = make_float4(t0, t1, t2, t3);
                }
            }
        }
        __syncthreads();
        As[a_k + 0][a_row] = av.x;
        As[a_k + 1][a_row] = av.y;
        As[a_k + 2][a_row] = av.z;
        As[a_k + 3][a_row] = av.w;
        *reinterpret_cast<float4*>(&Bs[b_k][b_c]) = bv;
        __syncthreads();

#pragma unroll
        for (int k = 0; k < 16; ++k) {
            const float4 a = *reinterpret_cast<const float4*>(&As[k][ty * 4]);
            const float4 b = *reinterpret_cast<const float4*>(&Bs[k][tx * 4]);
            const float avv[4] = {a.x, a.y, a.z, a.w};
            const float bvv[4] = {b.x, b.y, b.z, b.w};
#pragma unroll
            for (int i = 0; i < 4; ++i)
#pragma unroll
                for (int j = 0; j < 4; ++j)
                    acc[i][j] = fmaf(avv[i], bvv[j], acc[i][j]);
        }
    }

#pragma unroll
    for (int i = 0; i < 4; ++i) {
        int r = row0 + ty * 4 + i;
        if (r >= M) continue;
#pragma unroll
        for (int j = 0; j < 4; ++j) {
            int c = col0 + tx * 4 + j;
            if (c < N) C[(long)r * ldc + c] = acc[i][j];
        }
    }
}

// fs16[s][c] = bf16(feats[s][c] * ns[s])   (F = 128)
__global__ void conv_feats_kernel(const float* __restrict__ feats, const float* __restrict__ ns,
                                  unsigned short* __restrict__ fs16, int N) {
    int idx = blockIdx.x * blockDim.x + threadIdx.x;
    if (idx >= N * 16) return;
    int node = idx >> 4;
    int c = (idx & 15) * 8;
    float s = ns[node];
    const float* p = feats + (long)node * 128 + c;
    float4 a = *reinterpret_cast<const float4*>(p);
    float4 b = *reinterpret_cast<const float4*>(p + 4);
    uint4 o;
    o.x = (unsigned)f2bf(a.x * s) | ((unsigned)f2bf(a.y * s) << 16);
    o.y = (unsigned)f2bf(a.z * s) | ((unsigned)f2bf(a.w * s) << 16);
    o.z = (unsigned)f2bf(b.x * s) | ((unsigned)f2bf(b.y * s) << 16);
    o.w = (unsigned)f2bf(b.z * s) | ((unsigned)f2bf(b.w * s) << 16);
    *reinterpret_cast<uint4*>(fs16 + (long)node * 128 + c) = o;
}

// Wc [128][D] fp32 -> Bt [PD=512 rows n][128 k] bf16 (transposed, pad rows zero)
__global__ void conv_Bt_kernel(const float* __restrict__ Wc, unsigned short* __restrict__ Bt,
                               int D, int PD) {
    int idx = blockIdx.x * blockDim.x + threadIdx.x;   // PD*16 threads
    if (idx >= PD * 16) return;
    int n = idx >> 4;
    int k8 = (idx & 15) * 8;
    uint4 o = make_uint4(0, 0, 0, 0);
    if (n < D) {
        unsigned short t[8];
#pragma unroll
        for (int q = 0; q < 8; ++q) t[q] = f2bf(Wc[(long)(k8 + q) * D + n]);
        o.x = (unsigned)t[0] | ((unsigned)t[1] << 16);
        o.y = (unsigned)t[2] | ((unsigned)t[3] << 16);
        o.z = (unsigned)t[4] | ((unsigned)t[5] << 16);
        o.w = (unsigned)t[6] | ((unsigned)t[7] << 16);
    }
    *reinterpret_cast<uint4*>(Bt + (long)n * 128 + k8) = o;
}

// ---------------------------------------------------------------------------
// Feature-space CSR gather, wave per node:
//   g16[d] = bf16( Σ_{s∈in(d)} fs16[s] + fs16[d] )   (fp32 accum)
//   h[d]   = Σ ns[s] + ns[d]
// ---------------------------------------------------------------------------
__global__ __launch_bounds__(256) void gather_feats_kernel(
    const unsigned short* __restrict__ fs16, const int* __restrict__ csr_src,
    const int* __restrict__ row_ptr, const float* __restrict__ ns,
    unsigned short* __restrict__ g16, float* __restrict__ h, int N) {
    int d = blockIdx.x * 4 + (threadIdx.x >> 6);
    int lane = threadIdx.x & 63;
    if (d >= N) return;

    // self loop init
    unsigned su = *reinterpret_cast<const unsigned*>(fs16 + (long)d * 128 + lane * 2);
    float a0 = __uint_as_float(su << 16);
    float a1 = __uint_as_float(su & 0xFFFF0000u);
    float hacc = 0.f;

    const int beg = row_ptr[d], end = row_ptr[d + 1];
    for (int j0 = beg; j0 < end; j0 += 64) {
        int cnt = end - j0;
        if (cnt > 64) cnt = 64;
        int s = (lane < cnt) ? csr_src[j0 + lane] : 0;
        if (lane < cnt) hacc += ns[s];
        for (int k = 0; k < cnt; ++k) {
            int sk = __shfl(s, k);
            unsigned v = *reinterpret_cast<const unsigned*>(fs16 + (long)sk * 128 + lane * 2);
            a0 += __uint_as_float(v << 16);
            a1 += __uint_as_float(v & 0xFFFF0000u);
        }
    }
#pragma unroll
    for (int m = 32; m > 0; m >>= 1) hacc += __shfl_xor(hacc, m);
    if (lane == 0) h[d] = hacc + ns[d];
    unsigned o = (unsigned)f2bf(a0) | ((unsigned)f2bf(a1) << 16);
    *reinterpret_cast<unsigned*>(g16 + (long)d * 128 + lane * 2) = o;
}

// ---------------------------------------------------------------------------
// MFMA GEMM: emb[r][c] = nd[r]*( (g16@Wc)[r][c] + h[r]*bcp[c] ) + bgp[c]
// fused epilogue dots: u1[r] += Σ_c emb·v1p, u2[r] += Σ_c emb·v2p
// ---------------------------------------------------------------------------
__global__ __launch_bounds__(256) void gcn_gemm_kernel(
    const unsigned short* __restrict__ g16, const unsigned short* __restrict__ Bt,
    const float* __restrict__ h, const float* __restrict__ nd,
    const float* __restrict__ bcp, const float* __restrict__ bgp,
    const float* __restrict__ v1p, const float* __restrict__ v2p,
    float* __restrict__ emb, float* __restrict__ u1, float* __restrict__ u2,
    int M, int D) {

    __shared__ __align__(16) unsigned short As[128 * 32];
    __shared__ __align__(16) unsigned short Bs[128 * 32];

    const int tid  = threadIdx.x;
    const int w    = tid >> 6;
    const int lane = tid & 63;
    const int row0 = blockIdx.x * 128;
    const int col0 = blockIdx.y * 128;

    const int r0   = 2 * w * 16 + (lane >> 2);
    const int r1   = (2 * w + 1) * 16 + (lane >> 2);
    const int slot = lane & 3;
    const int c0   = slot ^ ((r0 >> 1) & 3);
    const int c1   = slot ^ ((r1 >> 1) & 3);

    const unsigned short* pA0 = g16 + (long)(row0 + r0) * 128 + c0 * 8;
    const unsigned short* pA1 = g16 + (long)(row0 + r1) * 128 + c1 * 8;
    const unsigned short* pB0 = Bt + (long)(col0 + r0) * 128 + c0 * 8;
    const unsigned short* pB1 = Bt + (long)(col0 + r1) * 128 + c1 * 8;

    unsigned short* dA0 = As + 2 * w * 512;
    unsigned short* dA1 = As + (2 * w + 1) * 512;
    unsigned short* dB0 = Bs + 2 * w * 512;
    unsigned short* dB1 = Bs + (2 * w + 1) * 512;

    const int wrow = (w & 1) * 64;
    const int wcol = (w >> 1) * 64;
    const int lm = lane & 15, q = lane >> 4;
    const s16x8* pa[4];
    const s16x8* pb[4];
#pragma unroll
    for (int i = 0; i < 4; ++i) {
        int r = wrow + i * 16 + lm;
        int cs = q ^ ((r >> 1) & 3);
        pa[i] = reinterpret_cast<const s16x8*>(As + r * 32 + cs * 8);
        int n = wcol + i * 16 + lm;
        int cs2 = q ^ ((n >> 1) & 3);
        pb[i] = reinterpret_cast<const s16x8*>(Bs + n * 32 + cs2 * 8);
    }

    f32x4 acc[4][4];
#pragma unroll
    for (int i = 0; i < 4; ++i)
#pragma unroll
        for (int j = 0; j < 4; ++j) acc[i][j] = (f32x4)0.f;

    for (int k0 = 0; k0 < 128; k0 += 32) {
        async_ld16(pA0 + k0, dA0);
        async_ld16(pA1 + k0, dA1);
        async_ld16(pB0 + k0, dB0);
        async_ld16(pB1 + k0, dB1);
        __syncthreads();

        s16x8 af[4], bf[4];
#pragma unroll
        for (int i = 0; i < 4; ++i) { af[i] = *pa[i]; bf[i] = *pb[i]; }
#pragma unroll
        for (int i = 0; i < 4; ++i)
#pragma unroll
            for (int j = 0; j < 4; ++j)
                acc[i][j] = __builtin_amdgcn_mfma_f32_16x16x32_bf16(af[i], bf[j], acc[i][j], 0, 0, 0);
        __syncthreads();
    }

    // epilogue: finalize emb + fused u-dots
    float bcv[4], bgv[4], w1[4], w2[4];
    int colv[4];
#pragma unroll
    for (int j = 0; j < 4; ++j) {
        int c = col0 + wcol + j * 16 + lm;
        colv[j] = c;
        bcv[j] = bcp[c];
        bgv[j] = bgp[c];
        w1[j] = v1p[c];
        w2[j] = v2p[c];
    }

#pragma unroll
    for (int i = 0; i < 4; ++i) {
        float p1[4], p2[4];
#pragma unroll
        for (int reg = 0; reg < 4; ++reg) {
            int row = row0 + wrow + i * 16 + q * 4 + reg;
            float hb = h[row];
            float sc = nd[row];
            float s1 = 0.f, s2 = 0.f;
#pragma unroll
            for (int j = 0; j < 4; ++j) {
                float o = fmaf(sc, acc[i][j][reg] + hb * bcv[j], bgv[j]);
                if (row < M && colv[j] < D) emb[(long)row * D + colv[j]] = o;
                s1 = fmaf(o, w1[j], s1);
                s2 = fmaf(o, w2[j], s2);
            }
            p1[reg] = s1;
            p2[reg] = s2;
        }
#pragma unroll
        for (int mask = 1; mask < 16; mask <<= 1)
#pragma unroll
            for (int reg = 0; reg < 4; ++reg) {
                p1[reg] += __shfl_xor(p1[reg], mask);
                p2[reg] += __shfl_xor(p2[reg], mask);
            }
        if (lm == 0) {
#pragma unroll
            for (int reg = 0; reg < 4; ++reg) {
                int row = row0 + wrow + i * 16 + q * 4 + reg;
                if (row < M) {
                    atomicAdd(&u1[row], p1[reg]);
                    atomicAdd(&u2[row], p2[reg]);
                }
            }
        }
    }
}

// weights[r] = u1[trip[r,0]] + u2[trip[r,2]] + bias_dot
__global__ void weights_kernel(const int* __restrict__ trip, const float* __restrict__ u1,
                               const float* __restrict__ u2, const float* __restrict__ bdot,
                               float* __restrict__ w, int T) {
    int r = blockIdx.x * blockDim.x + threadIdx.x;
    if (r < T) {
        int s = trip[(long)r * 3 + 0];
        int o = trip[(long)r * 3 + 2];
        w[r] = u1[s] + u2[o] + bdot[0];
    }
}

// ---------------------------------------------------------------------------

extern "C" void kernel_launch(void* const* d_in, const int* in_sizes, int n_in,
                              void* d_out, int out_size, void* d_ws, size_t ws_size,
                              hipStream_t stream) {
    const float* feats      = (const float*)d_in[0];
    const float* W_aff      = (const float*)d_in[1];
    const float* b_aff      = (const float*)d_in[2];
    const float* W_gcn      = (const float*)d_in[3];
    const float* b_gcn      = (const float*)d_in[4];
    const float* W_pred_in  = (const float*)d_in[5];
    const float* b_pred_in  = (const float*)d_in[6];
    const float* W_pred_out = (const float*)d_in[7];
    const float* b_pred_out = (const float*)d_in[8];
    const int*   src        = (const int*)d_in[9];
    const int*   dst        = (const int*)d_in[10];
    const int*   trip       = (const int*)d_in[11];

    const int D = in_sizes[2];           // 500
    const int F = in_sizes[1] / D;       // 128
    const int N = in_sizes[0] / F;       // 50000
    const int E = in_sizes[9];           // 800000
    const int T = in_sizes[11] / 3;      // 200000

    const int PD = 512;
    const int GX = (N + 127) / 128;      // 391 row-blocks
    const int Mpad = GX * 128;           // 50048
    const int NB = (N + 1023) / 1024;    // scan blocks (49)
    const int NC = (D + 7) / 8;          // bcomb split-K chunks (63)

    float* weights = (float*)d_out;          // [T]
    float* emb     = (float*)d_out + T;      // [N*D]

    // workspace layout (16B-aligned chunks first)
    char* p = (char*)d_ws;
    unsigned short* fs16 = (unsigned short*)p;  p += (size_t)N * 128 * 2;        // 12.8 MB
    unsigned short* g16  = (unsigned short*)p;  p += (size_t)Mpad * 128 * 2;     // 12.8 MB
    unsigned short* Bt   = (unsigned short*)p;  p += (size_t)PD * 128 * 2;       // 128 KB
    float* Wc   = (float*)p;  p += (size_t)F * D * 4;                            // 256 KB
    float* bparts = (float*)p;  p += (size_t)64 * PD * 4;                        // 128 KB
    float* bcp  = (float*)p;  p += PD * 4;
    float* bgp  = (float*)p;  p += PD * 4;
    float* v1p  = (float*)p;  p += PD * 4;
    float* v2p  = (float*)p;  p += PD * 4;
    float* v    = (float*)p;  p += 1024 * 4;
    float* bdot = (float*)p;  p += 16;
    float* ns   = (float*)p;  p += (size_t)N * 4;
    float* nd   = (float*)p;  p += (size_t)N * 4;
    float* h    = (float*)p;  p += (size_t)Mpad * 4;
    float* u1   = (float*)p;  p += (size_t)N * 4;
    float* u2   = (float*)p;  p += (size_t)N * 4;
    unsigned* outd = (unsigned*)p;  p += (size_t)N * 4;
    unsigned* ind  = (unsigned*)p;  p += (size_t)N * 4;
    int* row_ptr = (int*)p;  p += (size_t)(N + 1) * 4;
    int* cursor  = (int*)p;  p += (size_t)N * 4;
    int* csr_src = (int*)p;  p += (size_t)E * 4;
    int* partials = (int*)p; p += 1024 * 4;

    // zero: degree counters, u-accumulators, g16/h pad rows (deterministic OOB rows)
    hipMemsetAsync(outd, 0, 2 * (size_t)N * sizeof(unsigned), stream);
    hipMemsetAsync(u1, 0, 2 * (size_t)N * sizeof(float), stream);
    hipMemsetAsync(g16 + (size_t)N * 128, 0, (size_t)(Mpad - N) * 128 * 2, stream);
    hipMemsetAsync(h + N, 0, (size_t)(Mpad - N) * 4, stream);

    // degrees + fused norm/scan + CSR build
    degree_kernel<<<(E + 255) / 256, 256, 0, stream>>>(src, dst, outd, ind, E);
    scan_part1<<<NB, 256, 0, stream>>>(outd, ind, ns, nd, partials, N);
    scan_part2<<<1, 64, 0, stream>>>(partials, row_ptr, NB, N);
    scan_part3<<<NB, 256, 0, stream>>>(ind, partials, row_ptr, cursor, N);
    csr_fill_kernel<<<(E + 255) / 256, 256, 0, stream>>>(src, dst, cursor, csr_src, E);

    // pred linearization + weight prep
    vcomb_kernel<<<(2 * D + 3) / 4, 256, 0, stream>>>(W_pred_in, W_pred_out, v, D, 2 * D);
    bias_dot_kernel<<<1, 256, 0, stream>>>(b_pred_in, W_pred_out, b_pred_out, bdot, D);

    // Wc = W_aff @ W_gcn ; bc partials (split-K) ; pads ; Bt (bf16 transposed Wc)
    {
        dim3 grid((F + 63) / 64, (D + 63) / 64);
        sgemm_kernel<<<grid, 256, 0, stream>>>(W_aff, D, W_gcn, D, Wc, D, F, D, D);
    }
    {
        dim3 grid((PD + 255) / 256, NC);
        bcomb_part_kernel<<<grid, 256, 0, stream>>>(b_aff, W_gcn, bparts, D, PD);
    }
    pad_kernel<<<(PD + 255) / 256, 256, 0, stream>>>(bparts, b_gcn, v, bcp, bgp, v1p, v2p, D, PD, NC);
    conv_Bt_kernel<<<(PD * 16 + 255) / 256, 256, 0, stream>>>(Wc, Bt, D, PD);

    // fs16 = bf16(ns ⊙ feats)
    conv_feats_kernel<<<(N * 16 + 255) / 256, 256, 0, stream>>>(feats, ns, fs16, N);

    // feature-space gather: g16, h
    gather_feats_kernel<<<(N + 3) / 4, 256, 0, stream>>>(fs16, csr_src, row_ptr, ns, g16, h, N);

    // MFMA GEMM: emb (+ fused u1/u2 dots)
    {
        dim3 grid(GX, PD / 128);
        gcn_gemm_kernel<<<grid, 256, 0, stream>>>(g16, Bt, h, nd, bcp, bgp, v1p, v2p,
                                                  emb, u1, u2, N, D);
    }

    // weights from per-node scalars
    weights_kernel<<<(T + 255) / 256, 256, 0, stream>>>(trip, u1, u2, bdot, weights, T);
}

// Round 3
// 397.778 us; speedup vs baseline: 1.6678x; 1.1088x over previous
//
#include <hip/hip_runtime.h>

// ---------------------------------------------------------------------------
// Algebra: emb = nd ⊙ (Â (ns ⊙ (feats@Wc + bc))) + b_gcn
//        = nd ⊙ ( g@Wc + h·bcᵀ ) + b_gcn     with g = Â(ns⊙feats), h = Â ns
// (Â = adjacency-by-dst incl. self loops; Wc = W_aff@W_gcn, bc = b_aff@W_gcn)
// Gather is done in F=128 feature space (4x less traffic than D=500 space).
// pred MLP is linear => weights[r] = emb[s]·v1 + emb[o]·v2 + bias_dot,
// v = W_pred_in @ W_pred_out; u-dots fused into the MFMA GEMM epilogue.
//
// R1: 3-phase multi-block scan (+norm fusion). 663→543 (pred −120, got −120).
// R2: bcomb split-K. 543→441 (pred ~420).
// R3: device atomics cost 32B fabric transactions @~24G/s (degree WRITE_SIZE
// 50MB = 1.6M×32B). Replace ind-histogram + scan + csr_fill atomics with a
// bucket partition (dst>>8): LDS counting sorts, coalesced run writes, LDS
// cursors. outd histogram atomics kept (halved atomic count). Pred ~360 µs.
// ---------------------------------------------------------------------------

typedef float f32x4 __attribute__((ext_vector_type(4)));
typedef short s16x8 __attribute__((ext_vector_type(8)));

__device__ __forceinline__ unsigned short f2bf(float f) {
    unsigned u = __float_as_uint(f);
    unsigned r = (u + 0x7FFFu + ((u >> 16) & 1u)) >> 16;
    return (unsigned short)r;
}

__device__ __forceinline__ void async_ld16(const void* g, void* lds) {
    __builtin_amdgcn_global_load_lds(
        (const __attribute__((address_space(1))) unsigned int*)g,
        (__attribute__((address_space(3))) unsigned int*)lds,
        16, 0, 0);
}

// ---------------------------------------------------------------------------
// Pass 1: outd histogram (global atomics, unavoidable) + dst-bucket histogram
// (LDS-aggregated; bucket = dst>>8, <=256 buckets).
// ---------------------------------------------------------------------------
__global__ __launch_bounds__(256) void deg_bucket_kernel(
    const int* __restrict__ src, const int* __restrict__ dst,
    unsigned* __restrict__ outd, int* __restrict__ bhist, int E) {
    __shared__ int lh[256];
    lh[threadIdx.x] = 0;
    __syncthreads();
    const int stride = gridDim.x * blockDim.x;
    for (int e = blockIdx.x * blockDim.x + threadIdx.x; e < E; e += stride) {
        atomicAdd(&outd[src[e]], 1u);
        atomicAdd(&lh[dst[e] >> 8], 1);
    }
    __syncthreads();
    int c = lh[threadIdx.x];
    if (c > 0) atomicAdd(&bhist[threadIdx.x], c);
}

// Exclusive scan of bhist[0..nbuk) -> bbase[0..nbuk], copy to bcursor. 1 block.
__global__ void bscan_kernel(const int* __restrict__ bhist, int* __restrict__ bbase,
                             int* __restrict__ bcursor, int nbuk, int E) {
    __shared__ int scanv[256];
    const int tid = threadIdx.x;
    int c = (tid < nbuk) ? bhist[tid] : 0;
    scanv[tid] = c;
    __syncthreads();
    for (int st = 1; st < 256; st <<= 1) {
        int t = (tid >= st) ? scanv[tid - st] : 0;
        __syncthreads();
        scanv[tid] += t;
        __syncthreads();
    }
    int excl = scanv[tid] - c;
    if (tid < nbuk) { bbase[tid] = excl; bcursor[tid] = excl; }
    if (tid == 0) bbase[nbuk] = E;
}

// ns[i] = rsqrt(outd[i]+1)
__global__ void ns_kernel(const unsigned* __restrict__ outd, float* __restrict__ ns, int N) {
    int i = blockIdx.x * blockDim.x + threadIdx.x;
    if (i < N) ns[i] = rsqrtf((float)(outd[i] + 1u));
}

// ---------------------------------------------------------------------------
// Partition (dst,src) pairs by dst-bucket. Per block: LDS counting sort of a
// 4096-edge chunk, one global cursor reservation per touched bucket, then
// coalesced run writes (avg run ~21 pairs = 168B contiguous).
// ---------------------------------------------------------------------------
#define PCH 4096
__global__ __launch_bounds__(256) void partition_kernel(
    const int* __restrict__ src, const int* __restrict__ dst,
    int* __restrict__ bcursor, unsigned long long* __restrict__ pairs,
    int E, int nbuk) {
    __shared__ int lhist[256];
    __shared__ int lbase[256];
    __shared__ int gbase[256];
    __shared__ int scanv[256];
    __shared__ unsigned long long lpair[PCH];
    __shared__ unsigned char lbid[PCH];

    const int tid = threadIdx.x;
    const int c0 = blockIdx.x * PCH;
    int cnt = E - c0; if (cnt > PCH) cnt = PCH;

    lhist[tid] = 0;
    __syncthreads();

    int dv[16], sv[16], rk[16];
#pragma unroll
    for (int q = 0; q < 16; ++q) {
        int e = c0 + q * 256 + tid;
        if (e < E) {
            int d = dst[e];
            dv[q] = d;
            sv[q] = src[e];
            rk[q] = atomicAdd(&lhist[d >> 8], 1);
        } else {
            dv[q] = -1;
        }
    }
    __syncthreads();

    int c = lhist[tid];
    scanv[tid] = c;
    __syncthreads();
    for (int st = 1; st < 256; st <<= 1) {
        int t = (tid >= st) ? scanv[tid - st] : 0;
        __syncthreads();
        scanv[tid] += t;
        __syncthreads();
    }
    lbase[tid] = scanv[tid] - c;
    if (tid < nbuk && c > 0) gbase[tid] = atomicAdd(&bcursor[tid], c);
    __syncthreads();

#pragma unroll
    for (int q = 0; q < 16; ++q) {
        if (dv[q] >= 0) {
            int b = dv[q] >> 8;
            int slot = lbase[b] + rk[q];
            lpair[slot] = ((unsigned long long)(unsigned)dv[q] << 32) | (unsigned)sv[q];
            lbid[slot] = (unsigned char)b;
        }
    }
    __syncthreads();

    for (int i = tid; i < cnt; i += 256) {
        int b = lbid[i];
        pairs[(long)gbase[b] + (i - lbase[b])] = lpair[i];
    }
}

// ---------------------------------------------------------------------------
// Per-bucket CSR build: block b owns nodes [b*256, b*256+256) and edge range
// [bbase[b], bbase[b+1]). LDS histogram -> row_ptr + nd, LDS cursors -> scatter
// csr_src into the bucket's contiguous region (16KB locality).
// ---------------------------------------------------------------------------
__global__ __launch_bounds__(256) void bucket_csr_kernel(
    const unsigned long long* __restrict__ pairs, const int* __restrict__ bbase,
    int* __restrict__ row_ptr, float* __restrict__ ndv,
    int* __restrict__ csr_src, int N) {
    __shared__ int hist[256];
    __shared__ int scanv[256];
    __shared__ int lcur[256];
    const int tid = threadIdx.x;
    const int b = blockIdx.x;
    const int e0 = bbase[b], e1 = bbase[b + 1];

    hist[tid] = 0;
    __syncthreads();
    for (int e = e0 + tid; e < e1; e += 256) {
        int d = (int)(pairs[e] >> 32);
        atomicAdd(&hist[d & 255], 1);
    }
    __syncthreads();

    int c = hist[tid];
    scanv[tid] = c;
    __syncthreads();
    for (int st = 1; st < 256; st <<= 1) {
        int t = (tid >= st) ? scanv[tid - st] : 0;
        __syncthreads();
        scanv[tid] += t;
        __syncthreads();
    }
    int excl = scanv[tid] - c;
    int node = b * 256 + tid;
    if (node < N) {
        row_ptr[node] = e0 + excl;
        ndv[node] = rsqrtf((float)(c + 1));
    }
    if (node == N) row_ptr[N] = e0 + excl;
    lcur[tid] = excl;
    __syncthreads();

    for (int e = e0 + tid; e < e1; e += 256) {
        unsigned long long pr = pairs[e];
        int d = (int)(pr >> 32);
        int r = atomicAdd(&lcur[d & 255], 1);
        csr_src[e0 + r] = (int)(pr & 0xFFFFFFFFu);
    }
}

// Split-K partials for bc[n] = sum_k b_aff[k] * W_gcn[k*D + n]
__global__ __launch_bounds__(256) void bcomb_part_kernel(
    const float* __restrict__ b_aff, const float* __restrict__ W_gcn,
    float* __restrict__ part, int D, int PD) {
    int n = blockIdx.x * blockDim.x + threadIdx.x;
    int c = blockIdx.y;
    if (n >= PD) return;
    float s = 0.f;
    if (n < D) {
        int k0 = c * 8;
        int k1 = k0 + 8; if (k1 > D) k1 = D;
        for (int k = k0; k < k1; ++k) s = fmaf(b_aff[k], W_gcn[(long)k * D + n], s);
    }
    part[(long)c * PD + n] = s;
}

// v[k] = sum_c W_pred_in[k*D + c] * w_out[c]   (one wave per row k, k < 2D)
__global__ void vcomb_kernel(const float* __restrict__ Win, const float* __restrict__ wout,
                             float* __restrict__ v, int D, int K2) {
    int k = blockIdx.x * (blockDim.x >> 6) + (threadIdx.x >> 6);
    int lane = threadIdx.x & 63;
    if (k >= K2) return;
    float s = 0.f;
    for (int c = lane; c < D; c += 64) s = fmaf(Win[(long)k * D + c], wout[c], s);
#pragma unroll
    for (int m = 32; m > 0; m >>= 1) s += __shfl_down(s, m);
    if (lane == 0) v[k] = s;
}

// bias_dot = b_pred_out + sum_c b_pred_in[c]*w_out[c]
__global__ void bias_dot_kernel(const float* __restrict__ b_in, const float* __restrict__ w_out,
                                const float* __restrict__ b_out, float* __restrict__ bias_dot, int D) {
    __shared__ float sm[256];
    float s = 0.f;
    for (int c = threadIdx.x; c < D; c += 256) s = fmaf(b_in[c], w_out[c], s);
    sm[threadIdx.x] = s;
    __syncthreads();
    for (int st = 128; st > 0; st >>= 1) {
        if (threadIdx.x < st) sm[threadIdx.x] += sm[threadIdx.x + st];
        __syncthreads();
    }
    if (threadIdx.x == 0) bias_dot[0] = sm[0] + b_out[0];
}

// Zero-pad small vectors to PD=512: bcp (reduced from split-K partials), bgp, v1p, v2p
__global__ void pad_kernel(const float* __restrict__ part, const float* __restrict__ b_gcn,
                           const float* __restrict__ v, float* __restrict__ bcp,
                           float* __restrict__ bgp, float* __restrict__ v1p,
                           float* __restrict__ v2p, int D, int PD, int NC) {
    int i = blockIdx.x * blockDim.x + threadIdx.x;
    if (i < PD) {
        float s = 0.f;
        for (int c = 0; c < NC; ++c) s += part[(long)c * PD + i];
        bcp[i] = s;                       // pad cols already 0 in part
        bgp[i] = (i < D) ? b_gcn[i] : 0.f;
        v1p[i] = (i < D) ? v[i] : 0.f;
        v2p[i] = (i < D) ? v[D + i] : 0.f;
    }
}

// ---------------------------------------------------------------------------
// fp32 tiled GEMM (only used for the tiny Wc = W_aff @ W_gcn)
// ---------------------------------------------------------------------------
__global__ __launch_bounds__(256) void sgemm_kernel(const float* __restrict__ A, int lda,
                                                    const float* __restrict__ B, int ldb,
                                                    float* __restrict__ C, int ldc,
                                                    int M, int N, int K) {
    __shared__ __align__(16) float As[16][68];
    __shared__ __align__(16) float Bs[16][68];
    const int tid = threadIdx.x;
    const int tx = tid & 15, ty = tid >> 4;
    const int row0 = blockIdx.x * 64;
    const int col0 = blockIdx.y * 64;

    const int a_row = tid >> 2;
    const int a_k   = (tid & 3) * 4;
    const int b_k   = tid >> 4;
    const int b_c   = (tid & 15) * 4;

    float acc[4][4] = {};

    for (int k0 = 0; k0 < K; k0 += 16) {
        float4 av = make_float4(0.f, 0.f, 0.f, 0.f);
        {
            int gr = row0 + a_row;
            int gk = k0 + a_k;
            if (gr < M) {
                if (gk + 3 < K) {
                    av = *reinterpret_cast<const float4*>(&A[(long)gr * lda + gk]);
                } else {
                    float t0 = (gk + 0 < K) ? A[(long)gr * lda + gk + 0] : 0.f;
                    float t1 = (gk + 1 < K) ? A[(long)gr * lda + gk + 1] : 0.f;
                    float t2 = (gk + 2 < K) ? A[(long)gr * lda + gk + 2] : 0.f;
                    float t3 = (gk + 3 < K) ? A[(long)gr * lda + gk + 3] : 0.f;
                    av = make_float4(t0, t1, t2, t3);
                }
            }
        }
        float4 bv = make_float4(0.f, 0.f, 0.f, 0.f);
        {
            int gk = k0 + b_k;
            int gc = col0 + b_c;
            if (gk < K) {
                if (gc + 3 < N) {
                    bv = *reinterpret_cast<const float4*>(&B[(long)gk * ldb + gc]);
                } else {
                    float t0 = (gc + 0 < N) ? B[(long)gk * ldb + gc + 0] : 0.f;
                    float t1 = (gc + 1 < N) ? B[(long)gk * ldb + gc + 1] : 0.f;
                    float t2 = (gc + 2 < N) ? B[(long)gk * ldb + gc + 2] : 0.f;
                    float t3 = (gc + 3 < N) ? B[(long)gk * ldb + gc + 3] : 0.f;
                    bv = make_float4(t0, t1, t2, t3);
                }
            }
        }
        __syncthreads();
        As[a_k + 0][a_row] = av.x;
        As[a_k + 1][a_row] = av.y;
        As[a_k + 2][a_row] = av.z;
        As[a_k + 3][a_row] = av.w;
        *reinterpret_cast<float4*>(&Bs[b_k][b_c]) = bv;
        __syncthreads();

#pragma unroll
        for (int k = 0; k < 16; ++k) {
            const float4 a = *reinterpret_cast<const float4*>(&As[k][ty * 4]);
            const float4 b = *reinterpret_cast<const float4*>(&Bs[k][tx * 4]);
            const float avv[4] = {a.x, a.y, a.z, a.w};
            const float bvv[4] = {b.x, b.y, b.z, b.w};
#pragma unroll
            for (int i = 0; i < 4; ++i)
#pragma unroll
                for (int j = 0; j < 4; ++j)
                    acc[i][j] = fmaf(avv[i], bvv[j], acc[i][j]);
        }
    }

#pragma unroll
    for (int i = 0; i < 4; ++i) {
        int r = row0 + ty * 4 + i;
        if (r >= M) continue;
#pragma unroll
        for (int j = 0; j < 4; ++j) {
            int c = col0 + tx * 4 + j;
            if (c < N) C[(long)r * ldc + c] = acc[i][j];
        }
    }
}

// fs16[s][c] = bf16(feats[s][c] * ns[s])   (F = 128)
__global__ void conv_feats_kernel(const float* __restrict__ feats, const float* __restrict__ ns,
                                  unsigned short* __restrict__ fs16, int N) {
    int idx = blockIdx.x * blockDim.x + threadIdx.x;
    if (idx >= N * 16) return;
    int node = idx >> 4;
    int c = (idx & 15) * 8;
    float s = ns[node];
    const float* p = feats + (long)node * 128 + c;
    float4 a = *reinterpret_cast<const float4*>(p);
    float4 b = *reinterpret_cast<const float4*>(p + 4);
    uint4 o;
    o.x = (unsigned)f2bf(a.x * s) | ((unsigned)f2bf(a.y * s) << 16);
    o.y = (unsigned)f2bf(a.z * s) | ((unsigned)f2bf(a.w * s) << 16);
    o.z = (unsigned)f2bf(b.x * s) | ((unsigned)f2bf(b.y * s) << 16);
    o.w = (unsigned)f2bf(b.z * s) | ((unsigned)f2bf(b.w * s) << 16);
    *reinterpret_cast<uint4*>(fs16 + (long)node * 128 + c) = o;
}

// Wc [128][D] fp32 -> Bt [PD=512 rows n][128 k] bf16 (transposed, pad rows zero)
__global__ void conv_Bt_kernel(const float* __restrict__ Wc, unsigned short* __restrict__ Bt,
                               int D, int PD) {
    int idx = blockIdx.x * blockDim.x + threadIdx.x;   // PD*16 threads
    if (idx >= PD * 16) return;
    int n = idx >> 4;
    int k8 = (idx & 15) * 8;
    uint4 o = make_uint4(0, 0, 0, 0);
    if (n < D) {
        unsigned short t[8];
#pragma unroll
        for (int q = 0; q < 8; ++q) t[q] = f2bf(Wc[(long)(k8 + q) * D + n]);
        o.x = (unsigned)t[0] | ((unsigned)t[1] << 16);
        o.y = (unsigned)t[2] | ((unsigned)t[3] << 16);
        o.z = (unsigned)t[4] | ((unsigned)t[5] << 16);
        o.w = (unsigned)t[6] | ((unsigned)t[7] << 16);
    }
    *reinterpret_cast<uint4*>(Bt + (long)n * 128 + k8) = o;
}

// ---------------------------------------------------------------------------
// Feature-space CSR gather, wave per node:
//   g16[d] = bf16( Σ_{s∈in(d)} fs16[s] + fs16[d] )   (fp32 accum)
//   h[d]   = Σ ns[s] + ns[d]
// ---------------------------------------------------------------------------
__global__ __launch_bounds__(256) void gather_feats_kernel(
    const unsigned short* __restrict__ fs16, const int* __restrict__ csr_src,
    const int* __restrict__ row_ptr, const float* __restrict__ ns,
    unsigned short* __restrict__ g16, float* __restrict__ h, int N) {
    int d = blockIdx.x * 4 + (threadIdx.x >> 6);
    int lane = threadIdx.x & 63;
    if (d >= N) return;

    // self loop init
    unsigned su = *reinterpret_cast<const unsigned*>(fs16 + (long)d * 128 + lane * 2);
    float a0 = __uint_as_float(su << 16);
    float a1 = __uint_as_float(su & 0xFFFF0000u);
    float hacc = 0.f;

    const int beg = row_ptr[d], end = row_ptr[d + 1];
    for (int j0 = beg; j0 < end; j0 += 64) {
        int cnt = end - j0;
        if (cnt > 64) cnt = 64;
        int s = (lane < cnt) ? csr_src[j0 + lane] : 0;
        if (lane < cnt) hacc += ns[s];
        for (int k = 0; k < cnt; ++k) {
            int sk = __shfl(s, k);
            unsigned v = *reinterpret_cast<const unsigned*>(fs16 + (long)sk * 128 + lane * 2);
            a0 += __uint_as_float(v << 16);
            a1 += __uint_as_float(v & 0xFFFF0000u);
        }
    }
#pragma unroll
    for (int m = 32; m > 0; m >>= 1) hacc += __shfl_xor(hacc, m);
    if (lane == 0) h[d] = hacc + ns[d];
    unsigned o = (unsigned)f2bf(a0) | ((unsigned)f2bf(a1) << 16);
    *reinterpret_cast<unsigned*>(g16 + (long)d * 128 + lane * 2) = o;
}

// ---------------------------------------------------------------------------
// MFMA GEMM: emb[r][c] = nd[r]*( (g16@Wc)[r][c] + h[r]*bcp[c] ) + bgp[c]
// fused epilogue dots: u1[r] += Σ_c emb·v1p, u2[r] += Σ_c emb·v2p
// ---------------------------------------------------------------------------
__global__ __launch_bounds__(256) void gcn_gemm_kernel(
    const unsigned short* __restrict__ g16, const unsigned short* __restrict__ Bt,
    const float* __restrict__ h, const float* __restrict__ nd,
    const float* __restrict__ bcp, const float* __restrict__ bgp,
    const float* __restrict__ v1p, const float* __restrict__ v2p,
    float* __restrict__ emb, float* __restrict__ u1, float* __restrict__ u2,
    int M, int D) {

    __shared__ __align__(16) unsigned short As[128 * 32];
    __shared__ __align__(16) unsigned short Bs[128 * 32];

    const int tid  = threadIdx.x;
    const int w    = tid >> 6;
    const int lane = tid & 63;
    const int row0 = blockIdx.x * 128;
    const int col0 = blockIdx.y * 128;

    const int r0   = 2 * w * 16 + (lane >> 2);
    const int r1   = (2 * w + 1) * 16 + (lane >> 2);
    const int slot = lane & 3;
    const int c0   = slot ^ ((r0 >> 1) & 3);
    const int c1   = slot ^ ((r1 >> 1) & 3);

    const unsigned short* pA0 = g16 + (long)(row0 + r0) * 128 + c0 * 8;
    const unsigned short* pA1 = g16 + (long)(row0 + r1) * 128 + c1 * 8;
    const unsigned short* pB0 = Bt + (long)(col0 + r0) * 128 + c0 * 8;
    const unsigned short* pB1 = Bt + (long)(col0 + r1) * 128 + c1 * 8;

    unsigned short* dA0 = As + 2 * w * 512;
    unsigned short* dA1 = As + (2 * w + 1) * 512;
    unsigned short* dB0 = Bs + 2 * w * 512;
    unsigned short* dB1 = Bs + (2 * w + 1) * 512;

    const int wrow = (w & 1) * 64;
    const int wcol = (w >> 1) * 64;
    const int lm = lane & 15, q = lane >> 4;
    const s16x8* pa[4];
    const s16x8* pb[4];
#pragma unroll
    for (int i = 0; i < 4; ++i) {
        int r = wrow + i * 16 + lm;
        int cs = q ^ ((r >> 1) & 3);
        pa[i] = reinterpret_cast<const s16x8*>(As + r * 32 + cs * 8);
        int n = wcol + i * 16 + lm;
        int cs2 = q ^ ((n >> 1) & 3);
        pb[i] = reinterpret_cast<const s16x8*>(Bs + n * 32 + cs2 * 8);
    }

    f32x4 acc[4][4];
#pragma unroll
    for (int i = 0; i < 4; ++i)
#pragma unroll
        for (int j = 0; j < 4; ++j) acc[i][j] = (f32x4)0.f;

    for (int k0 = 0; k0 < 128; k0 += 32) {
        async_ld16(pA0 + k0, dA0);
        async_ld16(pA1 + k0, dA1);
        async_ld16(pB0 + k0, dB0);
        async_ld16(pB1 + k0, dB1);
        __syncthreads();

        s16x8 af[4], bf[4];
#pragma unroll
        for (int i = 0; i < 4; ++i) { af[i] = *pa[i]; bf[i] = *pb[i]; }
#pragma unroll
        for (int i = 0; i < 4; ++i)
#pragma unroll
            for (int j = 0; j < 4; ++j)
                acc[i][j] = __builtin_amdgcn_mfma_f32_16x16x32_bf16(af[i], bf[j], acc[i][j], 0, 0, 0);
        __syncthreads();
    }

    // epilogue: finalize emb + fused u-dots
    float bcv[4], bgv[4], w1[4], w2[4];
    int colv[4];
#pragma unroll
    for (int j = 0; j < 4; ++j) {
        int c = col0 + wcol + j * 16 + lm;
        colv[j] = c;
        bcv[j] = bcp[c];
        bgv[j] = bgp[c];
        w1[j] = v1p[c];
        w2[j] = v2p[c];
    }

#pragma unroll
    for (int i = 0; i < 4; ++i) {
        float p1[4], p2[4];
#pragma unroll
        for (int reg = 0; reg < 4; ++reg) {
            int row = row0 + wrow + i * 16 + q * 4 + reg;
            float hb = h[row];
            float sc = nd[row];
            float s1 = 0.f, s2 = 0.f;
#pragma unroll
            for (int j = 0; j < 4; ++j) {
                float o = fmaf(sc, acc[i][j][reg] + hb * bcv[j], bgv[j]);
                if (row < M && colv[j] < D) emb[(long)row * D + colv[j]] = o;
                s1 = fmaf(o, w1[j], s1);
                s2 = fmaf(o, w2[j], s2);
            }
            p1[reg] = s1;
            p2[reg] = s2;
        }
#pragma unroll
        for (int mask = 1; mask < 16; mask <<= 1)
#pragma unroll
            for (int reg = 0; reg < 4; ++reg) {
                p1[reg] += __shfl_xor(p1[reg], mask);
                p2[reg] += __shfl_xor(p2[reg], mask);
            }
        if (lm == 0) {
#pragma unroll
            for (int reg = 0; reg < 4; ++reg) {
                int row = row0 + wrow + i * 16 + q * 4 + reg;
                if (row < M) {
                    atomicAdd(&u1[row], p1[reg]);
                    atomicAdd(&u2[row], p2[reg]);
                }
            }
        }
    }
}

// weights[r] = u1[trip[r,0]] + u2[trip[r,2]] + bias_dot
__global__ void weights_kernel(const int* __restrict__ trip, const float* __restrict__ u1,
                               const float* __restrict__ u2, const float* __restrict__ bdot,
                               float* __restrict__ w, int T) {
    int r = blockIdx.x * blockDim.x + threadIdx.x;
    if (r < T) {
        int s = trip[(long)r * 3 + 0];
        int o = trip[(long)r * 3 + 2];
        w[r] = u1[s] + u2[o] + bdot[0];
    }
}

// ---------------------------------------------------------------------------

extern "C" void kernel_launch(void* const* d_in, const int* in_sizes, int n_in,
                              void* d_out, int out_size, void* d_ws, size_t ws_size,
                              hipStream_t stream) {
    const float* feats      = (const float*)d_in[0];
    const float* W_aff      = (const float*)d_in[1];
    const float* b_aff      = (const float*)d_in[2];
    const float* W_gcn      = (const float*)d_in[3];
    const float* b_gcn      = (const float*)d_in[4];
    const float* W_pred_in  = (const float*)d_in[5];
    const float* b_pred_in  = (const float*)d_in[6];
    const float* W_pred_out = (const float*)d_in[7];
    const float* b_pred_out = (const float*)d_in[8];
    const int*   src        = (const int*)d_in[9];
    const int*   dst        = (const int*)d_in[10];
    const int*   trip       = (const int*)d_in[11];

    const int D = in_sizes[2];           // 500
    const int F = in_sizes[1] / D;       // 128
    const int N = in_sizes[0] / F;       // 50000
    const int E = in_sizes[9];           // 800000
    const int T = in_sizes[11] / 3;      // 200000

    const int PD = 512;
    const int GX = (N + 127) / 128;      // 391 row-blocks
    const int Mpad = GX * 128;           // 50048
    const int NC = (D + 7) / 8;          // bcomb split-K chunks (63)
    const int NBUK = (N >> 8) + 1;       // 196 dst-buckets of 256 nodes

    float* weights = (float*)d_out;          // [T]
    float* emb     = (float*)d_out + T;      // [N*D]

    // workspace layout (16B-aligned chunks first)
    char* p = (char*)d_ws;
    unsigned short* fs16 = (unsigned short*)p;  p += (size_t)N * 128 * 2;        // 12.8 MB
    unsigned short* g16  = (unsigned short*)p;  p += (size_t)Mpad * 128 * 2;     // 12.8 MB
    unsigned long long* pairs = (unsigned long long*)p; p += (size_t)E * 8;      // 6.4 MB
    unsigned short* Bt   = (unsigned short*)p;  p += (size_t)PD * 128 * 2;       // 128 KB
    float* Wc   = (float*)p;  p += (size_t)F * D * 4;                            // 256 KB
    float* bparts = (float*)p;  p += (size_t)64 * PD * 4;                        // 128 KB
    float* bcp  = (float*)p;  p += PD * 4;
    float* bgp  = (float*)p;  p += PD * 4;
    float* v1p  = (float*)p;  p += PD * 4;
    float* v2p  = (float*)p;  p += PD * 4;
    float* v    = (float*)p;  p += 1024 * 4;
    float* bdot = (float*)p;  p += 16;
    float* ns   = (float*)p;  p += (size_t)N * 4;
    float* nd   = (float*)p;  p += (size_t)N * 4;
    float* h    = (float*)p;  p += (size_t)Mpad * 4;
    float* u1   = (float*)p;  p += (size_t)N * 4;
    float* u2   = (float*)p;  p += (size_t)N * 4;
    unsigned* outd = (unsigned*)p;  p += (size_t)N * 4;
    int* bhist   = (int*)p;  p += 256 * 4;       // adjacent to outd: one memset
    int* bbase   = (int*)p;  p += 264 * 4;
    int* bcursor = (int*)p;  p += 256 * 4;
    int* row_ptr = (int*)p;  p += (size_t)(N + 1) * 4;
    int* csr_src = (int*)p;  p += (size_t)E * 4;

    // zero: outd+bhist, u-accumulators, g16/h pad rows (deterministic OOB rows)
    hipMemsetAsync(outd, 0, (size_t)N * 4 + 256 * 4, stream);
    hipMemsetAsync(u1, 0, 2 * (size_t)N * sizeof(float), stream);
    hipMemsetAsync(g16 + (size_t)N * 128, 0, (size_t)(Mpad - N) * 128 * 2, stream);
    hipMemsetAsync(h + N, 0, (size_t)(Mpad - N) * 4, stream);

    // degrees (outd atomics + bucket histogram), bucket scan, norms, partition, CSR
    deg_bucket_kernel<<<512, 256, 0, stream>>>(src, dst, outd, bhist, E);
    bscan_kernel<<<1, 256, 0, stream>>>(bhist, bbase, bcursor, NBUK, E);
    ns_kernel<<<(N + 255) / 256, 256, 0, stream>>>(outd, ns, N);
    partition_kernel<<<(E + PCH - 1) / PCH, 256, 0, stream>>>(src, dst, bcursor, pairs, E, NBUK);
    bucket_csr_kernel<<<NBUK, 256, 0, stream>>>(pairs, bbase, row_ptr, nd, csr_src, N);

    // pred linearization + weight prep
    vcomb_kernel<<<(2 * D + 3) / 4, 256, 0, stream>>>(W_pred_in, W_pred_out, v, D, 2 * D);
    bias_dot_kernel<<<1, 256, 0, stream>>>(b_pred_in, W_pred_out, b_pred_out, bdot, D);

    // Wc = W_aff @ W_gcn ; bc partials (split-K) ; pads ; Bt (bf16 transposed Wc)
    {
        dim3 grid((F + 63) / 64, (D + 63) / 64);
        sgemm_kernel<<<grid, 256, 0, stream>>>(W_aff, D, W_gcn, D, Wc, D, F, D, D);
    }
    {
        dim3 grid((PD + 255) / 256, NC);
        bcomb_part_kernel<<<grid, 256, 0, stream>>>(b_aff, W_gcn, bparts, D, PD);
    }
    pad_kernel<<<(PD + 255) / 256, 256, 0, stream>>>(bparts, b_gcn, v, bcp, bgp, v1p, v2p, D, PD, NC);
    conv_Bt_kernel<<<(PD * 16 + 255) / 256, 256, 0, stream>>>(Wc, Bt, D, PD);

    // fs16 = bf16(ns ⊙ feats)
    conv_feats_kernel<<<(N * 16 + 255) / 256, 256, 0, stream>>>(feats, ns, fs16, N);

    // feature-space gather: g16, h
    gather_feats_kernel<<<(N + 3) / 4, 256, 0, stream>>>(fs16, csr_src, row_ptr, ns, g16, h, N);

    // MFMA GEMM: emb (+ fused u1/u2 dots)
    {
        dim3 grid(GX, PD / 128);
        gcn_gemm_kernel<<<grid, 256, 0, stream>>>(g16, Bt, h, nd, bcp, bgp, v1p, v2p,
                                                  emb, u1, u2, N, D);
    }

    // weights from per-node scalars
    weights_kernel<<<(T + 255) / 256, 256, 0, stream>>>(trip, u1, u2, bdot, weights, T);
}

// Round 4
// 365.412 us; speedup vs baseline: 1.8156x; 1.0886x over previous
//
#include <hip/hip_runtime.h>

// ---------------------------------------------------------------------------
// Algebra: emb = nd ⊙ (Â (ns ⊙ (feats@Wc + bc))) + b_gcn
//        = nd ⊙ ( g@Wc + h·bcᵀ ) + b_gcn     with g = Â(ns⊙feats), h = Â ns
// (Â = adjacency-by-dst incl. self loops; Wc = W_aff@W_gcn, bc = b_aff@W_gcn)
// Gather is done in F=128 feature space (4x less traffic than D=500 space).
// pred MLP is linear => weights[r] = emb[s]·v1 + emb[o]·v2 + bias_dot,
// v = W_pred_in @ W_pred_out; u-dots fused into the MFMA GEMM epilogue.
//
// R1: multi-block scan (+norm fusion). 663→543 (pred −120, got −120).
// R2: bcomb split-K. 543→441 (pred ~420).
// R3: bucket-partition CSR build (no per-edge csr atomics). 441→398 (pred 360).
// R4: (a) gather inner loop unroll-4 -> 4 outstanding L3 loads per wave
// (was 1, latency-bound: 60 µs @ 20% HBM, VALU 28%); (b) outd via src-bucket
// partition + LDS histogram -> zero per-edge global atomics anywhere.
// Pred ~330 µs (gather 60→~32, deg 34→~10).
// ---------------------------------------------------------------------------

typedef float f32x4 __attribute__((ext_vector_type(4)));
typedef short s16x8 __attribute__((ext_vector_type(8)));

__device__ __forceinline__ unsigned short f2bf(float f) {
    unsigned u = __float_as_uint(f);
    unsigned r = (u + 0x7FFFu + ((u >> 16) & 1u)) >> 16;
    return (unsigned short)r;
}

__device__ __forceinline__ void async_ld16(const void* g, void* lds) {
    __builtin_amdgcn_global_load_lds(
        (const __attribute__((address_space(1))) unsigned int*)g,
        (__attribute__((address_space(3))) unsigned int*)lds,
        16, 0, 0);
}

// ---------------------------------------------------------------------------
// Bucket histograms of src>>8 and dst>>8 (LDS-aggregated, per-block flush).
// ---------------------------------------------------------------------------
__global__ __launch_bounds__(256) void hist2_kernel(
    const int* __restrict__ src, const int* __restrict__ dst,
    int* __restrict__ bhist_src, int* __restrict__ bhist_dst, int E) {
    __shared__ int lhs[256], lhd[256];
    lhs[threadIdx.x] = 0;
    lhd[threadIdx.x] = 0;
    __syncthreads();
    const int stride = gridDim.x * blockDim.x;
    for (int e = blockIdx.x * blockDim.x + threadIdx.x; e < E; e += stride) {
        atomicAdd(&lhs[src[e] >> 8], 1);
        atomicAdd(&lhd[dst[e] >> 8], 1);
    }
    __syncthreads();
    int cs = lhs[threadIdx.x], cd = lhd[threadIdx.x];
    if (cs > 0) atomicAdd(&bhist_src[threadIdx.x], cs);
    if (cd > 0) atomicAdd(&bhist_dst[threadIdx.x], cd);
}

// Exclusive scans of both bucket histograms -> bases + cursors. 1 block.
__global__ void bscan2_kernel(const int* __restrict__ bhist_src, const int* __restrict__ bhist_dst,
                              int* __restrict__ sbbase, int* __restrict__ sbcursor,
                              int* __restrict__ dbbase, int* __restrict__ dbcursor,
                              int nbuk, int E) {
    __shared__ int sv[256];
    const int tid = threadIdx.x;

    int c = (tid < nbuk) ? bhist_src[tid] : 0;
    sv[tid] = c;
    __syncthreads();
    for (int st = 1; st < 256; st <<= 1) {
        int t = (tid >= st) ? sv[tid - st] : 0;
        __syncthreads();
        sv[tid] += t;
        __syncthreads();
    }
    if (tid < nbuk) { int ex = sv[tid] - c; sbbase[tid] = ex; sbcursor[tid] = ex; }
    if (tid == 0) sbbase[nbuk] = E;
    __syncthreads();

    c = (tid < nbuk) ? bhist_dst[tid] : 0;
    sv[tid] = c;
    __syncthreads();
    for (int st = 1; st < 256; st <<= 1) {
        int t = (tid >= st) ? sv[tid - st] : 0;
        __syncthreads();
        sv[tid] += t;
        __syncthreads();
    }
    if (tid < nbuk) { int ex = sv[tid] - c; dbbase[tid] = ex; dbcursor[tid] = ex; }
    if (tid == 0) dbbase[nbuk] = E;
}

// ---------------------------------------------------------------------------
// Partition (dst,src) pairs by dst-bucket: LDS counting sort per 4096-edge
// chunk, one cursor reservation per (block,bucket), coalesced run writes.
// ---------------------------------------------------------------------------
#define PCH 4096
__global__ __launch_bounds__(256) void partition_kernel(
    const int* __restrict__ src, const int* __restrict__ dst,
    int* __restrict__ bcursor, unsigned long long* __restrict__ pairs,
    int E, int nbuk) {
    __shared__ int lhist[256];
    __shared__ int lbase[256];
    __shared__ int gbase[256];
    __shared__ int scanv[256];
    __shared__ unsigned long long lpair[PCH];
    __shared__ unsigned char lbid[PCH];

    const int tid = threadIdx.x;
    const int c0 = blockIdx.x * PCH;
    int cnt = E - c0; if (cnt > PCH) cnt = PCH;

    lhist[tid] = 0;
    __syncthreads();

    int dv[16], sv[16], rk[16];
#pragma unroll
    for (int q = 0; q < 16; ++q) {
        int e = c0 + q * 256 + tid;
        if (e < E) {
            int d = dst[e];
            dv[q] = d;
            sv[q] = src[e];
            rk[q] = atomicAdd(&lhist[d >> 8], 1);
        } else {
            dv[q] = -1;
        }
    }
    __syncthreads();

    int c = lhist[tid];
    scanv[tid] = c;
    __syncthreads();
    for (int st = 1; st < 256; st <<= 1) {
        int t = (tid >= st) ? scanv[tid - st] : 0;
        __syncthreads();
        scanv[tid] += t;
        __syncthreads();
    }
    lbase[tid] = scanv[tid] - c;
    if (tid < nbuk && c > 0) gbase[tid] = atomicAdd(&bcursor[tid], c);
    __syncthreads();

#pragma unroll
    for (int q = 0; q < 16; ++q) {
        if (dv[q] >= 0) {
            int b = dv[q] >> 8;
            int slot = lbase[b] + rk[q];
            lpair[slot] = ((unsigned long long)(unsigned)dv[q] << 32) | (unsigned)sv[q];
            lbid[slot] = (unsigned char)b;
        }
    }
    __syncthreads();

    for (int i = tid; i < cnt; i += 256) {
        int b = lbid[i];
        pairs[(long)gbase[b] + (i - lbase[b])] = lpair[i];
    }
}

// Same machinery for src values only (4B payload) -> ssorted.
__global__ __launch_bounds__(256) void partition_src_kernel(
    const int* __restrict__ src, int* __restrict__ bcursor,
    int* __restrict__ ssorted, int E, int nbuk) {
    __shared__ int lhist[256];
    __shared__ int lbase[256];
    __shared__ int gbase[256];
    __shared__ int scanv[256];
    __shared__ int lval[PCH];
    __shared__ unsigned char lbid[PCH];

    const int tid = threadIdx.x;
    const int c0 = blockIdx.x * PCH;
    int cnt = E - c0; if (cnt > PCH) cnt = PCH;

    lhist[tid] = 0;
    __syncthreads();

    int sv[16], rk[16];
#pragma unroll
    for (int q = 0; q < 16; ++q) {
        int e = c0 + q * 256 + tid;
        if (e < E) {
            int s = src[e];
            sv[q] = s;
            rk[q] = atomicAdd(&lhist[s >> 8], 1);
        } else {
            sv[q] = -1;
        }
    }
    __syncthreads();

    int c = lhist[tid];
    scanv[tid] = c;
    __syncthreads();
    for (int st = 1; st < 256; st <<= 1) {
        int t = (tid >= st) ? scanv[tid - st] : 0;
        __syncthreads();
        scanv[tid] += t;
        __syncthreads();
    }
    lbase[tid] = scanv[tid] - c;
    if (tid < nbuk && c > 0) gbase[tid] = atomicAdd(&bcursor[tid], c);
    __syncthreads();

#pragma unroll
    for (int q = 0; q < 16; ++q) {
        if (sv[q] >= 0) {
            int b = sv[q] >> 8;
            int slot = lbase[b] + rk[q];
            lval[slot] = sv[q];
            lbid[slot] = (unsigned char)b;
        }
    }
    __syncthreads();

    for (int i = tid; i < cnt; i += 256) {
        int b = lbid[i];
        ssorted[(long)gbase[b] + (i - lbase[b])] = lval[i];
    }
}

// ---------------------------------------------------------------------------
// Per-bucket CSR build: LDS histogram -> row_ptr + nd, LDS cursors -> scatter
// csr_src into the bucket's contiguous region.
// ---------------------------------------------------------------------------
__global__ __launch_bounds__(256) void bucket_csr_kernel(
    const unsigned long long* __restrict__ pairs, const int* __restrict__ bbase,
    int* __restrict__ row_ptr, float* __restrict__ ndv,
    int* __restrict__ csr_src, int N) {
    __shared__ int hist[256];
    __shared__ int scanv[256];
    __shared__ int lcur[256];
    const int tid = threadIdx.x;
    const int b = blockIdx.x;
    const int e0 = bbase[b], e1 = bbase[b + 1];

    hist[tid] = 0;
    __syncthreads();
    for (int e = e0 + tid; e < e1; e += 256) {
        int d = (int)(pairs[e] >> 32);
        atomicAdd(&hist[d & 255], 1);
    }
    __syncthreads();

    int c = hist[tid];
    scanv[tid] = c;
    __syncthreads();
    for (int st = 1; st < 256; st <<= 1) {
        int t = (tid >= st) ? scanv[tid - st] : 0;
        __syncthreads();
        scanv[tid] += t;
        __syncthreads();
    }
    int excl = scanv[tid] - c;
    int node = b * 256 + tid;
    if (node < N) {
        row_ptr[node] = e0 + excl;
        ndv[node] = rsqrtf((float)(c + 1));
    }
    if (node == N) row_ptr[N] = e0 + excl;
    lcur[tid] = excl;
    __syncthreads();

    for (int e = e0 + tid; e < e1; e += 256) {
        unsigned long long pr = pairs[e];
        int d = (int)(pr >> 32);
        int r = atomicAdd(&lcur[d & 255], 1);
        csr_src[e0 + r] = (int)(pr & 0xFFFFFFFFu);
    }
}

// Per-bucket out-degree histogram -> ns (no outd array, no global atomics).
__global__ __launch_bounds__(256) void bucket_ns_kernel(
    const int* __restrict__ ssorted, const int* __restrict__ sbbase,
    float* __restrict__ ns, int N) {
    __shared__ int hist[256];
    const int tid = threadIdx.x;
    const int b = blockIdx.x;
    const int e0 = sbbase[b], e1 = sbbase[b + 1];
    hist[tid] = 0;
    __syncthreads();
    for (int e = e0 + tid; e < e1; e += 256) atomicAdd(&hist[ssorted[e] & 255], 1);
    __syncthreads();
    int node = b * 256 + tid;
    if (node < N) ns[node] = rsqrtf((float)(hist[tid] + 1));
}

// Split-K partials for bc[n] = sum_k b_aff[k] * W_gcn[k*D + n]
__global__ __launch_bounds__(256) void bcomb_part_kernel(
    const float* __restrict__ b_aff, const float* __restrict__ W_gcn,
    float* __restrict__ part, int D, int PD) {
    int n = blockIdx.x * blockDim.x + threadIdx.x;
    int c = blockIdx.y;
    if (n >= PD) return;
    float s = 0.f;
    if (n < D) {
        int k0 = c * 8;
        int k1 = k0 + 8; if (k1 > D) k1 = D;
        for (int k = k0; k < k1; ++k) s = fmaf(b_aff[k], W_gcn[(long)k * D + n], s);
    }
    part[(long)c * PD + n] = s;
}

// v[k] = sum_c W_pred_in[k*D + c] * w_out[c]   (one wave per row k, k < 2D)
__global__ void vcomb_kernel(const float* __restrict__ Win, const float* __restrict__ wout,
                             float* __restrict__ v, int D, int K2) {
    int k = blockIdx.x * (blockDim.x >> 6) + (threadIdx.x >> 6);
    int lane = threadIdx.x & 63;
    if (k >= K2) return;
    float s = 0.f;
    for (int c = lane; c < D; c += 64) s = fmaf(Win[(long)k * D + c], wout[c], s);
#pragma unroll
    for (int m = 32; m > 0; m >>= 1) s += __shfl_down(s, m);
    if (lane == 0) v[k] = s;
}

// bias_dot = b_pred_out + sum_c b_pred_in[c]*w_out[c]
__global__ void bias_dot_kernel(const float* __restrict__ b_in, const float* __restrict__ w_out,
                                const float* __restrict__ b_out, float* __restrict__ bias_dot, int D) {
    __shared__ float sm[256];
    float s = 0.f;
    for (int c = threadIdx.x; c < D; c += 256) s = fmaf(b_in[c], w_out[c], s);
    sm[threadIdx.x] = s;
    __syncthreads();
    for (int st = 128; st > 0; st >>= 1) {
        if (threadIdx.x < st) sm[threadIdx.x] += sm[threadIdx.x + st];
        __syncthreads();
    }
    if (threadIdx.x == 0) bias_dot[0] = sm[0] + b_out[0];
}

// Zero-pad small vectors to PD=512: bcp (reduced from split-K partials), bgp, v1p, v2p
__global__ void pad_kernel(const float* __restrict__ part, const float* __restrict__ b_gcn,
                           const float* __restrict__ v, float* __restrict__ bcp,
                           float* __restrict__ bgp, float* __restrict__ v1p,
                           float* __restrict__ v2p, int D, int PD, int NC) {
    int i = blockIdx.x * blockDim.x + threadIdx.x;
    if (i < PD) {
        float s = 0.f;
        for (int c = 0; c < NC; ++c) s += part[(long)c * PD + i];
        bcp[i] = s;                       // pad cols already 0 in part
        bgp[i] = (i < D) ? b_gcn[i] : 0.f;
        v1p[i] = (i < D) ? v[i] : 0.f;
        v2p[i] = (i < D) ? v[D + i] : 0.f;
    }
}

// ---------------------------------------------------------------------------
// fp32 tiled GEMM (only used for the tiny Wc = W_aff @ W_gcn)
// ---------------------------------------------------------------------------
__global__ __launch_bounds__(256) void sgemm_kernel(const float* __restrict__ A, int lda,
                                                    const float* __restrict__ B, int ldb,
                                                    float* __restrict__ C, int ldc,
                                                    int M, int N, int K) {
    __shared__ __align__(16) float As[16][68];
    __shared__ __align__(16) float Bs[16][68];
    const int tid = threadIdx.x;
    const int tx = tid & 15, ty = tid >> 4;
    const int row0 = blockIdx.x * 64;
    const int col0 = blockIdx.y * 64;

    const int a_row = tid >> 2;
    const int a_k   = (tid & 3) * 4;
    const int b_k   = tid >> 4;
    const int b_c   = (tid & 15) * 4;

    float acc[4][4] = {};

    for (int k0 = 0; k0 < K; k0 += 16) {
        float4 av = make_float4(0.f, 0.f, 0.f, 0.f);
        {
            int gr = row0 + a_row;
            int gk = k0 + a_k;
            if (gr < M) {
                if (gk + 3 < K) {
                    av = *reinterpret_cast<const float4*>(&A[(long)gr * lda + gk]);
                } else {
                    float t0 = (gk + 0 < K) ? A[(long)gr * lda + gk + 0] : 0.f;
                    float t1 = (gk + 1 < K) ? A[(long)gr * lda + gk + 1] : 0.f;
                    float t2 = (gk + 2 < K) ? A[(long)gr * lda + gk + 2] : 0.f;
                    float t3 = (gk + 3 < K) ? A[(long)gr * lda + gk + 3] : 0.f;
                    av = make_float4(t0, t1, t2, t3);
                }
            }
        }
        float4 bv = make_float4(0.f, 0.f, 0.f, 0.f);
        {
            int gk = k0 + b_k;
            int gc = col0 + b_c;
            if (gk < K) {
                if (gc + 3 < N) {
                    bv = *reinterpret_cast<const float4*>(&B[(long)gk * ldb + gc]);
                } else {
                    float t0 = (gc + 0 < N) ? B[(long)gk * ldb + gc + 0] : 0.f;
                    float t1 = (gc + 1 < N) ? B[(long)gk * ldb + gc + 1] : 0.f;
                    float t2 = (gc + 2 < N) ? B[(long)gk * ldb + gc + 2] : 0.f;
                    float t3 = (gc + 3 < N) ? B[(long)gk * ldb + gc + 3] : 0.f;
                    bv = make_float4(t0, t1, t2, t3);
                }
            }
        }
        __syncthreads();
        As[a_k + 0][a_row] = av.x;
        As[a_k + 1][a_row] = av.y;
        As[a_k + 2][a_row] = av.z;
        As[a_k + 3][a_row] = av.w;
        *reinterpret_cast<float4*>(&Bs[b_k][b_c]) = bv;
        __syncthreads();

#pragma unroll
        for (int k = 0; k < 16; ++k) {
            const float4 a = *reinterpret_cast<const float4*>(&As[k][ty * 4]);
            const float4 b = *reinterpret_cast<const float4*>(&Bs[k][tx * 4]);
            const float avv[4] = {a.x, a.y, a.z, a.w};
            const float bvv[4] = {b.x, b.y, b.z, b.w};
#pragma unroll
            for (int i = 0; i < 4; ++i)
#pragma unroll
                for (int j = 0; j < 4; ++j)
                    acc[i][j] = fmaf(avv[i], bvv[j], acc[i][j]);
        }
    }

#pragma unroll
    for (int i = 0; i < 4; ++i) {
        int r = row0 + ty * 4 + i;
        if (r >= M) continue;
#pragma unroll
        for (int j = 0; j < 4; ++j) {
            int c = col0 + tx * 4 + j;
            if (c < N) C[(long)r * ldc + c] = acc[i][j];
        }
    }
}

// fs16[s][c] = bf16(feats[s][c] * ns[s])   (F = 128)
__global__ void conv_feats_kernel(const float* __restrict__ feats, const float* __restrict__ ns,
                                  unsigned short* __restrict__ fs16, int N) {
    int idx = blockIdx.x * blockDim.x + threadIdx.x;
    if (idx >= N * 16) return;
    int node = idx >> 4;
    int c = (idx & 15) * 8;
    float s = ns[node];
    const float* p = feats + (long)node * 128 + c;
    float4 a = *reinterpret_cast<const float4*>(p);
    float4 b = *reinterpret_cast<const float4*>(p + 4);
    uint4 o;
    o.x = (unsigned)f2bf(a.x * s) | ((unsigned)f2bf(a.y * s) << 16);
    o.y = (unsigned)f2bf(a.z * s) | ((unsigned)f2bf(a.w * s) << 16);
    o.z = (unsigned)f2bf(b.x * s) | ((unsigned)f2bf(b.y * s) << 16);
    o.w = (unsigned)f2bf(b.z * s) | ((unsigned)f2bf(b.w * s) << 16);
    *reinterpret_cast<uint4*>(fs16 + (long)node * 128 + c) = o;
}

// Wc [128][D] fp32 -> Bt [PD=512 rows n][128 k] bf16 (transposed, pad rows zero)
__global__ void conv_Bt_kernel(const float* __restrict__ Wc, unsigned short* __restrict__ Bt,
                               int D, int PD) {
    int idx = blockIdx.x * blockDim.x + threadIdx.x;   // PD*16 threads
    if (idx >= PD * 16) return;
    int n = idx >> 4;
    int k8 = (idx & 15) * 8;
    uint4 o = make_uint4(0, 0, 0, 0);
    if (n < D) {
        unsigned short t[8];
#pragma unroll
        for (int q = 0; q < 8; ++q) t[q] = f2bf(Wc[(long)(k8 + q) * D + n]);
        o.x = (unsigned)t[0] | ((unsigned)t[1] << 16);
        o.y = (unsigned)t[2] | ((unsigned)t[3] << 16);
        o.z = (unsigned)t[4] | ((unsigned)t[5] << 16);
        o.w = (unsigned)t[6] | ((unsigned)t[7] << 16);
    }
    *reinterpret_cast<uint4*>(Bt + (long)n * 128 + k8) = o;
}

// ---------------------------------------------------------------------------
// Feature-space CSR gather, wave per node:
//   g16[d] = bf16( Σ_{s∈in(d)} fs16[s] + fs16[d] )   (fp32 accum)
//   h[d]   = Σ ns[s] + ns[d]
// R4: 4-way unrolled neighbor loop -> 4 outstanding loads per wave.
// ---------------------------------------------------------------------------
__global__ __launch_bounds__(256) void gather_feats_kernel(
    const unsigned short* __restrict__ fs16, const int* __restrict__ csr_src,
    const int* __restrict__ row_ptr, const float* __restrict__ ns,
    unsigned short* __restrict__ g16, float* __restrict__ h, int N) {
    int d = blockIdx.x * 4 + (threadIdx.x >> 6);
    int lane = threadIdx.x & 63;
    if (d >= N) return;

    // self loop init
    unsigned su = *reinterpret_cast<const unsigned*>(fs16 + (long)d * 128 + lane * 2);
    float a0 = __uint_as_float(su << 16);
    float a1 = __uint_as_float(su & 0xFFFF0000u);
    float hacc = 0.f;

    const int beg = row_ptr[d], end = row_ptr[d + 1];
    for (int j0 = beg; j0 < end; j0 += 64) {
        int cnt = end - j0;
        if (cnt > 64) cnt = 64;
        int s = (lane < cnt) ? csr_src[j0 + lane] : 0;
        if (lane < cnt) hacc += ns[s];
        int k = 0;
        for (; k + 4 <= cnt; k += 4) {
            int s0 = __shfl(s, k);
            int s1 = __shfl(s, k + 1);
            int s2 = __shfl(s, k + 2);
            int s3 = __shfl(s, k + 3);
            unsigned v0 = *reinterpret_cast<const unsigned*>(fs16 + (long)s0 * 128 + lane * 2);
            unsigned v1 = *reinterpret_cast<const unsigned*>(fs16 + (long)s1 * 128 + lane * 2);
            unsigned v2 = *reinterpret_cast<const unsigned*>(fs16 + (long)s2 * 128 + lane * 2);
            unsigned v3 = *reinterpret_cast<const unsigned*>(fs16 + (long)s3 * 128 + lane * 2);
            a0 += __uint_as_float(v0 << 16); a1 += __uint_as_float(v0 & 0xFFFF0000u);
            a0 += __uint_as_float(v1 << 16); a1 += __uint_as_float(v1 & 0xFFFF0000u);
            a0 += __uint_as_float(v2 << 16); a1 += __uint_as_float(v2 & 0xFFFF0000u);
            a0 += __uint_as_float(v3 << 16); a1 += __uint_as_float(v3 & 0xFFFF0000u);
        }
        for (; k < cnt; ++k) {
            int sk = __shfl(s, k);
            unsigned v = *reinterpret_cast<const unsigned*>(fs16 + (long)sk * 128 + lane * 2);
            a0 += __uint_as_float(v << 16);
            a1 += __uint_as_float(v & 0xFFFF0000u);
        }
    }
#pragma unroll
    for (int m = 32; m > 0; m >>= 1) hacc += __shfl_xor(hacc, m);
    if (lane == 0) h[d] = hacc + ns[d];
    unsigned o = (unsigned)f2bf(a0) | ((unsigned)f2bf(a1) << 16);
    *reinterpret_cast<unsigned*>(g16 + (long)d * 128 + lane * 2) = o;
}

// ---------------------------------------------------------------------------
// MFMA GEMM: emb[r][c] = nd[r]*( (g16@Wc)[r][c] + h[r]*bcp[c] ) + bgp[c]
// fused epilogue dots: u1[r] += Σ_c emb·v1p, u2[r] += Σ_c emb·v2p
// ---------------------------------------------------------------------------
__global__ __launch_bounds__(256) void gcn_gemm_kernel(
    const unsigned short* __restrict__ g16, const unsigned short* __restrict__ Bt,
    const float* __restrict__ h, const float* __restrict__ nd,
    const float* __restrict__ bcp, const float* __restrict__ bgp,
    const float* __restrict__ v1p, const float* __restrict__ v2p,
    float* __restrict__ emb, float* __restrict__ u1, float* __restrict__ u2,
    int M, int D) {

    __shared__ __align__(16) unsigned short As[128 * 32];
    __shared__ __align__(16) unsigned short Bs[128 * 32];

    const int tid  = threadIdx.x;
    const int w    = tid >> 6;
    const int lane = tid & 63;
    const int row0 = blockIdx.x * 128;
    const int col0 = blockIdx.y * 128;

    const int r0   = 2 * w * 16 + (lane >> 2);
    const int r1   = (2 * w + 1) * 16 + (lane >> 2);
    const int slot = lane & 3;
    const int c0   = slot ^ ((r0 >> 1) & 3);
    const int c1   = slot ^ ((r1 >> 1) & 3);

    const unsigned short* pA0 = g16 + (long)(row0 + r0) * 128 + c0 * 8;
    const unsigned short* pA1 = g16 + (long)(row0 + r1) * 128 + c1 * 8;
    const unsigned short* pB0 = Bt + (long)(col0 + r0) * 128 + c0 * 8;
    const unsigned short* pB1 = Bt + (long)(col0 + r1) * 128 + c1 * 8;

    unsigned short* dA0 = As + 2 * w * 512;
    unsigned short* dA1 = As + (2 * w + 1) * 512;
    unsigned short* dB0 = Bs + 2 * w * 512;
    unsigned short* dB1 = Bs + (2 * w + 1) * 512;

    const int wrow = (w & 1) * 64;
    const int wcol = (w >> 1) * 64;
    const int lm = lane & 15, q = lane >> 4;
    const s16x8* pa[4];
    const s16x8* pb[4];
#pragma unroll
    for (int i = 0; i < 4; ++i) {
        int r = wrow + i * 16 + lm;
        int cs = q ^ ((r >> 1) & 3);
        pa[i] = reinterpret_cast<const s16x8*>(As + r * 32 + cs * 8);
        int n = wcol + i * 16 + lm;
        int cs2 = q ^ ((n >> 1) & 3);
        pb[i] = reinterpret_cast<const s16x8*>(Bs + n * 32 + cs2 * 8);
    }

    f32x4 acc[4][4];
#pragma unroll
    for (int i = 0; i < 4; ++i)
#pragma unroll
        for (int j = 0; j < 4; ++j) acc[i][j] = (f32x4)0.f;

    for (int k0 = 0; k0 < 128; k0 += 32) {
        async_ld16(pA0 + k0, dA0);
        async_ld16(pA1 + k0, dA1);
        async_ld16(pB0 + k0, dB0);
        async_ld16(pB1 + k0, dB1);
        __syncthreads();

        s16x8 af[4], bf[4];
#pragma unroll
        for (int i = 0; i < 4; ++i) { af[i] = *pa[i]; bf[i] = *pb[i]; }
#pragma unroll
        for (int i = 0; i < 4; ++i)
#pragma unroll
            for (int j = 0; j < 4; ++j)
                acc[i][j] = __builtin_amdgcn_mfma_f32_16x16x32_bf16(af[i], bf[j], acc[i][j], 0, 0, 0);
        __syncthreads();
    }

    // epilogue: finalize emb + fused u-dots
    float bcv[4], bgv[4], w1[4], w2[4];
    int colv[4];
#pragma unroll
    for (int j = 0; j < 4; ++j) {
        int c = col0 + wcol + j * 16 + lm;
        colv[j] = c;
        bcv[j] = bcp[c];
        bgv[j] = bgp[c];
        w1[j] = v1p[c];
        w2[j] = v2p[c];
    }

#pragma unroll
    for (int i = 0; i < 4; ++i) {
        float p1[4], p2[4];
#pragma unroll
        for (int reg = 0; reg < 4; ++reg) {
            int row = row0 + wrow + i * 16 + q * 4 + reg;
            float hb = h[row];
            float sc = nd[row];
            float s1 = 0.f, s2 = 0.f;
#pragma unroll
            for (int j = 0; j < 4; ++j) {
                float o = fmaf(sc, acc[i][j][reg] + hb * bcv[j], bgv[j]);
                if (row < M && colv[j] < D) emb[(long)row * D + colv[j]] = o;
                s1 = fmaf(o, w1[j], s1);
                s2 = fmaf(o, w2[j], s2);
            }
            p1[reg] = s1;
            p2[reg] = s2;
        }
#pragma unroll
        for (int mask = 1; mask < 16; mask <<= 1)
#pragma unroll
            for (int reg = 0; reg < 4; ++reg) {
                p1[reg] += __shfl_xor(p1[reg], mask);
                p2[reg] += __shfl_xor(p2[reg], mask);
            }
        if (lm == 0) {
#pragma unroll
            for (int reg = 0; reg < 4; ++reg) {
                int row = row0 + wrow + i * 16 + q * 4 + reg;
                if (row < M) {
                    atomicAdd(&u1[row], p1[reg]);
                    atomicAdd(&u2[row], p2[reg]);
                }
            }
        }
    }
}

// weights[r] = u1[trip[r,0]] + u2[trip[r,2]] + bias_dot
__global__ void weights_kernel(const int* __restrict__ trip, const float* __restrict__ u1,
                               const float* __restrict__ u2, const float* __restrict__ bdot,
                               float* __restrict__ w, int T) {
    int r = blockIdx.x * blockDim.x + threadIdx.x;
    if (r < T) {
        int s = trip[(long)r * 3 + 0];
        int o = trip[(long)r * 3 + 2];
        w[r] = u1[s] + u2[o] + bdot[0];
    }
}

// ---------------------------------------------------------------------------

extern "C" void kernel_launch(void* const* d_in, const int* in_sizes, int n_in,
                              void* d_out, int out_size, void* d_ws, size_t ws_size,
                              hipStream_t stream) {
    const float* feats      = (const float*)d_in[0];
    const float* W_aff      = (const float*)d_in[1];
    const float* b_aff      = (const float*)d_in[2];
    const float* W_gcn      = (const float*)d_in[3];
    const float* b_gcn      = (const float*)d_in[4];
    const float* W_pred_in  = (const float*)d_in[5];
    const float* b_pred_in  = (const float*)d_in[6];
    const float* W_pred_out = (const float*)d_in[7];
    const float* b_pred_out = (const float*)d_in[8];
    const int*   src        = (const int*)d_in[9];
    const int*   dst        = (const int*)d_in[10];
    const int*   trip       = (const int*)d_in[11];

    const int D = in_sizes[2];           // 500
    const int F = in_sizes[1] / D;       // 128
    const int N = in_sizes[0] / F;       // 50000
    const int E = in_sizes[9];           // 800000
    const int T = in_sizes[11] / 3;      // 200000

    const int PD = 512;
    const int GX = (N + 127) / 128;      // 391 row-blocks
    const int Mpad = GX * 128;           // 50048
    const int NC = (D + 7) / 8;          // bcomb split-K chunks (63)
    const int NBUK = (N >> 8) + 1;       // 196 buckets of 256 nodes

    float* weights = (float*)d_out;          // [T]
    float* emb     = (float*)d_out + T;      // [N*D]

    // workspace layout (16B-aligned chunks first)
    char* p = (char*)d_ws;
    unsigned short* fs16 = (unsigned short*)p;  p += (size_t)N * 128 * 2;        // 12.8 MB
    unsigned short* g16  = (unsigned short*)p;  p += (size_t)Mpad * 128 * 2;     // 12.8 MB
    unsigned long long* pairs = (unsigned long long*)p; p += (size_t)E * 8;      // 6.4 MB
    int* ssorted = (int*)p;  p += (size_t)E * 4;                                 // 3.2 MB
    unsigned short* Bt   = (unsigned short*)p;  p += (size_t)PD * 128 * 2;       // 128 KB
    float* Wc   = (float*)p;  p += (size_t)F * D * 4;                            // 256 KB
    float* bparts = (float*)p;  p += (size_t)64 * PD * 4;                        // 128 KB
    float* bcp  = (float*)p;  p += PD * 4;
    float* bgp  = (float*)p;  p += PD * 4;
    float* v1p  = (float*)p;  p += PD * 4;
    float* v2p  = (float*)p;  p += PD * 4;
    float* v    = (float*)p;  p += 1024 * 4;
    float* bdot = (float*)p;  p += 16;
    float* ns   = (float*)p;  p += (size_t)N * 4;
    float* nd   = (float*)p;  p += (size_t)N * 4;
    float* h    = (float*)p;  p += (size_t)Mpad * 4;
    float* u1   = (float*)p;  p += (size_t)N * 4;
    float* u2   = (float*)p;  p += (size_t)N * 4;
    int* bhist_src = (int*)p;  p += 256 * 4;     // zeroed together (contiguous)
    int* bhist_dst = (int*)p;  p += 256 * 4;
    int* sbbase   = (int*)p;  p += 260 * 4;
    int* sbcursor = (int*)p;  p += 256 * 4;
    int* dbbase   = (int*)p;  p += 260 * 4;
    int* dbcursor = (int*)p;  p += 256 * 4;
    int* row_ptr = (int*)p;  p += (size_t)(N + 1) * 4;
    int* csr_src = (int*)p;  p += (size_t)E * 4;

    // zero: bucket histograms, u-accumulators, g16/h pad rows
    hipMemsetAsync(bhist_src, 0, 512 * 4, stream);
    hipMemsetAsync(u1, 0, 2 * (size_t)N * sizeof(float), stream);
    hipMemsetAsync(g16 + (size_t)N * 128, 0, (size_t)(Mpad - N) * 128 * 2, stream);
    hipMemsetAsync(h + N, 0, (size_t)(Mpad - N) * 4, stream);

    // graph prep: bucket histograms -> scans -> partitions -> CSR + degrees
    hist2_kernel<<<256, 256, 0, stream>>>(src, dst, bhist_src, bhist_dst, E);
    bscan2_kernel<<<1, 256, 0, stream>>>(bhist_src, bhist_dst, sbbase, sbcursor,
                                         dbbase, dbcursor, NBUK, E);
    partition_kernel<<<(E + PCH - 1) / PCH, 256, 0, stream>>>(src, dst, dbcursor, pairs, E, NBUK);
    partition_src_kernel<<<(E + PCH - 1) / PCH, 256, 0, stream>>>(src, sbcursor, ssorted, E, NBUK);
    bucket_csr_kernel<<<NBUK, 256, 0, stream>>>(pairs, dbbase, row_ptr, nd, csr_src, N);
    bucket_ns_kernel<<<NBUK, 256, 0, stream>>>(ssorted, sbbase, ns, N);

    // pred linearization + weight prep
    vcomb_kernel<<<(2 * D + 3) / 4, 256, 0, stream>>>(W_pred_in, W_pred_out, v, D, 2 * D);
    bias_dot_kernel<<<1, 256, 0, stream>>>(b_pred_in, W_pred_out, b_pred_out, bdot, D);

    // Wc = W_aff @ W_gcn ; bc partials (split-K) ; pads ; Bt (bf16 transposed Wc)
    {
        dim3 grid((F + 63) / 64, (D + 63) / 64);
        sgemm_kernel<<<grid, 256, 0, stream>>>(W_aff, D, W_gcn, D, Wc, D, F, D, D);
    }
    {
        dim3 grid((PD + 255) / 256, NC);
        bcomb_part_kernel<<<grid, 256, 0, stream>>>(b_aff, W_gcn, bparts, D, PD);
    }
    pad_kernel<<<(PD + 255) / 256, 256, 0, stream>>>(bparts, b_gcn, v, bcp, bgp, v1p, v2p, D, PD, NC);
    conv_Bt_kernel<<<(PD * 16 + 255) / 256, 256, 0, stream>>>(Wc, Bt, D, PD);

    // fs16 = bf16(ns ⊙ feats)
    conv_feats_kernel<<<(N * 16 + 255) / 256, 256, 0, stream>>>(feats, ns, fs16, N);

    // feature-space gather: g16, h
    gather_feats_kernel<<<(N + 3) / 4, 256, 0, stream>>>(fs16, csr_src, row_ptr, ns, g16, h, N);

    // MFMA GEMM: emb (+ fused u1/u2 dots)
    {
        dim3 grid(GX, PD / 128);
        gcn_gemm_kernel<<<grid, 256, 0, stream>>>(g16, Bt, h, nd, bcp, bgp, v1p, v2p,
                                                  emb, u1, u2, N, D);
    }

    // weights from per-node scalars
    weights_kernel<<<(T + 255) / 256, 256, 0, stream>>>(trip, u1, u2, bdot, weights, T);
}

// Round 5
// 354.908 us; speedup vs baseline: 1.8693x; 1.0296x over previous
//
#include <hip/hip_runtime.h>

// ---------------------------------------------------------------------------
// Algebra: emb = nd ⊙ (Â (ns ⊙ (feats@Wc + bc))) + b_gcn
//        = nd ⊙ ( g@Wc + h·bcᵀ ) + b_gcn     with g = Â(ns⊙feats), h = Â ns
// (Â = adjacency-by-dst incl. self loops; Wc = W_aff@W_gcn, bc = b_aff@W_gcn)
// Gather is done in F=128 feature space (4x less traffic than D=500 space).
// pred MLP is linear => weights[r] = emb[s]·v1 + emb[o]·v2 + bias_dot,
// v = W_pred_in @ W_pred_out; u-dots fused into the MFMA GEMM epilogue.
//
// R1: multi-block scan (+norm fusion). 663→543 (pred −120, got −120).
// R2: bcomb split-K. 543→441 (pred ~420).
// R3: bucket-partition CSR build (no per-edge csr atomics). 441→398 (pred 360).
// R4: gather unroll-4 + zero global per-edge atomics. 398→365 (pred 330).
// R5: top-5 is all harness fillBuffer (60 µs, not addressable). Remaining own
// cost: gather still issues 4B/lane loads. -> 16B/lane (uint4, 16 lanes/row,
// 4 neighbors/wave, x2 unroll); fuse partition+partition_src (one src/dst
// read) and bucket_csr+bucket_ns. Pred ~325 µs.
// ---------------------------------------------------------------------------

typedef float f32x4 __attribute__((ext_vector_type(4)));
typedef short s16x8 __attribute__((ext_vector_type(8)));

__device__ __forceinline__ unsigned short f2bf(float f) {
    unsigned u = __float_as_uint(f);
    unsigned r = (u + 0x7FFFu + ((u >> 16) & 1u)) >> 16;
    return (unsigned short)r;
}

__device__ __forceinline__ void async_ld16(const void* g, void* lds) {
    __builtin_amdgcn_global_load_lds(
        (const __attribute__((address_space(1))) unsigned int*)g,
        (__attribute__((address_space(3))) unsigned int*)lds,
        16, 0, 0);
}

// ---------------------------------------------------------------------------
// Bucket histograms of src>>8 and dst>>8 (LDS-aggregated, per-block flush).
// ---------------------------------------------------------------------------
__global__ __launch_bounds__(256) void hist2_kernel(
    const int* __restrict__ src, const int* __restrict__ dst,
    int* __restrict__ bhist_src, int* __restrict__ bhist_dst, int E) {
    __shared__ int lhs[256], lhd[256];
    lhs[threadIdx.x] = 0;
    lhd[threadIdx.x] = 0;
    __syncthreads();
    const int stride = gridDim.x * blockDim.x;
    for (int e = blockIdx.x * blockDim.x + threadIdx.x; e < E; e += stride) {
        atomicAdd(&lhs[src[e] >> 8], 1);
        atomicAdd(&lhd[dst[e] >> 8], 1);
    }
    __syncthreads();
    int cs = lhs[threadIdx.x], cd = lhd[threadIdx.x];
    if (cs > 0) atomicAdd(&bhist_src[threadIdx.x], cs);
    if (cd > 0) atomicAdd(&bhist_dst[threadIdx.x], cd);
}

// Exclusive scans of both bucket histograms -> bases + cursors. 1 block.
__global__ void bscan2_kernel(const int* __restrict__ bhist_src, const int* __restrict__ bhist_dst,
                              int* __restrict__ sbbase, int* __restrict__ sbcursor,
                              int* __restrict__ dbbase, int* __restrict__ dbcursor,
                              int nbuk, int E) {
    __shared__ int sv[256];
    const int tid = threadIdx.x;

    int c = (tid < nbuk) ? bhist_src[tid] : 0;
    sv[tid] = c;
    __syncthreads();
    for (int st = 1; st < 256; st <<= 1) {
        int t = (tid >= st) ? sv[tid - st] : 0;
        __syncthreads();
        sv[tid] += t;
        __syncthreads();
    }
    if (tid < nbuk) { int ex = sv[tid] - c; sbbase[tid] = ex; sbcursor[tid] = ex; }
    if (tid == 0) sbbase[nbuk] = E;
    __syncthreads();

    c = (tid < nbuk) ? bhist_dst[tid] : 0;
    sv[tid] = c;
    __syncthreads();
    for (int st = 1; st < 256; st <<= 1) {
        int t = (tid >= st) ? sv[tid - st] : 0;
        __syncthreads();
        sv[tid] += t;
        __syncthreads();
    }
    if (tid < nbuk) { int ex = sv[tid] - c; dbbase[tid] = ex; dbcursor[tid] = ex; }
    if (tid == 0) dbbase[nbuk] = E;
}

// ---------------------------------------------------------------------------
// Fused partition: one read of (src,dst); phase A sorts (dst,src) pairs by
// dst-bucket, phase B sorts src by src-bucket — sequential phases reuse the
// same 32KB LDS payload buffer. Coalesced run writes, one cursor reservation
// per (block,bucket).
// ---------------------------------------------------------------------------
#define PCH 4096
__global__ __launch_bounds__(256) void fused_partition_kernel(
    const int* __restrict__ src, const int* __restrict__ dst,
    int* __restrict__ dcursor, unsigned long long* __restrict__ pairs,
    int* __restrict__ scursor, int* __restrict__ ssorted,
    int E, int nbuk) {
    __shared__ int lhist[256];
    __shared__ int lbase[256];
    __shared__ int gbase[256];
    __shared__ int scanv[256];
    __shared__ unsigned long long lpair[PCH];   // 32 KB (reused as int in B)
    __shared__ unsigned char lbid[PCH];

    const int tid = threadIdx.x;
    const int c0 = blockIdx.x * PCH;
    int cnt = E - c0; if (cnt > PCH) cnt = PCH;

    int dv[16], sv[16], rk[16];

    // ---- phase A: (dst,src) by dst-bucket ----
    lhist[tid] = 0;
    __syncthreads();
#pragma unroll
    for (int q = 0; q < 16; ++q) {
        int e = c0 + q * 256 + tid;
        if (e < E) {
            int d = dst[e];
            dv[q] = d;
            sv[q] = src[e];
            rk[q] = atomicAdd(&lhist[d >> 8], 1);
        } else {
            dv[q] = -1;
            sv[q] = -1;
        }
    }
    __syncthreads();

    int c = lhist[tid];
    scanv[tid] = c;
    __syncthreads();
    for (int st = 1; st < 256; st <<= 1) {
        int t = (tid >= st) ? scanv[tid - st] : 0;
        __syncthreads();
        scanv[tid] += t;
        __syncthreads();
    }
    lbase[tid] = scanv[tid] - c;
    if (tid < nbuk && c > 0) gbase[tid] = atomicAdd(&dcursor[tid], c);
    __syncthreads();

#pragma unroll
    for (int q = 0; q < 16; ++q) {
        if (dv[q] >= 0) {
            int b = dv[q] >> 8;
            int slot = lbase[b] + rk[q];
            lpair[slot] = ((unsigned long long)(unsigned)dv[q] << 32) | (unsigned)sv[q];
            lbid[slot] = (unsigned char)b;
        }
    }
    __syncthreads();

    for (int i = tid; i < cnt; i += 256) {
        int b = lbid[i];
        pairs[(long)gbase[b] + (i - lbase[b])] = lpair[i];
    }
    __syncthreads();

    // ---- phase B: src by src-bucket (reuse LDS) ----
    int* lval = (int*)lpair;
    lhist[tid] = 0;
    __syncthreads();
#pragma unroll
    for (int q = 0; q < 16; ++q) {
        if (sv[q] >= 0) rk[q] = atomicAdd(&lhist[sv[q] >> 8], 1);
    }
    __syncthreads();

    c = lhist[tid];
    scanv[tid] = c;
    __syncthreads();
    for (int st = 1; st < 256; st <<= 1) {
        int t = (tid >= st) ? scanv[tid - st] : 0;
        __syncthreads();
        scanv[tid] += t;
        __syncthreads();
    }
    lbase[tid] = scanv[tid] - c;
    if (tid < nbuk && c > 0) gbase[tid] = atomicAdd(&scursor[tid], c);
    __syncthreads();

#pragma unroll
    for (int q = 0; q < 16; ++q) {
        if (sv[q] >= 0) {
            int b = sv[q] >> 8;
            int slot = lbase[b] + rk[q];
            lval[slot] = sv[q];
            lbid[slot] = (unsigned char)b;
        }
    }
    __syncthreads();

    for (int i = tid; i < cnt; i += 256) {
        int b = lbid[i];
        ssorted[(long)gbase[b] + (i - lbase[b])] = lval[i];
    }
}

// ---------------------------------------------------------------------------
// Per-bucket finalize: CSR build (row_ptr, nd, csr_src scatter) + out-degree
// histogram -> ns. Block b owns nodes [b*256, b*256+256).
// ---------------------------------------------------------------------------
__global__ __launch_bounds__(256) void bucket_finalize_kernel(
    const unsigned long long* __restrict__ pairs, const int* __restrict__ dbbase,
    const int* __restrict__ ssorted, const int* __restrict__ sbbase,
    int* __restrict__ row_ptr, float* __restrict__ ndv,
    int* __restrict__ csr_src, float* __restrict__ ns, int N) {
    __shared__ int hist[256];
    __shared__ int scanv[256];
    __shared__ int lcur[256];
    const int tid = threadIdx.x;
    const int b = blockIdx.x;
    const int node = b * 256 + tid;

    // ---- CSR for dst-bucket b ----
    const int e0 = dbbase[b], e1 = dbbase[b + 1];
    hist[tid] = 0;
    __syncthreads();
    for (int e = e0 + tid; e < e1; e += 256) {
        int d = (int)(pairs[e] >> 32);
        atomicAdd(&hist[d & 255], 1);
    }
    __syncthreads();

    int c = hist[tid];
    scanv[tid] = c;
    __syncthreads();
    for (int st = 1; st < 256; st <<= 1) {
        int t = (tid >= st) ? scanv[tid - st] : 0;
        __syncthreads();
        scanv[tid] += t;
        __syncthreads();
    }
    int excl = scanv[tid] - c;
    if (node < N) {
        row_ptr[node] = e0 + excl;
        ndv[node] = rsqrtf((float)(c + 1));
    }
    if (node == N) row_ptr[N] = e0 + excl;
    lcur[tid] = excl;
    __syncthreads();

    for (int e = e0 + tid; e < e1; e += 256) {
        unsigned long long pr = pairs[e];
        int d = (int)(pr >> 32);
        int r = atomicAdd(&lcur[d & 255], 1);
        csr_src[e0 + r] = (int)(pr & 0xFFFFFFFFu);
    }

    // ---- out-degree histogram for src-bucket b -> ns ----
    __syncthreads();
    hist[tid] = 0;
    __syncthreads();
    const int s0 = sbbase[b], s1 = sbbase[b + 1];
    for (int e = s0 + tid; e < s1; e += 256) atomicAdd(&hist[ssorted[e] & 255], 1);
    __syncthreads();
    if (node < N) ns[node] = rsqrtf((float)(hist[tid] + 1));
}

// Split-K partials for bc[n] = sum_k b_aff[k] * W_gcn[k*D + n]
__global__ __launch_bounds__(256) void bcomb_part_kernel(
    const float* __restrict__ b_aff, const float* __restrict__ W_gcn,
    float* __restrict__ part, int D, int PD) {
    int n = blockIdx.x * blockDim.x + threadIdx.x;
    int c = blockIdx.y;
    if (n >= PD) return;
    float s = 0.f;
    if (n < D) {
        int k0 = c * 8;
        int k1 = k0 + 8; if (k1 > D) k1 = D;
        for (int k = k0; k < k1; ++k) s = fmaf(b_aff[k], W_gcn[(long)k * D + n], s);
    }
    part[(long)c * PD + n] = s;
}

// v[k] = sum_c W_pred_in[k*D + c] * w_out[c]   (one wave per row k, k < 2D)
__global__ void vcomb_kernel(const float* __restrict__ Win, const float* __restrict__ wout,
                             float* __restrict__ v, int D, int K2) {
    int k = blockIdx.x * (blockDim.x >> 6) + (threadIdx.x >> 6);
    int lane = threadIdx.x & 63;
    if (k >= K2) return;
    float s = 0.f;
    for (int c = lane; c < D; c += 64) s = fmaf(Win[(long)k * D + c], wout[c], s);
#pragma unroll
    for (int m = 32; m > 0; m >>= 1) s += __shfl_down(s, m);
    if (lane == 0) v[k] = s;
}

// bias_dot = b_pred_out + sum_c b_pred_in[c]*w_out[c]
__global__ void bias_dot_kernel(const float* __restrict__ b_in, const float* __restrict__ w_out,
                                const float* __restrict__ b_out, float* __restrict__ bias_dot, int D) {
    __shared__ float sm[256];
    float s = 0.f;
    for (int c = threadIdx.x; c < D; c += 256) s = fmaf(b_in[c], w_out[c], s);
    sm[threadIdx.x] = s;
    __syncthreads();
    for (int st = 128; st > 0; st >>= 1) {
        if (threadIdx.x < st) sm[threadIdx.x] += sm[threadIdx.x + st];
        __syncthreads();
    }
    if (threadIdx.x == 0) bias_dot[0] = sm[0] + b_out[0];
}

// Zero-pad small vectors to PD=512: bcp (reduced from split-K partials), bgp, v1p, v2p
__global__ void pad_kernel(const float* __restrict__ part, const float* __restrict__ b_gcn,
                           const float* __restrict__ v, float* __restrict__ bcp,
                           float* __restrict__ bgp, float* __restrict__ v1p,
                           float* __restrict__ v2p, int D, int PD, int NC) {
    int i = blockIdx.x * blockDim.x + threadIdx.x;
    if (i < PD) {
        float s = 0.f;
        for (int c = 0; c < NC; ++c) s += part[(long)c * PD + i];
        bcp[i] = s;                       // pad cols already 0 in part
        bgp[i] = (i < D) ? b_gcn[i] : 0.f;
        v1p[i] = (i < D) ? v[i] : 0.f;
        v2p[i] = (i < D) ? v[D + i] : 0.f;
    }
}

// ---------------------------------------------------------------------------
// fp32 tiled GEMM (only used for the tiny Wc = W_aff @ W_gcn)
// ---------------------------------------------------------------------------
__global__ __launch_bounds__(256) void sgemm_kernel(const float* __restrict__ A, int lda,
                                                    const float* __restrict__ B, int ldb,
                                                    float* __restrict__ C, int ldc,
                                                    int M, int N, int K) {
    __shared__ __align__(16) float As[16][68];
    __shared__ __align__(16) float Bs[16][68];
    const int tid = threadIdx.x;
    const int tx = tid & 15, ty = tid >> 4;
    const int row0 = blockIdx.x * 64;
    const int col0 = blockIdx.y * 64;

    const int a_row = tid >> 2;
    const int a_k   = (tid & 3) * 4;
    const int b_k   = tid >> 4;
    const int b_c   = (tid & 15) * 4;

    float acc[4][4] = {};

    for (int k0 = 0; k0 < K; k0 += 16) {
        float4 av = make_float4(0.f, 0.f, 0.f, 0.f);
        {
            int gr = row0 + a_row;
            int gk = k0 + a_k;
            if (gr < M) {
                if (gk + 3 < K) {
                    av = *reinterpret_cast<const float4*>(&A[(long)gr * lda + gk]);
                } else {
                    float t0 = (gk + 0 < K) ? A[(long)gr * lda + gk + 0] : 0.f;
                    float t1 = (gk + 1 < K) ? A[(long)gr * lda + gk + 1] : 0.f;
                    float t2 = (gk + 2 < K) ? A[(long)gr * lda + gk + 2] : 0.f;
                    float t3 = (gk + 3 < K) ? A[(long)gr * lda + gk + 3] : 0.f;
                    av = make_float4(t0, t1, t2, t3);
                }
            }
        }
        float4 bv = make_float4(0.f, 0.f, 0.f, 0.f);
        {
            int gk = k0 + b_k;
            int gc = col0 + b_c;
            if (gk < K) {
                if (gc + 3 < N) {
                    bv = *reinterpret_cast<const float4*>(&B[(long)gk * ldb + gc]);
                } else {
                    float t0 = (gc + 0 < N) ? B[(long)gk * ldb + gc + 0] : 0.f;
                    float t1 = (gc + 1 < N) ? B[(long)gk * ldb + gc + 1] : 0.f;
                    float t2 = (gc + 2 < N) ? B[(long)gk * ldb + gc + 2] : 0.f;
                    float t3 = (gc + 3 < N) ? B[(long)gk * ldb + gc + 3] : 0.f;
                    bv = make_float4(t0, t1, t2, t3);
                }
            }
        }
        __syncthreads();
        As[a_k + 0][a_row] = av.x;
        As[a_k + 1][a_row] = av.y;
        As[a_k + 2][a_row] = av.z;
        As[a_k + 3][a_row] = av.w;
        *reinterpret_cast<float4*>(&Bs[b_k][b_c]) = bv;
        __syncthreads();

#pragma unroll
        for (int k = 0; k < 16; ++k) {
            const float4 a = *reinterpret_cast<const float4*>(&As[k][ty * 4]);
            const float4 b = *reinterpret_cast<const float4*>(&Bs[k][tx * 4]);
            const float avv[4] = {a.x, a.y, a.z, a.w};
            const float bvv[4] = {b.x, b.y, b.z, b.w};
#pragma unroll
            for (int i = 0; i < 4; ++i)
#pragma unroll
                for (int j = 0; j < 4; ++j)
                    acc[i][j] = fmaf(avv[i], bvv[j], acc[i][j]);
        }
    }

#pragma unroll
    for (int i = 0; i < 4; ++i) {
        int r = row0 + ty * 4 + i;
        if (r >= M) continue;
#pragma unroll
        for (int j = 0; j < 4; ++j) {
            int c = col0 + tx * 4 + j;
            if (c < N) C[(long)r * ldc + c] = acc[i][j];
        }
    }
}

// fs16[s][c] = bf16(feats[s][c] * ns[s])   (F = 128)
__global__ void conv_feats_kernel(const float* __restrict__ feats, const float* __restrict__ ns,
                                  unsigned short* __restrict__ fs16, int N) {
    int idx = blockIdx.x * blockDim.x + threadIdx.x;
    if (idx >= N * 16) return;
    int node = idx >> 4;
    int c = (idx & 15) * 8;
    float s = ns[node];
    const float* p = feats + (long)node * 128 + c;
    float4 a = *reinterpret_cast<const float4*>(p);
    float4 b = *reinterpret_cast<const float4*>(p + 4);
    uint4 o;
    o.x = (unsigned)f2bf(a.x * s) | ((unsigned)f2bf(a.y * s) << 16);
    o.y = (unsigned)f2bf(a.z * s) | ((unsigned)f2bf(a.w * s) << 16);
    o.z = (unsigned)f2bf(b.x * s) | ((unsigned)f2bf(b.y * s) << 16);
    o.w = (unsigned)f2bf(b.z * s) | ((unsigned)f2bf(b.w * s) << 16);
    *reinterpret_cast<uint4*>(fs16 + (long)node * 128 + c) = o;
}

// Wc [128][D] fp32 -> Bt [PD=512 rows n][128 k] bf16 (transposed, pad rows zero)
__global__ void conv_Bt_kernel(const float* __restrict__ Wc, unsigned short* __restrict__ Bt,
                               int D, int PD) {
    int idx = blockIdx.x * blockDim.x + threadIdx.x;   // PD*16 threads
    if (idx >= PD * 16) return;
    int n = idx >> 4;
    int k8 = (idx & 15) * 8;
    uint4 o = make_uint4(0, 0, 0, 0);
    if (n < D) {
        unsigned short t[8];
#pragma unroll
        for (int q = 0; q < 8; ++q) t[q] = f2bf(Wc[(long)(k8 + q) * D + n]);
        o.x = (unsigned)t[0] | ((unsigned)t[1] << 16);
        o.y = (unsigned)t[2] | ((unsigned)t[3] << 16);
        o.z = (unsigned)t[4] | ((unsigned)t[5] << 16);
        o.w = (unsigned)t[6] | ((unsigned)t[7] << 16);
    }
    *reinterpret_cast<uint4*>(Bt + (long)n * 128 + k8) = o;
}

// ---------------------------------------------------------------------------
// Feature-space CSR gather, wave per node, 16B/lane loads:
// 16 lanes cover one 128-feat row (uint4 = 8 bf16); 4 lane-groups process 4
// neighbors concurrently, x2 unroll = 8 neighbors/iter, 2 loads in flight/lane.
//   g16[d] = bf16( Σ_{s∈in(d)} fs16[s] + fs16[d] )   (fp32 accum)
//   h[d]   = Σ ns[s] + ns[d]
// ---------------------------------------------------------------------------
__global__ __launch_bounds__(256) void gather_feats_kernel(
    const unsigned short* __restrict__ fs16, const int* __restrict__ csr_src,
    const int* __restrict__ row_ptr, const float* __restrict__ ns,
    unsigned short* __restrict__ g16, float* __restrict__ h, int N) {
    int d = blockIdx.x * 4 + (threadIdx.x >> 6);
    int lane = threadIdx.x & 63;
    if (d >= N) return;
    const int g = lane >> 4;      // neighbor slot within quad
    const int fl = lane & 15;     // feature slot (8 feats)

    float a[8] = {0.f, 0.f, 0.f, 0.f, 0.f, 0.f, 0.f, 0.f};
    float hacc = 0.f;

    const int beg = row_ptr[d], end = row_ptr[d + 1];
    for (int j0 = beg; j0 < end; j0 += 64) {
        int cnt = end - j0;
        if (cnt > 64) cnt = 64;
        int s = (lane < cnt) ? csr_src[j0 + lane] : 0;
        if (lane < cnt) hacc += ns[s];
        for (int k = 0; k < cnt; k += 8) {
            int k0 = k + g, k1 = k + 4 + g;
            int i0 = __shfl(s, k0 & 63);
            int i1 = __shfl(s, k1 & 63);
            uint4 v0 = make_uint4(0u, 0u, 0u, 0u), v1 = make_uint4(0u, 0u, 0u, 0u);
            if (k0 < cnt) v0 = *reinterpret_cast<const uint4*>(fs16 + (long)i0 * 128 + fl * 8);
            if (k1 < cnt) v1 = *reinterpret_cast<const uint4*>(fs16 + (long)i1 * 128 + fl * 8);
            a[0] += __uint_as_float(v0.x << 16); a[1] += __uint_as_float(v0.x & 0xFFFF0000u);
            a[2] += __uint_as_float(v0.y << 16); a[3] += __uint_as_float(v0.y & 0xFFFF0000u);
            a[4] += __uint_as_float(v0.z << 16); a[5] += __uint_as_float(v0.z & 0xFFFF0000u);
            a[6] += __uint_as_float(v0.w << 16); a[7] += __uint_as_float(v0.w & 0xFFFF0000u);
            a[0] += __uint_as_float(v1.x << 16); a[1] += __uint_as_float(v1.x & 0xFFFF0000u);
            a[2] += __uint_as_float(v1.y << 16); a[3] += __uint_as_float(v1.y & 0xFFFF0000u);
            a[4] += __uint_as_float(v1.z << 16); a[5] += __uint_as_float(v1.z & 0xFFFF0000u);
            a[6] += __uint_as_float(v1.w << 16); a[7] += __uint_as_float(v1.w & 0xFFFF0000u);
        }
    }

    // reduce across the 4 neighbor groups (lanes fl, fl+16, fl+32, fl+48)
#pragma unroll
    for (int r = 0; r < 8; ++r) {
        a[r] += __shfl_xor(a[r], 16);
        a[r] += __shfl_xor(a[r], 32);
    }
    // self row (every lane adds the same fl-segment; consistent across copies)
    {
        uint4 sv4 = *reinterpret_cast<const uint4*>(fs16 + (long)d * 128 + fl * 8);
        a[0] += __uint_as_float(sv4.x << 16); a[1] += __uint_as_float(sv4.x & 0xFFFF0000u);
        a[2] += __uint_as_float(sv4.y << 16); a[3] += __uint_as_float(sv4.y & 0xFFFF0000u);
        a[4] += __uint_as_float(sv4.z << 16); a[5] += __uint_as_float(sv4.z & 0xFFFF0000u);
        a[6] += __uint_as_float(sv4.w << 16); a[7] += __uint_as_float(sv4.w & 0xFFFF0000u);
    }
#pragma unroll
    for (int m = 32; m > 0; m >>= 1) hacc += __shfl_xor(hacc, m);
    if (lane == 0) h[d] = hacc + ns[d];
    if (lane < 16) {
        uint4 o;
        o.x = (unsigned)f2bf(a[0]) | ((unsigned)f2bf(a[1]) << 16);
        o.y = (unsigned)f2bf(a[2]) | ((unsigned)f2bf(a[3]) << 16);
        o.z = (unsigned)f2bf(a[4]) | ((unsigned)f2bf(a[5]) << 16);
        o.w = (unsigned)f2bf(a[6]) | ((unsigned)f2bf(a[7]) << 16);
        *reinterpret_cast<uint4*>(g16 + (long)d * 128 + fl * 8) = o;
    }
}

// ---------------------------------------------------------------------------
// MFMA GEMM: emb[r][c] = nd[r]*( (g16@Wc)[r][c] + h[r]*bcp[c] ) + bgp[c]
// fused epilogue dots: u1[r] += Σ_c emb·v1p, u2[r] += Σ_c emb·v2p
// ---------------------------------------------------------------------------
__global__ __launch_bounds__(256) void gcn_gemm_kernel(
    const unsigned short* __restrict__ g16, const unsigned short* __restrict__ Bt,
    const float* __restrict__ h, const float* __restrict__ nd,
    const float* __restrict__ bcp, const float* __restrict__ bgp,
    const float* __restrict__ v1p, const float* __restrict__ v2p,
    float* __restrict__ emb, float* __restrict__ u1, float* __restrict__ u2,
    int M, int D) {

    __shared__ __align__(16) unsigned short As[128 * 32];
    __shared__ __align__(16) unsigned short Bs[128 * 32];

    const int tid  = threadIdx.x;
    const int w    = tid >> 6;
    const int lane = tid & 63;
    const int row0 = blockIdx.x * 128;
    const int col0 = blockIdx.y * 128;

    const int r0   = 2 * w * 16 + (lane >> 2);
    const int r1   = (2 * w + 1) * 16 + (lane >> 2);
    const int slot = lane & 3;
    const int c0   = slot ^ ((r0 >> 1) & 3);
    const int c1   = slot ^ ((r1 >> 1) & 3);

    const unsigned short* pA0 = g16 + (long)(row0 + r0) * 128 + c0 * 8;
    const unsigned short* pA1 = g16 + (long)(row0 + r1) * 128 + c1 * 8;
    const unsigned short* pB0 = Bt + (long)(col0 + r0) * 128 + c0 * 8;
    const unsigned short* pB1 = Bt + (long)(col0 + r1) * 128 + c1 * 8;

    unsigned short* dA0 = As + 2 * w * 512;
    unsigned short* dA1 = As + (2 * w + 1) * 512;
    unsigned short* dB0 = Bs + 2 * w * 512;
    unsigned short* dB1 = Bs + (2 * w + 1) * 512;

    const int wrow = (w & 1) * 64;
    const int wcol = (w >> 1) * 64;
    const int lm = lane & 15, q = lane >> 4;
    const s16x8* pa[4];
    const s16x8* pb[4];
#pragma unroll
    for (int i = 0; i < 4; ++i) {
        int r = wrow + i * 16 + lm;
        int cs = q ^ ((r >> 1) & 3);
        pa[i] = reinterpret_cast<const s16x8*>(As + r * 32 + cs * 8);
        int n = wcol + i * 16 + lm;
        int cs2 = q ^ ((n >> 1) & 3);
        pb[i] = reinterpret_cast<const s16x8*>(Bs + n * 32 + cs2 * 8);
    }

    f32x4 acc[4][4];
#pragma unroll
    for (int i = 0; i < 4; ++i)
#pragma unroll
        for (int j = 0; j < 4; ++j) acc[i][j] = (f32x4)0.f;

    for (int k0 = 0; k0 < 128; k0 += 32) {
        async_ld16(pA0 + k0, dA0);
        async_ld16(pA1 + k0, dA1);
        async_ld16(pB0 + k0, dB0);
        async_ld16(pB1 + k0, dB1);
        __syncthreads();

        s16x8 af[4], bf[4];
#pragma unroll
        for (int i = 0; i < 4; ++i) { af[i] = *pa[i]; bf[i] = *pb[i]; }
#pragma unroll
        for (int i = 0; i < 4; ++i)
#pragma unroll
            for (int j = 0; j < 4; ++j)
                acc[i][j] = __builtin_amdgcn_mfma_f32_16x16x32_bf16(af[i], bf[j], acc[i][j], 0, 0, 0);
        __syncthreads();
    }

    // epilogue: finalize emb + fused u-dots
    float bcv[4], bgv[4], w1[4], w2[4];
    int colv[4];
#pragma unroll
    for (int j = 0; j < 4; ++j) {
        int c = col0 + wcol + j * 16 + lm;
        colv[j] = c;
        bcv[j] = bcp[c];
        bgv[j] = bgp[c];
        w1[j] = v1p[c];
        w2[j] = v2p[c];
    }

#pragma unroll
    for (int i = 0; i < 4; ++i) {
        float p1[4], p2[4];
#pragma unroll
        for (int reg = 0; reg < 4; ++reg) {
            int row = row0 + wrow + i * 16 + q * 4 + reg;
            float hb = h[row];
            float sc = nd[row];
            float s1 = 0.f, s2 = 0.f;
#pragma unroll
            for (int j = 0; j < 4; ++j) {
                float o = fmaf(sc, acc[i][j][reg] + hb * bcv[j], bgv[j]);
                if (row < M && colv[j] < D) emb[(long)row * D + colv[j]] = o;
                s1 = fmaf(o, w1[j], s1);
                s2 = fmaf(o, w2[j], s2);
            }
            p1[reg] = s1;
            p2[reg] = s2;
        }
#pragma unroll
        for (int mask = 1; mask < 16; mask <<= 1)
#pragma unroll
            for (int reg = 0; reg < 4; ++reg) {
                p1[reg] += __shfl_xor(p1[reg], mask);
                p2[reg] += __shfl_xor(p2[reg], mask);
            }
        if (lm == 0) {
#pragma unroll
            for (int reg = 0; reg < 4; ++reg) {
                int row = row0 + wrow + i * 16 + q * 4 + reg;
                if (row < M) {
                    atomicAdd(&u1[row], p1[reg]);
                    atomicAdd(&u2[row], p2[reg]);
                }
            }
        }
    }
}

// weights[r] = u1[trip[r,0]] + u2[trip[r,2]] + bias_dot
__global__ void weights_kernel(const int* __restrict__ trip, const float* __restrict__ u1,
                               const float* __restrict__ u2, const float* __restrict__ bdot,
                               float* __restrict__ w, int T) {
    int r = blockIdx.x * blockDim.x + threadIdx.x;
    if (r < T) {
        int s = trip[(long)r * 3 + 0];
        int o = trip[(long)r * 3 + 2];
        w[r] = u1[s] + u2[o] + bdot[0];
    }
}

// ---------------------------------------------------------------------------

extern "C" void kernel_launch(void* const* d_in, const int* in_sizes, int n_in,
                              void* d_out, int out_size, void* d_ws, size_t ws_size,
                              hipStream_t stream) {
    const float* feats      = (const float*)d_in[0];
    const float* W_aff      = (const float*)d_in[1];
    const float* b_aff      = (const float*)d_in[2];
    const float* W_gcn      = (const float*)d_in[3];
    const float* b_gcn      = (const float*)d_in[4];
    const float* W_pred_in  = (const float*)d_in[5];
    const float* b_pred_in  = (const float*)d_in[6];
    const float* W_pred_out = (const float*)d_in[7];
    const float* b_pred_out = (const float*)d_in[8];
    const int*   src        = (const int*)d_in[9];
    const int*   dst        = (const int*)d_in[10];
    const int*   trip       = (const int*)d_in[11];

    const int D = in_sizes[2];           // 500
    const int F = in_sizes[1] / D;       // 128
    const int N = in_sizes[0] / F;       // 50000
    const int E = in_sizes[9];           // 800000
    const int T = in_sizes[11] / 3;      // 200000

    const int PD = 512;
    const int GX = (N + 127) / 128;      // 391 row-blocks
    const int Mpad = GX * 128;           // 50048
    const int NC = (D + 7) / 8;          // bcomb split-K chunks (63)
    const int NBUK = (N >> 8) + 1;       // 196 buckets of 256 nodes

    float* weights = (float*)d_out;          // [T]
    float* emb     = (float*)d_out + T;      // [N*D]

    // workspace layout (16B-aligned chunks first)
    char* p = (char*)d_ws;
    unsigned short* fs16 = (unsigned short*)p;  p += (size_t)N * 128 * 2;        // 12.8 MB
    unsigned short* g16  = (unsigned short*)p;  p += (size_t)Mpad * 128 * 2;     // 12.8 MB
    unsigned long long* pairs = (unsigned long long*)p; p += (size_t)E * 8;      // 6.4 MB
    int* ssorted = (int*)p;  p += (size_t)E * 4;                                 // 3.2 MB
    unsigned short* Bt   = (unsigned short*)p;  p += (size_t)PD * 128 * 2;       // 128 KB
    float* Wc   = (float*)p;  p += (size_t)F * D * 4;                            // 256 KB
    float* bparts = (float*)p;  p += (size_t)64 * PD * 4;                        // 128 KB
    float* bcp  = (float*)p;  p += PD * 4;
    float* bgp  = (float*)p;  p += PD * 4;
    float* v1p  = (float*)p;  p += PD * 4;
    float* v2p  = (float*)p;  p += PD * 4;
    float* v    = (float*)p;  p += 1024 * 4;
    float* bdot = (float*)p;  p += 16;
    float* ns   = (float*)p;  p += (size_t)N * 4;
    float* nd   = (float*)p;  p += (size_t)N * 4;
    float* h    = (float*)p;  p += (size_t)Mpad * 4;
    float* u1   = (float*)p;  p += (size_t)N * 4;
    float* u2   = (float*)p;  p += (size_t)N * 4;
    int* bhist_src = (int*)p;  p += 256 * 4;     // zeroed together (contiguous)
    int* bhist_dst = (int*)p;  p += 256 * 4;
    int* sbbase   = (int*)p;  p += 260 * 4;
    int* sbcursor = (int*)p;  p += 256 * 4;
    int* dbbase   = (int*)p;  p += 260 * 4;
    int* dbcursor = (int*)p;  p += 256 * 4;
    int* row_ptr = (int*)p;  p += (size_t)(N + 1) * 4;
    int* csr_src = (int*)p;  p += (size_t)E * 4;

    // zero: bucket histograms, u-accumulators, g16/h pad rows
    hipMemsetAsync(bhist_src, 0, 512 * 4, stream);
    hipMemsetAsync(u1, 0, 2 * (size_t)N * sizeof(float), stream);
    hipMemsetAsync(g16 + (size_t)N * 128, 0, (size_t)(Mpad - N) * 128 * 2, stream);
    hipMemsetAsync(h + N, 0, (size_t)(Mpad - N) * 4, stream);

    // graph prep: bucket histograms -> scans -> fused partition -> finalize
    hist2_kernel<<<256, 256, 0, stream>>>(src, dst, bhist_src, bhist_dst, E);
    bscan2_kernel<<<1, 256, 0, stream>>>(bhist_src, bhist_dst, sbbase, sbcursor,
                                         dbbase, dbcursor, NBUK, E);
    fused_partition_kernel<<<(E + PCH - 1) / PCH, 256, 0, stream>>>(
        src, dst, dbcursor, pairs, sbcursor, ssorted, E, NBUK);
    bucket_finalize_kernel<<<NBUK, 256, 0, stream>>>(pairs, dbbase, ssorted, sbbase,
                                                     row_ptr, nd, csr_src, ns, N);

    // pred linearization + weight prep
    vcomb_kernel<<<(2 * D + 3) / 4, 256, 0, stream>>>(W_pred_in, W_pred_out, v, D, 2 * D);
    bias_dot_kernel<<<1, 256, 0, stream>>>(b_pred_in, W_pred_out, b_pred_out, bdot, D);

    // Wc = W_aff @ W_gcn ; bc partials (split-K) ; pads ; Bt (bf16 transposed Wc)
    {
        dim3 grid((F + 63) / 64, (D + 63) / 64);
        sgemm_kernel<<<grid, 256, 0, stream>>>(W_aff, D, W_gcn, D, Wc, D, F, D, D);
    }
    {
        dim3 grid((PD + 255) / 256, NC);
        bcomb_part_kernel<<<grid, 256, 0, stream>>>(b_aff, W_gcn, bparts, D, PD);
    }
    pad_kernel<<<(PD + 255) / 256, 256, 0, stream>>>(bparts, b_gcn, v, bcp, bgp, v1p, v2p, D, PD, NC);
    conv_Bt_kernel<<<(PD * 16 + 255) / 256, 256, 0, stream>>>(Wc, Bt, D, PD);

    // fs16 = bf16(ns ⊙ feats)
    conv_feats_kernel<<<(N * 16 + 255) / 256, 256, 0, stream>>>(feats, ns, fs16, N);

    // feature-space gather: g16, h
    gather_feats_kernel<<<(N + 3) / 4, 256, 0, stream>>>(fs16, csr_src, row_ptr, ns, g16, h, N);

    // MFMA GEMM: emb (+ fused u1/u2 dots)
    {
        dim3 grid(GX, PD / 128);
        gcn_gemm_kernel<<<grid, 256, 0, stream>>>(g16, Bt, h, nd, bcp, bgp, v1p, v2p,
                                                  emb, u1, u2, N, D);
    }

    // weights from per-node scalars
    weights_kernel<<<(T + 255) / 256, 256, 0, stream>>>(trip, u1, u2, bdot, weights, T);
}

// Round 6
// 315.181 us; speedup vs baseline: 2.1049x; 1.1260x over previous
//
#include <hip/hip_runtime.h>

// ---------------------------------------------------------------------------
// Algebra: emb = nd ⊙ (Â (ns ⊙ (feats@Wc + bc))) + b_gcn
//        = nd ⊙ ( g@Wc + h·bcᵀ ) + b_gcn     with g = Â(ns⊙feats), h = Â ns
// (Â = adjacency-by-dst incl. self loops; Wc = W_aff@W_gcn, bc = b_aff@W_gcn)
// Gather in F=128 feature space. pred MLP linear => weights = u1[s]+u2[o]+bd.
//
// R1: multi-block scan. 663→543. R2: bcomb split-K. 543→441.
// R3: bucket-partition CSR (no per-edge global atomics). 441→398.
// R4: gather unroll + atomic-free degrees. 398→365.
// R5: 16B/lane gather + partition fusions. 365→355. Top-5 = harness fills.
// R6: long-tail consolidation: 18→11 dispatches (init replaces 4 memsets;
// prep1 = vcomb+bias_dot+bcomb; conv_Bt+=pad; finalize+=conv_feats) and
// sgemm split-K x4 (grid z, partials summed in conv_Bt). Pred ~325 µs.
// ---------------------------------------------------------------------------

typedef float f32x4 __attribute__((ext_vector_type(4)));
typedef short s16x8 __attribute__((ext_vector_type(8)));

__device__ __forceinline__ unsigned short f2bf(float f) {
    unsigned u = __float_as_uint(f);
    unsigned r = (u + 0x7FFFu + ((u >> 16) & 1u)) >> 16;
    return (unsigned short)r;
}

__device__ __forceinline__ void async_ld16(const void* g, void* lds) {
    __builtin_amdgcn_global_load_lds(
        (const __attribute__((address_space(1))) unsigned int*)g,
        (__attribute__((address_space(3))) unsigned int*)lds,
        16, 0, 0);
}

// ---------------------------------------------------------------------------
// One kernel replaces all memsets: u1/u2, g16 pad rows, h pad, bucket hists.
// ---------------------------------------------------------------------------
__global__ __launch_bounds__(256) void init_kernel(
    float* __restrict__ u, int nU4, unsigned* __restrict__ gpad, int nG,
    float* __restrict__ hpad, int nH, int* __restrict__ bh, int nB) {
    const int stride = gridDim.x * blockDim.x;
    const int i0 = blockIdx.x * blockDim.x + threadIdx.x;
    for (int i = i0; i < nU4; i += stride)
        *reinterpret_cast<float4*>(u + i * 4) = make_float4(0.f, 0.f, 0.f, 0.f);
    for (int i = i0; i < nG; i += stride) gpad[i] = 0u;
    for (int i = i0; i < nH; i += stride) hpad[i] = 0.f;
    for (int i = i0; i < nB; i += stride) bh[i] = 0;
}

// ---------------------------------------------------------------------------
// Bucket histograms of src>>8 and dst>>8 (LDS-aggregated, per-block flush).
// ---------------------------------------------------------------------------
__global__ __launch_bounds__(256) void hist2_kernel(
    const int* __restrict__ src, const int* __restrict__ dst,
    int* __restrict__ bhist_src, int* __restrict__ bhist_dst, int E) {
    __shared__ int lhs[256], lhd[256];
    lhs[threadIdx.x] = 0;
    lhd[threadIdx.x] = 0;
    __syncthreads();
    const int stride = gridDim.x * blockDim.x;
    for (int e = blockIdx.x * blockDim.x + threadIdx.x; e < E; e += stride) {
        atomicAdd(&lhs[src[e] >> 8], 1);
        atomicAdd(&lhd[dst[e] >> 8], 1);
    }
    __syncthreads();
    int cs = lhs[threadIdx.x], cd = lhd[threadIdx.x];
    if (cs > 0) atomicAdd(&bhist_src[threadIdx.x], cs);
    if (cd > 0) atomicAdd(&bhist_dst[threadIdx.x], cd);
}

// Exclusive scans of both bucket histograms -> bases + cursors. 1 block.
__global__ void bscan2_kernel(const int* __restrict__ bhist_src, const int* __restrict__ bhist_dst,
                              int* __restrict__ sbbase, int* __restrict__ sbcursor,
                              int* __restrict__ dbbase, int* __restrict__ dbcursor,
                              int nbuk, int E) {
    __shared__ int sv[256];
    const int tid = threadIdx.x;

    int c = (tid < nbuk) ? bhist_src[tid] : 0;
    sv[tid] = c;
    __syncthreads();
    for (int st = 1; st < 256; st <<= 1) {
        int t = (tid >= st) ? sv[tid - st] : 0;
        __syncthreads();
        sv[tid] += t;
        __syncthreads();
    }
    if (tid < nbuk) { int ex = sv[tid] - c; sbbase[tid] = ex; sbcursor[tid] = ex; }
    if (tid == 0) sbbase[nbuk] = E;
    __syncthreads();

    c = (tid < nbuk) ? bhist_dst[tid] : 0;
    sv[tid] = c;
    __syncthreads();
    for (int st = 1; st < 256; st <<= 1) {
        int t = (tid >= st) ? sv[tid - st] : 0;
        __syncthreads();
        sv[tid] += t;
        __syncthreads();
    }
    if (tid < nbuk) { int ex = sv[tid] - c; dbbase[tid] = ex; dbcursor[tid] = ex; }
    if (tid == 0) dbbase[nbuk] = E;
}

// ---------------------------------------------------------------------------
// Fused partition: one read of (src,dst); phase A sorts (dst,src) pairs by
// dst-bucket, phase B sorts src by src-bucket — LDS counting sorts, coalesced
// run writes, one cursor reservation per (block,bucket).
// ---------------------------------------------------------------------------
#define PCH 4096
__global__ __launch_bounds__(256) void fused_partition_kernel(
    const int* __restrict__ src, const int* __restrict__ dst,
    int* __restrict__ dcursor, unsigned long long* __restrict__ pairs,
    int* __restrict__ scursor, int* __restrict__ ssorted,
    int E, int nbuk) {
    __shared__ int lhist[256];
    __shared__ int lbase[256];
    __shared__ int gbase[256];
    __shared__ int scanv[256];
    __shared__ unsigned long long lpair[PCH];   // 32 KB (reused as int in B)
    __shared__ unsigned char lbid[PCH];

    const int tid = threadIdx.x;
    const int c0 = blockIdx.x * PCH;
    int cnt = E - c0; if (cnt > PCH) cnt = PCH;

    int dv[16], sv[16], rk[16];

    // ---- phase A: (dst,src) by dst-bucket ----
    lhist[tid] = 0;
    __syncthreads();
#pragma unroll
    for (int q = 0; q < 16; ++q) {
        int e = c0 + q * 256 + tid;
        if (e < E) {
            int d = dst[e];
            dv[q] = d;
            sv[q] = src[e];
            rk[q] = atomicAdd(&lhist[d >> 8], 1);
        } else {
            dv[q] = -1;
            sv[q] = -1;
        }
    }
    __syncthreads();

    int c = lhist[tid];
    scanv[tid] = c;
    __syncthreads();
    for (int st = 1; st < 256; st <<= 1) {
        int t = (tid >= st) ? scanv[tid - st] : 0;
        __syncthreads();
        scanv[tid] += t;
        __syncthreads();
    }
    lbase[tid] = scanv[tid] - c;
    if (tid < nbuk && c > 0) gbase[tid] = atomicAdd(&dcursor[tid], c);
    __syncthreads();

#pragma unroll
    for (int q = 0; q < 16; ++q) {
        if (dv[q] >= 0) {
            int b = dv[q] >> 8;
            int slot = lbase[b] + rk[q];
            lpair[slot] = ((unsigned long long)(unsigned)dv[q] << 32) | (unsigned)sv[q];
            lbid[slot] = (unsigned char)b;
        }
    }
    __syncthreads();

    for (int i = tid; i < cnt; i += 256) {
        int b = lbid[i];
        pairs[(long)gbase[b] + (i - lbase[b])] = lpair[i];
    }
    __syncthreads();

    // ---- phase B: src by src-bucket (reuse LDS) ----
    int* lval = (int*)lpair;
    lhist[tid] = 0;
    __syncthreads();
#pragma unroll
    for (int q = 0; q < 16; ++q) {
        if (sv[q] >= 0) rk[q] = atomicAdd(&lhist[sv[q] >> 8], 1);
    }
    __syncthreads();

    c = lhist[tid];
    scanv[tid] = c;
    __syncthreads();
    for (int st = 1; st < 256; st <<= 1) {
        int t = (tid >= st) ? scanv[tid - st] : 0;
        __syncthreads();
        scanv[tid] += t;
        __syncthreads();
    }
    lbase[tid] = scanv[tid] - c;
    if (tid < nbuk && c > 0) gbase[tid] = atomicAdd(&scursor[tid], c);
    __syncthreads();

#pragma unroll
    for (int q = 0; q < 16; ++q) {
        if (sv[q] >= 0) {
            int b = sv[q] >> 8;
            int slot = lbase[b] + rk[q];
            lval[slot] = sv[q];
            lbid[slot] = (unsigned char)b;
        }
    }
    __syncthreads();

    for (int i = tid; i < cnt; i += 256) {
        int b = lbid[i];
        ssorted[(long)gbase[b] + (i - lbase[b])] = lval[i];
    }
}

// ---------------------------------------------------------------------------
// Per-bucket finalize: CSR (row_ptr, nd, csr_src) + out-degree -> ns, AND
// conv_feats for the bucket's 256 nodes (fs16 = bf16(ns ⊙ feats)) — ns is
// already in LDS, rows are block-local.
// ---------------------------------------------------------------------------
__global__ __launch_bounds__(256) void bucket_finalize_kernel(
    const unsigned long long* __restrict__ pairs, const int* __restrict__ dbbase,
    const int* __restrict__ ssorted, const int* __restrict__ sbbase,
    const float* __restrict__ feats,
    int* __restrict__ row_ptr, float* __restrict__ ndv,
    int* __restrict__ csr_src, float* __restrict__ ns,
    unsigned short* __restrict__ fs16, int N) {
    __shared__ int hist[256];
    __shared__ int scanv[256];
    __shared__ int lcur[256];
    __shared__ float nsv[256];
    const int tid = threadIdx.x;
    const int b = blockIdx.x;
    const int node = b * 256 + tid;

    // ---- CSR for dst-bucket b ----
    const int e0 = dbbase[b], e1 = dbbase[b + 1];
    hist[tid] = 0;
    __syncthreads();
    for (int e = e0 + tid; e < e1; e += 256) {
        int d = (int)(pairs[e] >> 32);
        atomicAdd(&hist[d & 255], 1);
    }
    __syncthreads();

    int c = hist[tid];
    scanv[tid] = c;
    __syncthreads();
    for (int st = 1; st < 256; st <<= 1) {
        int t = (tid >= st) ? scanv[tid - st] : 0;
        __syncthreads();
        scanv[tid] += t;
        __syncthreads();
    }
    int excl = scanv[tid] - c;
    if (node < N) {
        row_ptr[node] = e0 + excl;
        ndv[node] = rsqrtf((float)(c + 1));
    }
    if (node == N) row_ptr[N] = e0 + excl;
    lcur[tid] = excl;
    __syncthreads();

    for (int e = e0 + tid; e < e1; e += 256) {
        unsigned long long pr = pairs[e];
        int d = (int)(pr >> 32);
        int r = atomicAdd(&lcur[d & 255], 1);
        csr_src[e0 + r] = (int)(pr & 0xFFFFFFFFu);
    }

    // ---- out-degree histogram for src-bucket b -> ns ----
    __syncthreads();
    hist[tid] = 0;
    __syncthreads();
    const int s0 = sbbase[b], s1 = sbbase[b + 1];
    for (int e = s0 + tid; e < s1; e += 256) atomicAdd(&hist[ssorted[e] & 255], 1);
    __syncthreads();
    float nsval = rsqrtf((float)(hist[tid] + 1));
    nsv[tid] = nsval;
    if (node < N) ns[node] = nsval;
    __syncthreads();

    // ---- conv_feats for nodes [b*256, b*256+256): 16 rows/iter, 8 feats/thread
    for (int r0 = 0; r0 < 256; r0 += 16) {
        int r = r0 + (tid >> 4);
        int nn = b * 256 + r;
        if (nn >= N) break;
        int cq = (tid & 15) * 8;
        float s = nsv[r];
        const float* pf = feats + (long)nn * 128 + cq;
        float4 a = *reinterpret_cast<const float4*>(pf);
        float4 d2 = *reinterpret_cast<const float4*>(pf + 4);
        uint4 o;
        o.x = (unsigned)f2bf(a.x * s) | ((unsigned)f2bf(a.y * s) << 16);
        o.y = (unsigned)f2bf(a.z * s) | ((unsigned)f2bf(a.w * s) << 16);
        o.z = (unsigned)f2bf(d2.x * s) | ((unsigned)f2bf(d2.y * s) << 16);
        o.w = (unsigned)f2bf(d2.z * s) | ((unsigned)f2bf(d2.w * s) << 16);
        *reinterpret_cast<uint4*>(fs16 + (long)nn * 128 + cq) = o;
    }
}

// ---------------------------------------------------------------------------
// prep1: branched fusion of {bcomb split-K partials | vcomb | bias_dot}.
// blocks [0, NBbc): bcomb chunk partials; [NBbc, NBbc+NBv): vcomb; last: bias.
// ---------------------------------------------------------------------------
__global__ __launch_bounds__(256) void prep1_kernel(
    const float* __restrict__ b_aff, const float* __restrict__ W_gcn,
    float* __restrict__ part,
    const float* __restrict__ Win, const float* __restrict__ wout,
    float* __restrict__ v,
    const float* __restrict__ b_in, const float* __restrict__ b_out,
    float* __restrict__ bdot,
    int D, int PD, int NBbc, int NBv, int nbper) {
    __shared__ float sm[256];
    const int b = blockIdx.x;
    const int tid = threadIdx.x;

    if (b < NBbc) {
        // bcomb partial: chunk c covers k in [8c, min(8c+8,D))
        int nblk = b % nbper;
        int cch = b / nbper;
        int n = nblk * 256 + tid;
        if (n >= PD) return;
        float s = 0.f;
        if (n < D) {
            int k0 = cch * 8;
            int k1 = k0 + 8; if (k1 > D) k1 = D;
            for (int k = k0; k < k1; ++k) s = fmaf(b_aff[k], W_gcn[(long)k * D + n], s);
        }
        part[(long)cch * PD + n] = s;
    } else if (b < NBbc + NBv) {
        // vcomb: one wave per row k
        int k = (b - NBbc) * 4 + (tid >> 6);
        int lane = tid & 63;
        if (k >= 2 * D) return;
        float s = 0.f;
        for (int cc = lane; cc < D; cc += 64) s = fmaf(Win[(long)k * D + cc], wout[cc], s);
#pragma unroll
        for (int m = 32; m > 0; m >>= 1) s += __shfl_down(s, m);
        if (lane == 0) v[k] = s;
    } else {
        // bias_dot
        float s = 0.f;
        for (int cc = tid; cc < D; cc += 256) s = fmaf(b_in[cc], wout[cc], s);
        sm[tid] = s;
        __syncthreads();
        for (int st = 128; st > 0; st >>= 1) {
            if (tid < st) sm[tid] += sm[tid + st];
            __syncthreads();
        }
        if (tid == 0) bdot[0] = sm[0] + b_out[0];
    }
}

// ---------------------------------------------------------------------------
// fp32 tiled GEMM, split-K over blockIdx.z (chunks of 128) -> partials.
// Only used for the tiny Wc = W_aff @ W_gcn.
// ---------------------------------------------------------------------------
__global__ __launch_bounds__(256) void sgemm_kernel(const float* __restrict__ A, int lda,
                                                    const float* __restrict__ B, int ldb,
                                                    float* __restrict__ Cp, int ldc,
                                                    int M, int N, int K) {
    __shared__ __align__(16) float As[16][68];
    __shared__ __align__(16) float Bs[16][68];
    const int tid = threadIdx.x;
    const int tx = tid & 15, ty = tid >> 4;
    const int row0 = blockIdx.x * 64;
    const int col0 = blockIdx.y * 64;
    const int kbeg = blockIdx.z * 128;
    int kend = kbeg + 128; if (kend > K) kend = K;
    float* C = Cp + (long)blockIdx.z * M * ldc;

    const int a_row = tid >> 2;
    const int a_k   = (tid & 3) * 4;
    const int b_k   = tid >> 4;
    const int b_c   = (tid & 15) * 4;

    float acc[4][4] = {};

    for (int k0 = kbeg; k0 < kend; k0 += 16) {
        float4 av = make_float4(0.f, 0.f, 0.f, 0.f);
        {
            int gr = row0 + a_row;
            int gk = k0 + a_k;
            if (gr < M) {
                if (gk + 3 < kend) {
                    av = *reinterpret_cast<const float4*>(&A[(long)gr * lda + gk]);
                } else {
                    float t0 = (gk + 0 < kend) ? A[(long)gr * lda + gk + 0] : 0.f;
                    float t1 = (gk + 1 < kend) ? A[(long)gr * lda + gk + 1] : 0.f;
                    float t2 = (gk + 2 < kend) ? A[(long)gr * lda + gk + 2] : 0.f;
                    float t3 = (gk + 3 < kend) ? A[(long)gr * lda + gk + 3] : 0.f;
                    av = make_float4(t0, t1, t2, t3);
                }
            }
        }
        float4 bv = make_float4(0.f, 0.f, 0.f, 0.f);
        {
            int gk = k0 + b_k;
            int gc = col0 + b_c;
            if (gk < kend) {
                if (gc + 3 < N) {
                    bv = *reinterpret_cast<const float4*>(&B[(long)gk * ldb + gc]);
                } else {
                    float t0 = (gc + 0 < N) ? B[(long)gk * ldb + gc + 0] : 0.f;
                    float t1 = (gc + 1 < N) ? B[(long)gk * ldb + gc + 1] : 0.f;
                    float t2 = (gc + 2 < N) ? B[(long)gk * ldb + gc + 2] : 0.f;
                    float t3 = (gc + 3 < N) ? B[(long)gk * ldb + gc + 3] : 0.f;
                    bv = make_float4(t0, t1, t2, t3);
                }
            }
        }
        __syncthreads();
        As[a_k + 0][a_row] = av.x;
        As[a_k + 1][a_row] = av.y;
        As[a_k + 2][a_row] = av.z;
        As[a_k + 3][a_row] = av.w;
        *reinterpret_cast<float4*>(&Bs[b_k][b_c]) = bv;
        __syncthreads();

#pragma unroll
        for (int k = 0; k < 16; ++k) {
            const float4 a = *reinterpret_cast<const float4*>(&As[k][ty * 4]);
            const float4 b = *reinterpret_cast<const float4*>(&Bs[k][tx * 4]);
            const float avv[4] = {a.x, a.y, a.z, a.w};
            const float bvv[4] = {b.x, b.y, b.z, b.w};
#pragma unroll
            for (int i = 0; i < 4; ++i)
#pragma unroll
                for (int j = 0; j < 4; ++j)
                    acc[i][j] = fmaf(avv[i], bvv[j], acc[i][j]);
        }
    }

#pragma unroll
    for (int i = 0; i < 4; ++i) {
        int r = row0 + ty * 4 + i;
        if (r >= M) continue;
#pragma unroll
        for (int j = 0; j < 4; ++j) {
            int c = col0 + tx * 4 + j;
            if (c < N) C[(long)r * ldc + c] = acc[i][j];
        }
    }
}

// ---------------------------------------------------------------------------
// conv_Bt (+ fused pad): blocks [0,32): Bt[n][k] = bf16(Σ_z Wcp[z][k][n]);
// blocks 32..33: bcp/bgp/v1p/v2p pads (bcp reduced from bcomb partials).
// ---------------------------------------------------------------------------
__global__ __launch_bounds__(256) void convBt_pad_kernel(
    const float* __restrict__ Wcp, unsigned short* __restrict__ Bt,
    const float* __restrict__ part, const float* __restrict__ b_gcn,
    const float* __restrict__ v, float* __restrict__ bcp,
    float* __restrict__ bgp, float* __restrict__ v1p, float* __restrict__ v2p,
    int D, int PD, int NC, int F, int nConvBlk) {
    const int b = blockIdx.x;
    const int tid = threadIdx.x;
    if (b < nConvBlk) {
        int idx = b * 256 + tid;
        if (idx >= PD * 16) return;
        int n = idx >> 4;
        int k8 = (idx & 15) * 8;
        uint4 o = make_uint4(0, 0, 0, 0);
        if (n < D) {
            unsigned short t[8];
            const long FD = (long)F * D;
#pragma unroll
            for (int q = 0; q < 8; ++q) {
                long off = (long)(k8 + q) * D + n;
                float val = Wcp[off] + Wcp[FD + off] + Wcp[2 * FD + off] + Wcp[3 * FD + off];
                t[q] = f2bf(val);
            }
            o.x = (unsigned)t[0] | ((unsigned)t[1] << 16);
            o.y = (unsigned)t[2] | ((unsigned)t[3] << 16);
            o.z = (unsigned)t[4] | ((unsigned)t[5] << 16);
            o.w = (unsigned)t[6] | ((unsigned)t[7] << 16);
        }
        *reinterpret_cast<uint4*>(Bt + (long)n * 128 + k8) = o;
    } else {
        int i = (b - nConvBlk) * 256 + tid;
        if (i < PD) {
            float s = 0.f;
            for (int c = 0; c < NC; ++c) s += part[(long)c * PD + i];
            bcp[i] = s;
            bgp[i] = (i < D) ? b_gcn[i] : 0.f;
            v1p[i] = (i < D) ? v[i] : 0.f;
            v2p[i] = (i < D) ? v[D + i] : 0.f;
        }
    }
}

// ---------------------------------------------------------------------------
// Feature-space CSR gather, wave per node, 16B/lane loads.
//   g16[d] = bf16( Σ_{s∈in(d)} fs16[s] + fs16[d] ),  h[d] = Σ ns[s] + ns[d]
// ---------------------------------------------------------------------------
__global__ __launch_bounds__(256) void gather_feats_kernel(
    const unsigned short* __restrict__ fs16, const int* __restrict__ csr_src,
    const int* __restrict__ row_ptr, const float* __restrict__ ns,
    unsigned short* __restrict__ g16, float* __restrict__ h, int N) {
    int d = blockIdx.x * 4 + (threadIdx.x >> 6);
    int lane = threadIdx.x & 63;
    if (d >= N) return;
    const int g = lane >> 4;      // neighbor slot within quad
    const int fl = lane & 15;     // feature slot (8 feats)

    float a[8] = {0.f, 0.f, 0.f, 0.f, 0.f, 0.f, 0.f, 0.f};
    float hacc = 0.f;

    const int beg = row_ptr[d], end = row_ptr[d + 1];
    for (int j0 = beg; j0 < end; j0 += 64) {
        int cnt = end - j0;
        if (cnt > 64) cnt = 64;
        int s = (lane < cnt) ? csr_src[j0 + lane] : 0;
        if (lane < cnt) hacc += ns[s];
        for (int k = 0; k < cnt; k += 8) {
            int k0 = k + g, k1 = k + 4 + g;
            int i0 = __shfl(s, k0 & 63);
            int i1 = __shfl(s, k1 & 63);
            uint4 v0 = make_uint4(0u, 0u, 0u, 0u), v1 = make_uint4(0u, 0u, 0u, 0u);
            if (k0 < cnt) v0 = *reinterpret_cast<const uint4*>(fs16 + (long)i0 * 128 + fl * 8);
            if (k1 < cnt) v1 = *reinterpret_cast<const uint4*>(fs16 + (long)i1 * 128 + fl * 8);
            a[0] += __uint_as_float(v0.x << 16); a[1] += __uint_as_float(v0.x & 0xFFFF0000u);
            a[2] += __uint_as_float(v0.y << 16); a[3] += __uint_as_float(v0.y & 0xFFFF0000u);
            a[4] += __uint_as_float(v0.z << 16); a[5] += __uint_as_float(v0.z & 0xFFFF0000u);
            a[6] += __uint_as_float(v0.w << 16); a[7] += __uint_as_float(v0.w & 0xFFFF0000u);
            a[0] += __uint_as_float(v1.x << 16); a[1] += __uint_as_float(v1.x & 0xFFFF0000u);
            a[2] += __uint_as_float(v1.y << 16); a[3] += __uint_as_float(v1.y & 0xFFFF0000u);
            a[4] += __uint_as_float(v1.z << 16); a[5] += __uint_as_float(v1.z & 0xFFFF0000u);
            a[6] += __uint_as_float(v1.w << 16); a[7] += __uint_as_float(v1.w & 0xFFFF0000u);
        }
    }

#pragma unroll
    for (int r = 0; r < 8; ++r) {
        a[r] += __shfl_xor(a[r], 16);
        a[r] += __shfl_xor(a[r], 32);
    }
    {
        uint4 sv4 = *reinterpret_cast<const uint4*>(fs16 + (long)d * 128 + fl * 8);
        a[0] += __uint_as_float(sv4.x << 16); a[1] += __uint_as_float(sv4.x & 0xFFFF0000u);
        a[2] += __uint_as_float(sv4.y << 16); a[3] += __uint_as_float(sv4.y & 0xFFFF0000u);
        a[4] += __uint_as_float(sv4.z << 16); a[5] += __uint_as_float(sv4.z & 0xFFFF0000u);
        a[6] += __uint_as_float(sv4.w << 16); a[7] += __uint_as_float(sv4.w & 0xFFFF0000u);
    }
#pragma unroll
    for (int m = 32; m > 0; m >>= 1) hacc += __shfl_xor(hacc, m);
    if (lane == 0) h[d] = hacc + ns[d];
    if (lane < 16) {
        uint4 o;
        o.x = (unsigned)f2bf(a[0]) | ((unsigned)f2bf(a[1]) << 16);
        o.y = (unsigned)f2bf(a[2]) | ((unsigned)f2bf(a[3]) << 16);
        o.z = (unsigned)f2bf(a[4]) | ((unsigned)f2bf(a[5]) << 16);
        o.w = (unsigned)f2bf(a[6]) | ((unsigned)f2bf(a[7]) << 16);
        *reinterpret_cast<uint4*>(g16 + (long)d * 128 + fl * 8) = o;
    }
}

// ---------------------------------------------------------------------------
// MFMA GEMM: emb[r][c] = nd[r]*( (g16@Wc)[r][c] + h[r]*bcp[c] ) + bgp[c]
// fused epilogue dots: u1[r] += Σ_c emb·v1p, u2[r] += Σ_c emb·v2p
// ---------------------------------------------------------------------------
__global__ __launch_bounds__(256) void gcn_gemm_kernel(
    const unsigned short* __restrict__ g16, const unsigned short* __restrict__ Bt,
    const float* __restrict__ h, const float* __restrict__ nd,
    const float* __restrict__ bcp, const float* __restrict__ bgp,
    const float* __restrict__ v1p, const float* __restrict__ v2p,
    float* __restrict__ emb, float* __restrict__ u1, float* __restrict__ u2,
    int M, int D) {

    __shared__ __align__(16) unsigned short As[128 * 32];
    __shared__ __align__(16) unsigned short Bs[128 * 32];

    const int tid  = threadIdx.x;
    const int w    = tid >> 6;
    const int lane = tid & 63;
    const int row0 = blockIdx.x * 128;
    const int col0 = blockIdx.y * 128;

    const int r0   = 2 * w * 16 + (lane >> 2);
    const int r1   = (2 * w + 1) * 16 + (lane >> 2);
    const int slot = lane & 3;
    const int c0   = slot ^ ((r0 >> 1) & 3);
    const int c1   = slot ^ ((r1 >> 1) & 3);

    const unsigned short* pA0 = g16 + (long)(row0 + r0) * 128 + c0 * 8;
    const unsigned short* pA1 = g16 + (long)(row0 + r1) * 128 + c1 * 8;
    const unsigned short* pB0 = Bt + (long)(col0 + r0) * 128 + c0 * 8;
    const unsigned short* pB1 = Bt + (long)(col0 + r1) * 128 + c1 * 8;

    unsigned short* dA0 = As + 2 * w * 512;
    unsigned short* dA1 = As + (2 * w + 1) * 512;
    unsigned short* dB0 = Bs + 2 * w * 512;
    unsigned short* dB1 = Bs + (2 * w + 1) * 512;

    const int wrow = (w & 1) * 64;
    const int wcol = (w >> 1) * 64;
    const int lm = lane & 15, q = lane >> 4;
    const s16x8* pa[4];
    const s16x8* pb[4];
#pragma unroll
    for (int i = 0; i < 4; ++i) {
        int r = wrow + i * 16 + lm;
        int cs = q ^ ((r >> 1) & 3);
        pa[i] = reinterpret_cast<const s16x8*>(As + r * 32 + cs * 8);
        int n = wcol + i * 16 + lm;
        int cs2 = q ^ ((n >> 1) & 3);
        pb[i] = reinterpret_cast<const s16x8*>(Bs + n * 32 + cs2 * 8);
    }

    f32x4 acc[4][4];
#pragma unroll
    for (int i = 0; i < 4; ++i)
#pragma unroll
        for (int j = 0; j < 4; ++j) acc[i][j] = (f32x4)0.f;

    for (int k0 = 0; k0 < 128; k0 += 32) {
        async_ld16(pA0 + k0, dA0);
        async_ld16(pA1 + k0, dA1);
        async_ld16(pB0 + k0, dB0);
        async_ld16(pB1 + k0, dB1);
        __syncthreads();

        s16x8 af[4], bf[4];
#pragma unroll
        for (int i = 0; i < 4; ++i) { af[i] = *pa[i]; bf[i] = *pb[i]; }
#pragma unroll
        for (int i = 0; i < 4; ++i)
#pragma unroll
            for (int j = 0; j < 4; ++j)
                acc[i][j] = __builtin_amdgcn_mfma_f32_16x16x32_bf16(af[i], bf[j], acc[i][j], 0, 0, 0);
        __syncthreads();
    }

    float bcv[4], bgv[4], w1[4], w2[4];
    int colv[4];
#pragma unroll
    for (int j = 0; j < 4; ++j) {
        int c = col0 + wcol + j * 16 + lm;
        colv[j] = c;
        bcv[j] = bcp[c];
        bgv[j] = bgp[c];
        w1[j] = v1p[c];
        w2[j] = v2p[c];
    }

#pragma unroll
    for (int i = 0; i < 4; ++i) {
        float p1[4], p2[4];
#pragma unroll
        for (int reg = 0; reg < 4; ++reg) {
            int row = row0 + wrow + i * 16 + q * 4 + reg;
            float hb = h[row];
            float sc = nd[row];
            float s1 = 0.f, s2 = 0.f;
#pragma unroll
            for (int j = 0; j < 4; ++j) {
                float o = fmaf(sc, acc[i][j][reg] + hb * bcv[j], bgv[j]);
                if (row < M && colv[j] < D) emb[(long)row * D + colv[j]] = o;
                s1 = fmaf(o, w1[j], s1);
                s2 = fmaf(o, w2[j], s2);
            }
            p1[reg] = s1;
            p2[reg] = s2;
        }
#pragma unroll
        for (int mask = 1; mask < 16; mask <<= 1)
#pragma unroll
            for (int reg = 0; reg < 4; ++reg) {
                p1[reg] += __shfl_xor(p1[reg], mask);
                p2[reg] += __shfl_xor(p2[reg], mask);
            }
        if (lm == 0) {
#pragma unroll
            for (int reg = 0; reg < 4; ++reg) {
                int row = row0 + wrow + i * 16 + q * 4 + reg;
                if (row < M) {
                    atomicAdd(&u1[row], p1[reg]);
                    atomicAdd(&u2[row], p2[reg]);
                }
            }
        }
    }
}

// weights[r] = u1[trip[r,0]] + u2[trip[r,2]] + bias_dot
__global__ void weights_kernel(const int* __restrict__ trip, const float* __restrict__ u1,
                               const float* __restrict__ u2, const float* __restrict__ bdot,
                               float* __restrict__ w, int T) {
    int r = blockIdx.x * blockDim.x + threadIdx.x;
    if (r < T) {
        int s = trip[(long)r * 3 + 0];
        int o = trip[(long)r * 3 + 2];
        w[r] = u1[s] + u2[o] + bdot[0];
    }
}

// ---------------------------------------------------------------------------

extern "C" void kernel_launch(void* const* d_in, const int* in_sizes, int n_in,
                              void* d_out, int out_size, void* d_ws, size_t ws_size,
                              hipStream_t stream) {
    const float* feats      = (const float*)d_in[0];
    const float* W_aff      = (const float*)d_in[1];
    const float* b_aff      = (const float*)d_in[2];
    const float* W_gcn      = (const float*)d_in[3];
    const float* b_gcn      = (const float*)d_in[4];
    const float* W_pred_in  = (const float*)d_in[5];
    const float* b_pred_in  = (const float*)d_in[6];
    const float* W_pred_out = (const float*)d_in[7];
    const float* b_pred_out = (const float*)d_in[8];
    const int*   src        = (const int*)d_in[9];
    const int*   dst        = (const int*)d_in[10];
    const int*   trip       = (const int*)d_in[11];

    const int D = in_sizes[2];           // 500
    const int F = in_sizes[1] / D;       // 128
    const int N = in_sizes[0] / F;       // 50000
    const int E = in_sizes[9];           // 800000
    const int T = in_sizes[11] / 3;      // 200000

    const int PD = 512;
    const int GX = (N + 127) / 128;      // 391 row-blocks
    const int Mpad = GX * 128;           // 50048
    const int NC = (D + 7) / 8;          // bcomb split-K chunks (63)
    const int NBUK = (N >> 8) + 1;       // 196 buckets of 256 nodes
    const int KS = 4;                    // sgemm split-K chunks of 128

    float* weights = (float*)d_out;          // [T]
    float* emb     = (float*)d_out + T;      // [N*D]

    // workspace layout (16B-aligned chunks first)
    char* p = (char*)d_ws;
    unsigned short* fs16 = (unsigned short*)p;  p += (size_t)N * 128 * 2;        // 12.8 MB
    unsigned short* g16  = (unsigned short*)p;  p += (size_t)Mpad * 128 * 2;     // 12.8 MB
    unsigned long long* pairs = (unsigned long long*)p; p += (size_t)E * 8;      // 6.4 MB
    int* ssorted = (int*)p;  p += (size_t)E * 4;                                 // 3.2 MB
    unsigned short* Bt   = (unsigned short*)p;  p += (size_t)PD * 128 * 2;       // 128 KB
    float* Wcp  = (float*)p;  p += (size_t)KS * F * D * 4;                       // 1 MB (split-K partials)
    float* bparts = (float*)p;  p += (size_t)64 * PD * 4;                        // 128 KB
    float* bcp  = (float*)p;  p += PD * 4;
    float* bgp  = (float*)p;  p += PD * 4;
    float* v1p  = (float*)p;  p += PD * 4;
    float* v2p  = (float*)p;  p += PD * 4;
    float* v    = (float*)p;  p += 1024 * 4;
    float* bdot = (float*)p;  p += 16;
    float* ns   = (float*)p;  p += (size_t)N * 4;
    float* nd   = (float*)p;  p += (size_t)N * 4;
    float* h    = (float*)p;  p += (size_t)Mpad * 4;
    float* u1   = (float*)p;  p += (size_t)N * 4;   // u1,u2 contiguous (init zero)
    float* u2   = (float*)p;  p += (size_t)N * 4;
    int* bhist_src = (int*)p;  p += 256 * 4;     // bhist_src,bhist_dst contiguous
    int* bhist_dst = (int*)p;  p += 256 * 4;
    int* sbbase   = (int*)p;  p += 260 * 4;
    int* sbcursor = (int*)p;  p += 256 * 4;
    int* dbbase   = (int*)p;  p += 260 * 4;
    int* dbcursor = (int*)p;  p += 256 * 4;
    int* row_ptr = (int*)p;  p += (size_t)(N + 1) * 4;
    int* csr_src = (int*)p;  p += (size_t)E * 4;

    // one init launch replaces all memsets
    init_kernel<<<128, 256, 0, stream>>>(
        u1, (2 * N) / 4,
        (unsigned*)(g16 + (size_t)N * 128), (Mpad - N) * 128 / 2,
        h + N, Mpad - N,
        bhist_src, 512);

    // graph prep: histograms -> scans -> fused partition -> finalize(+ns+conv)
    hist2_kernel<<<256, 256, 0, stream>>>(src, dst, bhist_src, bhist_dst, E);
    bscan2_kernel<<<1, 256, 0, stream>>>(bhist_src, bhist_dst, sbbase, sbcursor,
                                         dbbase, dbcursor, NBUK, E);
    fused_partition_kernel<<<(E + PCH - 1) / PCH, 256, 0, stream>>>(
        src, dst, dbcursor, pairs, sbcursor, ssorted, E, NBUK);
    bucket_finalize_kernel<<<NBUK, 256, 0, stream>>>(pairs, dbbase, ssorted, sbbase,
                                                     feats, row_ptr, nd, csr_src, ns,
                                                     fs16, N);

    // dense prep: prep1 (bcomb partials + vcomb + bias_dot), sgemm split-K,
    // conv_Bt(+pad)
    {
        const int nbper = (PD + 255) / 256;
        const int NBbc = nbper * NC;
        const int NBv = (2 * D + 3) / 4;
        prep1_kernel<<<NBbc + NBv + 1, 256, 0, stream>>>(
            b_aff, W_gcn, bparts, W_pred_in, W_pred_out, v,
            b_pred_in, b_pred_out, bdot, D, PD, NBbc, NBv, nbper);
    }
    {
        dim3 grid((F + 63) / 64, (D + 63) / 64, KS);
        sgemm_kernel<<<grid, 256, 0, stream>>>(W_aff, D, W_gcn, D, Wcp, D, F, D, D);
    }
    {
        const int nConvBlk = (PD * 16 + 255) / 256;   // 32
        const int nPadBlk = (PD + 255) / 256;         // 2
        convBt_pad_kernel<<<nConvBlk + nPadBlk, 256, 0, stream>>>(
            Wcp, Bt, bparts, b_gcn, v, bcp, bgp, v1p, v2p, D, PD, NC, F, nConvBlk);
    }

    // feature-space gather: g16, h
    gather_feats_kernel<<<(N + 3) / 4, 256, 0, stream>>>(fs16, csr_src, row_ptr, ns, g16, h, N);

    // MFMA GEMM: emb (+ fused u1/u2 dots)
    {
        dim3 grid(GX, PD / 128);
        gcn_gemm_kernel<<<grid, 256, 0, stream>>>(g16, Bt, h, nd, bcp, bgp, v1p, v2p,
                                                  emb, u1, u2, N, D);
    }

    // weights from per-node scalars
    weights_kernel<<<(T + 255) / 256, 256, 0, stream>>>(trip, u1, u2, bdot, weights, T);
}